// Round 1
// baseline (2071.064 us; speedup 1.0000x reference)
//
#include <hip/hip_runtime.h>

// ---------------------------------------------------------------------------
// Types
// ---------------------------------------------------------------------------
using s16x8 = __attribute__((ext_vector_type(8))) short;   // 8 bf16 in 4 VGPRs
using f32x4 = __attribute__((ext_vector_type(4))) float;   // MFMA accumulator
using u16x4 = __attribute__((ext_vector_type(4))) unsigned short;

__device__ __forceinline__ unsigned short f2bf(float f) {
    union { float f; unsigned u; } v; v.f = f;
    unsigned u = v.u + 0x7FFFu + ((v.u >> 16) & 1u);   // round-nearest-even
    return (unsigned short)(u >> 16);
}

// block reduction: op==0 sum, op==1 max. lds must have >= blockDim/64 floats.
__device__ __forceinline__ float block_reduce(float v, int op, float* lds) {
    const int lane = threadIdx.x & 63;
    const int w    = threadIdx.x >> 6;
    const int nw   = blockDim.x >> 6;
#pragma unroll
    for (int off = 32; off > 0; off >>= 1) {
        float o = __shfl_down(v, off, 64);
        v = op ? fmaxf(v, o) : (v + o);
    }
    __syncthreads();
    if (lane == 0) lds[w] = v;
    __syncthreads();
    float r = lds[0];
    for (int i = 1; i < nw; i++) r = op ? fmaxf(r, lds[i]) : (r + lds[i]);
    return r;
}

// ---------------------------------------------------------------------------
// Generic batched GEMM:  C[z] = act( alpha * A[z] @ B[z](^T) + bias )
//   A: M x K, row stride lda, batch stride sAz           (fp32 -> bf16)
//   BKN=false: B is W (N x K row-major, ldb = row stride)  [C = A @ W^T]
//   BKN=true : B is K x N row-major (ldb = row stride)     [C = A @ B]
//   C: M x N, row stride ldc, batch stride sCz (fp32)
// Requires M%128==0, N%128==0, K%32==0.
// ---------------------------------------------------------------------------
template<bool BKN, bool RELU>
__global__ __launch_bounds__(256, 2)
void gemm_kernel(const float* __restrict__ A, const float* __restrict__ B,
                 const float* __restrict__ bias, float* __restrict__ C,
                 int M, int N, int K, int lda, int ldb, int ldc,
                 long sAz, long sBz, long sCz, float alpha)
{
    __shared__ unsigned short As[128][40];   // [m][k], +8 pad
    __shared__ unsigned short Bs[128][40];   // [n][k], +8 pad

    const int tid = threadIdx.x;
    const int z   = blockIdx.z;
    const int m0  = blockIdx.x * 128;
    const int n0  = blockIdx.y * 128;

    const float* Ab = A + (size_t)z * sAz + (size_t)m0 * lda;
    const float* Bb = B + (size_t)z * sBz;

    const int wave = tid >> 6, lane = tid & 63;
    const int wm = (wave & 1) * 64, wn = (wave >> 1) * 64;
    const int mi = lane & 15, quad = lane >> 4;

    f32x4 acc[4][4];
#pragma unroll
    for (int i = 0; i < 4; i++)
#pragma unroll
        for (int j = 0; j < 4; j++) acc[i][j] = (f32x4)0.f;

    const int ar = tid >> 3, ak = (tid & 7) * 4;     // 32 rows/pass, 4 passes
    const int bkr = tid >> 5, bnq = (tid & 31) * 4;  // K x N staging

    for (int k0 = 0; k0 < K; k0 += 32) {
        // ---- stage A (M x K rows -> As[m][k]) ----
#pragma unroll
        for (int p = 0; p < 4; p++) {
            int r = ar + p * 32;
            float4 v = *(const float4*)(Ab + (size_t)r * lda + k0 + ak);
            u16x4 u; u.x = f2bf(v.x); u.y = f2bf(v.y); u.z = f2bf(v.z); u.w = f2bf(v.w);
            *(u16x4*)&As[r][ak] = u;
        }
        // ---- stage B -> Bs[n][k] ----
        if (!BKN) {
#pragma unroll
            for (int p = 0; p < 4; p++) {
                int r = ar + p * 32;
                float4 v = *(const float4*)(Bb + (size_t)(n0 + r) * ldb + k0 + ak);
                u16x4 u; u.x = f2bf(v.x); u.y = f2bf(v.y); u.z = f2bf(v.z); u.w = f2bf(v.w);
                *(u16x4*)&Bs[r][ak] = u;
            }
        } else {
#pragma unroll
            for (int p = 0; p < 4; p++) {
                int k = bkr + p * 8;
                float4 v = *(const float4*)(Bb + (size_t)(k0 + k) * ldb + n0 + bnq);
                Bs[bnq + 0][k] = f2bf(v.x);
                Bs[bnq + 1][k] = f2bf(v.y);
                Bs[bnq + 2][k] = f2bf(v.z);
                Bs[bnq + 3][k] = f2bf(v.w);
            }
        }
        __syncthreads();

        s16x8 af[4], bf[4];
#pragma unroll
        for (int t = 0; t < 4; t++) af[t] = *(const s16x8*)&As[wm + t * 16 + mi][quad * 8];
#pragma unroll
        for (int t = 0; t < 4; t++) bf[t] = *(const s16x8*)&Bs[wn + t * 16 + mi][quad * 8];
#pragma unroll
        for (int tm = 0; tm < 4; tm++)
#pragma unroll
            for (int tn = 0; tn < 4; tn++)
                acc[tm][tn] = __builtin_amdgcn_mfma_f32_16x16x32_bf16(af[tm], bf[tn], acc[tm][tn], 0, 0, 0);
        __syncthreads();
    }

    // ---- epilogue ----
#pragma unroll
    for (int tn = 0; tn < 4; tn++) {
        int col = n0 + wn + tn * 16 + mi;
        float bv = bias ? bias[col] : 0.f;
#pragma unroll
        for (int tm = 0; tm < 4; tm++) {
#pragma unroll
            for (int r = 0; r < 4; r++) {
                int row = m0 + wm + tm * 16 + quad * 4 + r;
                float v = acc[tm][tn][r] * alpha + bv;
                if (RELU) v = fmaxf(v, 0.f);
                C[(size_t)z * sCz + (size_t)row * ldc + col] = v;
            }
        }
    }
}

// ---------------------------------------------------------------------------
// Precompute kernels for the collapsed feature-attention block
// consts layout (floats): u@0(384) v@512(384) abcd@1024(16) wv@1088(4*128)
//                         c0@1600(128) g@2048(2048*4) g0@10240(2048)
// ---------------------------------------------------------------------------
__global__ void precomp1(const float* __restrict__ fa_wi, const float* __restrict__ fa_bi,
                         const float* __restrict__ pl1_w, const float* __restrict__ pl1_b,
                         float* __restrict__ consts)
{
    int j = threadIdx.x;   // 384 threads
    if (j < 384) {
        float u = 0.f, v = 0.f;
        for (int k = 0; k < 128; k++) {
            float w = fa_wi[j * 128 + k];
            u = fmaf(w, pl1_w[k], u);
            v = fmaf(w, pl1_b[k], v);
        }
        consts[j]       = u;
        consts[512 + j] = v + fa_bi[j];
    }
}

__global__ void precomp2(const float* __restrict__ fa_wo, const float* __restrict__ fa_bo,
                         float* __restrict__ consts)
{
    int tid = threadIdx.x;  // 128 threads
    const float* u = consts;
    const float* v = consts + 512;
    if (tid < 16) {
        int h = tid >> 2, w = tid & 3;
        const float* ql = (w < 2) ? u : v;          // q side: a,b from u; c,d from v
        const float* kr = ((w & 1) == 0) ? u : v;   // k side: a,c from u; b,d from v
        float acc = 0.f;
        for (int d = 0; d < 32; d++) acc += ql[h * 32 + d] * kr[128 + h * 32 + d];
        consts[1024 + tid] = acc * 0.17677669529663687f;  // 1/sqrt(32)
    }
#pragma unroll
    for (int h = 0; h < 4; h++) {
        float acc = 0.f;
        for (int d = 0; d < 32; d++)
            acc = fmaf(fa_wo[tid * 128 + h * 32 + d], u[256 + h * 32 + d], acc);
        consts[1088 + h * 128 + tid] = acc;
    }
    float c0 = fa_bo[tid];
    for (int idx = 0; idx < 128; idx++)
        c0 = fmaf(fa_wo[tid * 128 + idx], v[256 + idx], c0);
    consts[1600 + tid] = c0;
}

__global__ void precomp3(const float* __restrict__ pl2_w, const float* __restrict__ pl2_b,
                         float* __restrict__ consts)
{
    int m = blockIdx.x * 256 + threadIdx.x;   // 2048
    const float* wv = consts + 1088;
    const float* c0 = consts + 1600;
    float a0 = 0.f, ah0 = 0.f, ah1 = 0.f, ah2 = 0.f, ah3 = 0.f;
    for (int j = 0; j < 128; j++) {
        float w = pl2_w[m * 128 + j];
        ah0 = fmaf(w, wv[0 * 128 + j], ah0);
        ah1 = fmaf(w, wv[1 * 128 + j], ah1);
        ah2 = fmaf(w, wv[2 * 128 + j], ah2);
        ah3 = fmaf(w, wv[3 * 128 + j], ah3);
        a0  = fmaf(w, c0[j], a0);
    }
    consts[2048 + m * 4 + 0] = ah0;
    consts[2048 + m * 4 + 1] = ah1;
    consts[2048 + m * 4 + 2] = ah2;
    consts[2048 + m * 4 + 3] = ah3;
    consts[10240 + m] = a0 + pl2_b[m];
}

// Feature attention: per n, thread f computes t[n,f,h] for h=0..3.
__global__ __launch_bounds__(128)
void feat_attn_kernel(const float* __restrict__ src, const float* __restrict__ consts,
                      float* __restrict__ tout)
{
    const int n = blockIdx.x, f = threadIdx.x;
    __shared__ float sv[128];
    const float si = src[n * 128 + f];
    sv[f] = si;
    __syncthreads();
    float4 tv;
    float* tp = (float*)&tv;
#pragma unroll
    for (int h = 0; h < 4; h++) {
        const float a = consts[1024 + h * 4 + 0];
        const float b = consts[1024 + h * 4 + 1];
        const float c = consts[1024 + h * 4 + 2];
        const float d = consts[1024 + h * 4 + 3];
        const float p = a * si + c;   // coefficient of s_j
        const float q = b * si + d;   // constant
        float mx = -3.4e38f;
        for (int j = 0; j < 128; j++) mx = fmaxf(mx, p * sv[j] + q);
        float l = 0.f, tt = 0.f;
        for (int j = 0; j < 128; j++) {
            float e = __expf(p * sv[j] + q - mx);
            l += e; tt = fmaf(e, sv[j], tt);
        }
        tp[h] = tt / l;
    }
    *(float4*)&tout[(size_t)(n * 128 + f) * 4] = tv;
}

// Fused pl2/pl3 + residual + LayerNorm(pn1) -> src1
__global__ __launch_bounds__(128)
void mlp_ln_kernel(const float* __restrict__ tbuf, const float* __restrict__ consts,
                   const float* __restrict__ src, const float* __restrict__ pl3_w,
                   const float* __restrict__ pl3_b, const float* __restrict__ pn1_g,
                   const float* __restrict__ pn1_b, float* __restrict__ src1)
{
    __shared__ float red[4];
    const int n = blockIdx.x, f = threadIdx.x;
    float4 t4 = *(const float4*)&tbuf[(size_t)(n * 128 + f) * 4];
    const float* g  = consts + 2048;
    const float* g0 = consts + 10240;
    float acc = 0.f;
    for (int m = 0; m < 2048; m++) {
        float4 gm = *(const float4*)&g[m * 4];
        float hm = fmaf(t4.x, gm.x, fmaf(t4.y, gm.y, fmaf(t4.z, gm.z, fmaf(t4.w, gm.w, g0[m]))));
        acc = fmaf(fmaxf(hm, 0.f), pl3_w[m], acc);
    }
    float y = acc + pl3_b[0] + src[n * 128 + f];
    float s  = block_reduce(y, 0, red);
    float ss = block_reduce(y * y, 0, red);
    float mean = s * (1.f / 128.f);
    float var  = ss * (1.f / 128.f) - mean * mean;
    float inv  = rsqrtf(var + 1e-5f);
    src1[n * 128 + f] = (y - mean) * inv * pn1_g[f] + pn1_b[f];
}

// Generic LayerNorm: out = LN(a [+ b]) * g + beta [+ post]
__global__ void ln_kernel(const float* __restrict__ a, const float* __restrict__ b,
                          const float* __restrict__ post, const float* __restrict__ g,
                          const float* __restrict__ beta, float* __restrict__ out, int D)
{
    __shared__ float red[4];
    const size_t row = blockIdx.x;
    const int tid = threadIdx.x;
    const int nit = D / blockDim.x;   // <= 4
    const float* ap = a + row * D;
    const float* bp = b ? b + row * D : nullptr;
    float xr[4];
    float s = 0.f, ss = 0.f;
    for (int i = 0; i < nit; i++) {
        int idx = i * blockDim.x + tid;
        float x = ap[idx] + (bp ? bp[idx] : 0.f);
        xr[i] = x; s += x; ss = fmaf(x, x, ss);
    }
    s  = block_reduce(s, 0, red);
    ss = block_reduce(ss, 0, red);
    float mean = s / D, var = ss / D - mean * mean;
    float inv = rsqrtf(var + 1e-5f);
    const float* pp = post ? post + row * D : nullptr;
    float* op = out + row * D;
    for (int i = 0; i < nit; i++) {
        int idx = i * blockDim.x + tid;
        float v = (xr[i] - mean) * inv * g[idx] + beta[idx];
        if (pp) v += pp[idx];
        op[idx] = v;
    }
}

// Row softmax in place (cols multiple of 256, cols/256 <= 4)
__global__ __launch_bounds__(256)
void softmax_kernel(float* __restrict__ S, int cols)
{
    __shared__ float red[4];
    const size_t row = blockIdx.x;
    float* p = S + row * (size_t)cols;
    const int tid = threadIdx.x;
    const int nit = cols / 256;
    float xr[4];
    float mx = -3.4e38f;
    for (int i = 0; i < nit; i++) { float x = p[i * 256 + tid]; xr[i] = x; mx = fmaxf(mx, x); }
    mx = block_reduce(mx, 1, red);
    float sum = 0.f;
    for (int i = 0; i < nit; i++) { float e = __expf(xr[i] - mx); xr[i] = e; sum += e; }
    sum = block_reduce(sum, 0, red);
    float inv = 1.f / sum;
    for (int i = 0; i < nit; i++) p[i * 256 + tid] = xr[i] * inv;
}

// ---------------------------------------------------------------------------
// Host side
// ---------------------------------------------------------------------------
static inline void gemm_go(hipStream_t s, const float* A, const float* B, const float* bias,
                           float* C, int M, int N, int K, int lda, int ldb, int ldc,
                           long sAz, long sBz, long sCz, int Z, float alpha,
                           bool bkn, bool relu)
{
    dim3 g(M / 128, N / 128, Z), b(256);
    if (bkn) {
        gemm_kernel<true, false><<<g, b, 0, s>>>(A, B, bias, C, M, N, K, lda, ldb, ldc, sAz, sBz, sCz, alpha);
    } else if (relu) {
        gemm_kernel<false, true><<<g, b, 0, s>>>(A, B, bias, C, M, N, K, lda, ldb, ldc, sAz, sBz, sCz, alpha);
    } else {
        gemm_kernel<false, false><<<g, b, 0, s>>>(A, B, bias, C, M, N, K, lda, ldb, ldc, sAz, sBz, sCz, alpha);
    }
}

extern "C" void kernel_launch(void* const* d_in, const int* in_sizes, int n_in,
                              void* d_out, int out_size, void* d_ws, size_t ws_size,
                              hipStream_t stream)
{
    const float* src   = (const float*)d_in[0];
    const float* sa_wi = (const float*)d_in[2];
    const float* sa_bi = (const float*)d_in[3];
    const float* sa_wo = (const float*)d_in[4];
    const float* sa_bo = (const float*)d_in[5];
    const float* fa_wi = (const float*)d_in[6];
    const float* fa_bi = (const float*)d_in[7];
    const float* fa_wo = (const float*)d_in[8];
    const float* fa_bo = (const float*)d_in[9];
    const float* pl1_w = (const float*)d_in[10];
    const float* pl1_b = (const float*)d_in[11];
    const float* pl2_w = (const float*)d_in[12];
    const float* pl2_b = (const float*)d_in[13];
    const float* pl3_w = (const float*)d_in[14];
    const float* pl3_b = (const float*)d_in[15];
    const float* pl4_w = (const float*)d_in[16];
    const float* pl4_b = (const float*)d_in[17];
    const float* pl5_w = (const float*)d_in[18];
    const float* pl5_b = (const float*)d_in[19];
    const float* pl6_w = (const float*)d_in[20];
    const float* pl6_b = (const float*)d_in[21];
    const float* pl7_w = (const float*)d_in[22];
    const float* pl7_b = (const float*)d_in[23];
    const float* l1_w  = (const float*)d_in[24];
    const float* l1_b  = (const float*)d_in[25];
    const float* l2_w  = (const float*)d_in[26];
    const float* l2_b  = (const float*)d_in[27];
    const float* pn1_g = (const float*)d_in[28];
    const float* pn1_b = (const float*)d_in[29];
    const float* pn2_g = (const float*)d_in[30];
    const float* pn2_b = (const float*)d_in[31];
    const float* n1_g  = (const float*)d_in[32];
    const float* n1_b  = (const float*)d_in[33];
    const float* n2_g  = (const float*)d_in[34];
    const float* n2_b  = (const float*)d_in[35];

    float* ws  = (float*)d_ws;
    float* out = (float*)d_out;

    // workspace layout (floats)
    float* CONSTS = ws;                  // 16384
    float* T      = ws + 16384;          // 294912*4   (t; later ff)
    float* SRC1   = ws + 1196032;        // 294912
    float* SRC1_  = ws + 1490944;        // 2304*1024
    float* HBIG   = ws + 3850240;        // 2304*2048  (h / sl_pre / h2 / h3)
    float* QKV    = ws + 8568832;        // 2048*3072  (qkv; later so)
    float* SBUF   = ws + 14860288;       // 8*1024*1024 (scores; later kv2/q2/S2/sr)
    float* OBUF   = ws + 23248896;       // 2048*1024  (attn out / sl2 / sr_attn)
    float* SL     = ws + 25346048;       // 2048*1024
    float* SLP    = ws + 27443200;       // 2048*1024
    // total: 29540352 floats = 118.2 MB

    // ---- collapsed feature-attention block ----
    precomp1<<<1, 384, 0, stream>>>(fa_wi, fa_bi, pl1_w, pl1_b, CONSTS);
    precomp2<<<1, 128, 0, stream>>>(fa_wo, fa_bo, CONSTS);
    precomp3<<<8, 256, 0, stream>>>(pl2_w, pl2_b, CONSTS);
    feat_attn_kernel<<<2304, 128, 0, stream>>>(src, CONSTS, T);
    mlp_ln_kernel<<<2304, 128, 0, stream>>>(T, CONSTS, src, pl3_w, pl3_b, pn1_g, pn1_b, SRC1);

    // ---- src1_ = relu(src1@pl4^T+b)@pl5^T+b ----
    gemm_go(stream, SRC1, pl4_w, pl4_b, HBIG, 2304, 2048, 128, 128, 128, 2048, 0, 0, 0, 1, 1.f, false, true);
    gemm_go(stream, HBIG, pl5_w, pl5_b, SRC1_, 2304, 1024, 2048, 2048, 2048, 1024, 0, 0, 0, 1, 1.f, false, false);

    // ---- self-attention on li = src1_[:1024] (rows 0..2047) ----
    gemm_go(stream, SRC1_, sa_wi, sa_bi, QKV, 2048, 3072, 1024, 1024, 1024, 3072, 0, 0, 0, 1, 1.f, false, false);
    const float iscale = 0.08838834764831845f;   // 1/sqrt(128)
    for (int b = 0; b < 2; b++) {
        gemm_go(stream, QKV + b * 3072, QKV + b * 3072 + 1024, nullptr, SBUF,
                1024, 1024, 128, 6144, 6144, 1024, 128, 128, 1048576, 8, iscale, false, false);
        softmax_kernel<<<8192, 256, 0, stream>>>(SBUF, 1024);
        gemm_go(stream, SBUF, QKV + b * 3072 + 2048, nullptr, OBUF + b * 1024,
                1024, 128, 1024, 1024, 6144, 2048, 1048576, 128, 128, 8, 1.f, true, false);
    }
    gemm_go(stream, OBUF, sa_wo, sa_bo, HBIG, 2048, 1024, 1024, 1024, 1024, 1024, 0, 0, 0, 1, 1.f, false, false);
    ln_kernel<<<2048, 256, 0, stream>>>(HBIG, SRC1_, nullptr, pn2_g, pn2_b, SL, 1024);

    // ---- sl_ = ln(relu(sl@pl6^T)@pl7^T, pn2) + sl ----
    gemm_go(stream, SL, pl6_w, pl6_b, HBIG, 2048, 2048, 1024, 1024, 1024, 2048, 0, 0, 0, 1, 1.f, false, true);
    gemm_go(stream, HBIG, pl7_w, pl7_b, OBUF, 2048, 1024, 2048, 2048, 2048, 1024, 0, 0, 0, 1, 1.f, false, false);
    ln_kernel<<<2048, 256, 0, stream>>>(OBUF, nullptr, SL, pn2_g, pn2_b, SLP, 1024);

    // ---- cross-attention: q from src1_[1024:], k/v from sl_ ----
    float* KV2 = SBUF;
    float* Q2  = SBUF + 4194304;
    float* S2  = SBUF + 4456448;
    gemm_go(stream, SLP, sa_wi + 1024 * 1024, sa_bi + 1024, KV2, 2048, 2048, 1024, 1024, 1024, 2048, 0, 0, 0, 1, 1.f, false, false);
    gemm_go(stream, SRC1_ + 2048 * 1024, sa_wi, sa_bi, Q2, 256, 1024, 1024, 1024, 1024, 1024, 0, 0, 0, 1, 1.f, false, false);
    for (int b = 0; b < 2; b++) {
        gemm_go(stream, Q2 + b * 1024, KV2 + b * 2048, nullptr, S2 + (size_t)b * 1048576,
                128, 1024, 128, 2048, 4096, 1024, 128, 128, 131072, 8, iscale, false, false);
        softmax_kernel<<<1024, 256, 0, stream>>>(S2 + (size_t)b * 1048576, 1024);
        gemm_go(stream, S2 + (size_t)b * 1048576, KV2 + b * 2048 + 1024, nullptr, OBUF + b * 1024,
                128, 128, 1024, 1024, 4096, 2048, 131072, 128, 128, 8, 1.f, true, false);
    }
    float* SR = SBUF;   // kv2 dead by now
    gemm_go(stream, OBUF, sa_wo, sa_bo, SR, 256, 1024, 1024, 1024, 1024, 1024, 0, 0, 0, 1, 1.f, false, false);

    // ---- so = ln(concat(sl, sr) + src1_, n1) ----
    float* SO = QKV;    // qkv dead
    ln_kernel<<<2048, 256, 0, stream>>>(SL, SRC1_, nullptr, n1_g, n1_b, SO, 1024);
    ln_kernel<<<256, 256, 0, stream>>>(SR, SRC1_ + 2048 * 1024, nullptr, n1_g, n1_b, SO + 2048 * 1024, 1024);

    // ---- ff = relu(so@l1^T)@l2^T ; out = ln(src1 + ff, n2) ----
    gemm_go(stream, SO, l1_w, l1_b, HBIG, 2304, 2048, 1024, 1024, 1024, 2048, 0, 0, 0, 1, 1.f, false, true);
    gemm_go(stream, HBIG, l2_w, l2_b, T, 2304, 128, 2048, 2048, 2048, 128, 0, 0, 0, 1, 1.f, false, false);
    ln_kernel<<<2304, 128, 0, stream>>>(T, SRC1, nullptr, n2_g, n2_b, out, 128);
}

// Round 2
// 924.558 us; speedup vs baseline: 2.2401x; 2.2401x over previous
//
#include <hip/hip_runtime.h>

using s16x8 = __attribute__((ext_vector_type(8))) short;   // 8 bf16 (4 VGPRs)
using f32x4 = __attribute__((ext_vector_type(4))) float;   // MFMA accumulator
typedef unsigned short ushort_t;

__device__ __forceinline__ unsigned short f2bf(float f) {
    union { float f; unsigned u; } v; v.f = f;
    unsigned u = v.u + 0x7FFFu + ((v.u >> 16) & 1u);   // round-nearest-even
    return (unsigned short)(u >> 16);
}
__device__ __forceinline__ float bf2f(unsigned short h) {
    union { unsigned u; float f; } v; v.u = ((unsigned)h) << 16;
    return v.f;
}

// block reduction: op==0 sum, op==1 max.
__device__ __forceinline__ float block_reduce(float v, int op, float* lds) {
    const int lane = threadIdx.x & 63;
    const int w    = threadIdx.x >> 6;
    const int nw   = blockDim.x >> 6;
#pragma unroll
    for (int off = 32; off > 0; off >>= 1) {
        float o = __shfl_down(v, off, 64);
        v = op ? fmaxf(v, o) : (v + o);
    }
    __syncthreads();
    if (lane == 0) lds[w] = v;
    __syncthreads();
    float r = lds[0];
    for (int i = 1; i < nw; i++) r = op ? fmaxf(r, lds[i]) : (r + lds[i]);
    return r;
}

__device__ __forceinline__ void load_lds16(const void* g, void* l) {
    __builtin_amdgcn_global_load_lds(
        (const __attribute__((address_space(1))) unsigned int*)g,
        (__attribute__((address_space(3))) unsigned int*)l, 16, 0, 0);
}

// ---------------------------------------------------------------------------
// fp32 -> bf16 weight conversion
// ---------------------------------------------------------------------------
__global__ void cvt_bf16(const float* __restrict__ in, ushort_t* __restrict__ out, int n4)
{
    int i = blockIdx.x * 256 + threadIdx.x;
    if (i < n4) {
        float4 v = *(const float4*)&in[i * 4];
        ushort_t u[4] = { f2bf(v.x), f2bf(v.y), f2bf(v.z), f2bf(v.w) };
        *(uint2*)&out[i * 4] = *(uint2*)u;
    }
}

// ---------------------------------------------------------------------------
// bf16 GEMM (m97 structure): C[z] = act(alpha * A[z] @ B[z]^T + bias)  bf16 out
//   A: M x K bf16, row stride lda
//   BKN=false: B is N x K row-major (W layout)      [C = A @ W^T]
//   BKN=true : B is K x N row-major                 [C = A @ B]  (VALU-staged)
// M%128==0, N%128==0, K%32==0, lda/ldb multiples of 8, pointers 16B-aligned.
// ---------------------------------------------------------------------------
template<bool BKN, bool RELU>
__global__ __launch_bounds__(256, 2)
void gemm_bf16(const ushort_t* __restrict__ A, const ushort_t* __restrict__ B,
               const float* __restrict__ bias, ushort_t* __restrict__ C,
               int M, int N, int K, int lda, int ldb, int ldc,
               long sAz, long sBz, long sCz, float alpha)
{
    __shared__ ushort_t As[128 * 32];
    __shared__ ushort_t Bs[128 * 32];

    const int tid = threadIdx.x;
    const int z   = blockIdx.z;
    const int m0  = blockIdx.x * 128;
    const int n0  = blockIdx.y * 128;

    const ushort_t* Ab = A + (size_t)z * sAz + (size_t)m0 * lda;
    const ushort_t* Bb = B + (size_t)z * sBz;

    const int wave = tid >> 6, lane = tid & 63;
    const int wm = (wave & 1) * 64, wn = (wave >> 1) * 64;
    const int mi = lane & 15, quad = lane >> 4;

    f32x4 acc[4][4];
#pragma unroll
    for (int i = 0; i < 4; i++)
#pragma unroll
        for (int j = 0; j < 4; j++) acc[i][j] = (f32x4)0.f;

    // global_load_lds staging map: chunk n covers row n>>2, cols ((n&3)*8..+8)
    const int r0 = tid >> 2, c0 = (tid & 3) * 8;
    // BKN B staging map
    const int bk = tid >> 3, bn = (tid & 7) * 16;

    for (int k0 = 0; k0 < K; k0 += 32) {
        // ---- stage A via async DMA ----
        load_lds16(Ab + (size_t)r0 * lda + k0 + c0,            &As[tid * 8]);
        load_lds16(Ab + (size_t)(r0 + 64) * lda + k0 + c0,     &As[(tid + 256) * 8]);
        if (!BKN) {
            const ushort_t* Bb2 = Bb + (size_t)n0 * ldb;
            load_lds16(Bb2 + (size_t)r0 * ldb + k0 + c0,        &Bs[tid * 8]);
            load_lds16(Bb2 + (size_t)(r0 + 64) * ldb + k0 + c0, &Bs[(tid + 256) * 8]);
        } else {
#pragma unroll
            for (int c = 0; c < 2; c++) {
                s16x8 v = *(const s16x8*)(Bb + (size_t)(k0 + bk) * ldb + n0 + bn + c * 8);
#pragma unroll
                for (int j = 0; j < 8; j++)
                    Bs[(bn + c * 8 + j) * 32 + bk] = (ushort_t)v[j];
            }
        }
        __syncthreads();

        s16x8 af[4], bfr[4];
#pragma unroll
        for (int t = 0; t < 4; t++)
            af[t] = *(const s16x8*)&As[(wm + t * 16 + mi) * 32 + quad * 8];
#pragma unroll
        for (int t = 0; t < 4; t++)
            bfr[t] = *(const s16x8*)&Bs[(wn + t * 16 + mi) * 32 + quad * 8];
#pragma unroll
        for (int tm = 0; tm < 4; tm++)
#pragma unroll
            for (int tn = 0; tn < 4; tn++)
                acc[tm][tn] = __builtin_amdgcn_mfma_f32_16x16x32_bf16(af[tm], bfr[tn], acc[tm][tn], 0, 0, 0);
        __syncthreads();
    }

    // ---- epilogue: bf16 out ----
#pragma unroll
    for (int tn = 0; tn < 4; tn++) {
        int col = n0 + wn + tn * 16 + mi;
        float bv = bias ? bias[col] : 0.f;
#pragma unroll
        for (int tm = 0; tm < 4; tm++) {
#pragma unroll
            for (int r = 0; r < 4; r++) {
                int row = m0 + wm + tm * 16 + quad * 4 + r;
                float v = acc[tm][tn][r] * alpha + bv;
                if (RELU) v = fmaxf(v, 0.f);
                C[(size_t)z * sCz + (size_t)row * ldc + col] = f2bf(v);
            }
        }
    }
}

// ---------------------------------------------------------------------------
// Collapsed feature-attention precompute (fp32, tiny)
// consts layout (floats): u@0(384) v@512(384) abcd@1024(16) wv@1088(4*128)
//                         c0@1600(128) g@2048(2048*4) g0@10240(2048)
// ---------------------------------------------------------------------------
__global__ void precomp1(const float* __restrict__ fa_wi, const float* __restrict__ fa_bi,
                         const float* __restrict__ pl1_w, const float* __restrict__ pl1_b,
                         float* __restrict__ consts)
{
    int j = threadIdx.x;
    if (j < 384) {
        float u = 0.f, v = 0.f;
        for (int k = 0; k < 128; k++) {
            float w = fa_wi[j * 128 + k];
            u = fmaf(w, pl1_w[k], u);
            v = fmaf(w, pl1_b[k], v);
        }
        consts[j]       = u;
        consts[512 + j] = v + fa_bi[j];
    }
}

__global__ void precomp2(const float* __restrict__ fa_wo, const float* __restrict__ fa_bo,
                         float* __restrict__ consts)
{
    int tid = threadIdx.x;  // 128
    const float* u = consts;
    const float* v = consts + 512;
    if (tid < 16) {
        int h = tid >> 2, w = tid & 3;
        const float* ql = (w < 2) ? u : v;
        const float* kr = ((w & 1) == 0) ? u : v;
        float acc = 0.f;
        for (int d = 0; d < 32; d++) acc += ql[h * 32 + d] * kr[128 + h * 32 + d];
        consts[1024 + tid] = acc * 0.17677669529663687f;
    }
#pragma unroll
    for (int h = 0; h < 4; h++) {
        float acc = 0.f;
        for (int d = 0; d < 32; d++)
            acc = fmaf(fa_wo[tid * 128 + h * 32 + d], u[256 + h * 32 + d], acc);
        consts[1088 + h * 128 + tid] = acc;
    }
    float c0 = fa_bo[tid];
    for (int idx = 0; idx < 128; idx++)
        c0 = fmaf(fa_wo[tid * 128 + idx], v[256 + idx], c0);
    consts[1600 + tid] = c0;
}

__global__ void precomp3(const float* __restrict__ pl2_w, const float* __restrict__ pl2_b,
                         float* __restrict__ consts)
{
    int m = blockIdx.x * 256 + threadIdx.x;   // 2048
    const float* wv = consts + 1088;
    const float* c0 = consts + 1600;
    float a0 = 0.f, ah0 = 0.f, ah1 = 0.f, ah2 = 0.f, ah3 = 0.f;
    for (int j = 0; j < 128; j++) {
        float w = pl2_w[m * 128 + j];
        ah0 = fmaf(w, wv[0 * 128 + j], ah0);
        ah1 = fmaf(w, wv[1 * 128 + j], ah1);
        ah2 = fmaf(w, wv[2 * 128 + j], ah2);
        ah3 = fmaf(w, wv[3 * 128 + j], ah3);
        a0  = fmaf(w, c0[j], a0);
    }
    consts[2048 + m * 4 + 0] = ah0;
    consts[2048 + m * 4 + 1] = ah1;
    consts[2048 + m * 4 + 2] = ah2;
    consts[2048 + m * 4 + 3] = ah3;
    consts[10240 + m] = a0 + pl2_b[m];
}

__global__ __launch_bounds__(128)
void feat_attn_kernel(const float* __restrict__ src, const float* __restrict__ consts,
                      float* __restrict__ tout)
{
    const int n = blockIdx.x, f = threadIdx.x;
    __shared__ float sv[128];
    const float si = src[n * 128 + f];
    sv[f] = si;
    __syncthreads();
    float4 tv;
    float* tp = (float*)&tv;
#pragma unroll
    for (int h = 0; h < 4; h++) {
        const float a = consts[1024 + h * 4 + 0];
        const float b = consts[1024 + h * 4 + 1];
        const float c = consts[1024 + h * 4 + 2];
        const float d = consts[1024 + h * 4 + 3];
        const float p = a * si + c;
        const float q = b * si + d;
        float mx = -3.4e38f;
        for (int j = 0; j < 128; j++) mx = fmaxf(mx, p * sv[j] + q);
        float l = 0.f, tt = 0.f;
        for (int j = 0; j < 128; j++) {
            float e = __expf(p * sv[j] + q - mx);
            l += e; tt = fmaf(e, sv[j], tt);
        }
        tp[h] = tt / l;
    }
    *(float4*)&tout[(size_t)(n * 128 + f) * 4] = tv;
}

// Fused pl2/pl3 + residual + LN(pn1) -> src1 (bf16)
__global__ __launch_bounds__(128)
void mlp_ln_kernel(const float* __restrict__ tbuf, const float* __restrict__ consts,
                   const float* __restrict__ src, const float* __restrict__ pl3_w,
                   const float* __restrict__ pl3_b, const float* __restrict__ pn1_g,
                   const float* __restrict__ pn1_b, ushort_t* __restrict__ src1)
{
    __shared__ float red[4];
    const int n = blockIdx.x, f = threadIdx.x;
    float4 t4 = *(const float4*)&tbuf[(size_t)(n * 128 + f) * 4];
    const float* g  = consts + 2048;
    const float* g0 = consts + 10240;
    float acc = 0.f;
    for (int m = 0; m < 2048; m++) {
        float4 gm = *(const float4*)&g[m * 4];
        float hm = fmaf(t4.x, gm.x, fmaf(t4.y, gm.y, fmaf(t4.z, gm.z, fmaf(t4.w, gm.w, g0[m]))));
        acc = fmaf(fmaxf(hm, 0.f), pl3_w[m], acc);
    }
    float y = acc + pl3_b[0] + src[n * 128 + f];
    float s  = block_reduce(y, 0, red);
    float ss = block_reduce(y * y, 0, red);
    float mean = s * (1.f / 128.f);
    float var  = ss * (1.f / 128.f) - mean * mean;
    float inv  = rsqrtf(var + 1e-5f);
    src1[n * 128 + f] = f2bf((y - mean) * inv * pn1_g[f] + pn1_b[f]);
}

// LN over bf16: out = LN(a [+ b]) * g + beta [+ post];  out bf16 or fp32
template<bool OUTF32>
__global__ void ln_bf16(const ushort_t* __restrict__ a, const ushort_t* __restrict__ b,
                        const ushort_t* __restrict__ post, const float* __restrict__ g,
                        const float* __restrict__ beta, void* __restrict__ out, int D)
{
    __shared__ float red[4];
    const size_t row = blockIdx.x;
    const int tid = threadIdx.x;
    const int nit = D / blockDim.x;   // <= 4
    const ushort_t* ap = a + row * D;
    const ushort_t* bp = b ? b + row * D : nullptr;
    float xr[4];
    float s = 0.f, ss = 0.f;
    for (int i = 0; i < nit; i++) {
        int idx = i * blockDim.x + tid;
        float x = bf2f(ap[idx]) + (bp ? bf2f(bp[idx]) : 0.f);
        xr[i] = x; s += x; ss = fmaf(x, x, ss);
    }
    s  = block_reduce(s, 0, red);
    ss = block_reduce(ss, 0, red);
    float mean = s / D, var = ss / D - mean * mean;
    float inv = rsqrtf(var + 1e-5f);
    const ushort_t* pp = post ? post + row * D : nullptr;
    for (int i = 0; i < nit; i++) {
        int idx = i * blockDim.x + tid;
        float v = (xr[i] - mean) * inv * g[idx] + beta[idx];
        if (pp) v += bf2f(pp[idx]);
        if (OUTF32) ((float*)out)[row * D + idx] = v;
        else        ((ushort_t*)out)[row * D + idx] = f2bf(v);
    }
}

// row softmax in place, bf16, cols == 1024, 256 threads
__global__ __launch_bounds__(256)
void softmax_bf16(ushort_t* __restrict__ S)
{
    __shared__ float red[4];
    const size_t row = blockIdx.x;
    ushort_t* p = S + row * 1024;
    const int tid = threadIdx.x;
    uint2 u = *(const uint2*)&p[tid * 4];
    ushort_t* us = (ushort_t*)&u;
    float xr[4];
    float mx = -3.4e38f;
#pragma unroll
    for (int i = 0; i < 4; i++) { xr[i] = bf2f(us[i]); mx = fmaxf(mx, xr[i]); }
    mx = block_reduce(mx, 1, red);
    float sum = 0.f;
#pragma unroll
    for (int i = 0; i < 4; i++) { xr[i] = __expf(xr[i] - mx); sum += xr[i]; }
    sum = block_reduce(sum, 0, red);
    float inv = 1.f / sum;
#pragma unroll
    for (int i = 0; i < 4; i++) us[i] = f2bf(xr[i] * inv);
    *(uint2*)&p[tid * 4] = u;
}

// ---------------------------------------------------------------------------
// Host side
// ---------------------------------------------------------------------------
static inline void gemm_go(hipStream_t s, const ushort_t* A, const ushort_t* B,
                           const float* bias, ushort_t* C,
                           int M, int N, int K, int lda, int ldb, int ldc,
                           long sAz, long sBz, long sCz, int Z, float alpha,
                           bool bkn, bool relu)
{
    dim3 g(M / 128, N / 128, Z), b(256);
    if (bkn)       gemm_bf16<true,  false><<<g, b, 0, s>>>(A, B, bias, C, M, N, K, lda, ldb, ldc, sAz, sBz, sCz, alpha);
    else if (relu) gemm_bf16<false, true ><<<g, b, 0, s>>>(A, B, bias, C, M, N, K, lda, ldb, ldc, sAz, sBz, sCz, alpha);
    else           gemm_bf16<false, false><<<g, b, 0, s>>>(A, B, bias, C, M, N, K, lda, ldb, ldc, sAz, sBz, sCz, alpha);
}

static inline void cvt_go(hipStream_t s, const float* in, ushort_t* out, int n)
{
    int n4 = n / 4;
    cvt_bf16<<<(n4 + 255) / 256, 256, 0, s>>>(in, out, n4);
}

extern "C" void kernel_launch(void* const* d_in, const int* in_sizes, int n_in,
                              void* d_out, int out_size, void* d_ws, size_t ws_size,
                              hipStream_t stream)
{
    const float* src   = (const float*)d_in[0];
    const float* sa_wi = (const float*)d_in[2];
    const float* sa_bi = (const float*)d_in[3];
    const float* sa_wo = (const float*)d_in[4];
    const float* sa_bo = (const float*)d_in[5];
    const float* fa_wi = (const float*)d_in[6];
    const float* fa_bi = (const float*)d_in[7];
    const float* fa_wo = (const float*)d_in[8];
    const float* fa_bo = (const float*)d_in[9];
    const float* pl1_w = (const float*)d_in[10];
    const float* pl1_b = (const float*)d_in[11];
    const float* pl2_w = (const float*)d_in[12];
    const float* pl2_b = (const float*)d_in[13];
    const float* pl3_w = (const float*)d_in[14];
    const float* pl3_b = (const float*)d_in[15];
    const float* pl4_w = (const float*)d_in[16];
    const float* pl4_b = (const float*)d_in[17];
    const float* pl5_w = (const float*)d_in[18];
    const float* pl5_b = (const float*)d_in[19];
    const float* pl6_w = (const float*)d_in[20];
    const float* pl6_b = (const float*)d_in[21];
    const float* pl7_w = (const float*)d_in[22];
    const float* pl7_b = (const float*)d_in[23];
    const float* l1_w  = (const float*)d_in[24];
    const float* l1_b  = (const float*)d_in[25];
    const float* l2_w  = (const float*)d_in[26];
    const float* l2_b  = (const float*)d_in[27];
    const float* pn1_g = (const float*)d_in[28];
    const float* pn1_b = (const float*)d_in[29];
    const float* pn2_g = (const float*)d_in[30];
    const float* pn2_b = (const float*)d_in[31];
    const float* n1_g  = (const float*)d_in[32];
    const float* n1_b  = (const float*)d_in[33];
    const float* n2_g  = (const float*)d_in[34];
    const float* n2_b  = (const float*)d_in[35];

    float* ws  = (float*)d_ws;
    float* out = (float*)d_out;

    // fp32 region
    float* CONSTS = ws;                  // 16384
    float* T      = ws + 16384;          // 294912*4 (feature-attn t, fp32)
    // bf16 region (byte offset 4784128, 16B aligned)
    ushort_t* wsb = (ushort_t*)(ws + 1196032);
    ushort_t* SAWIb  = wsb + 0;          // 3145728
    ushort_t* SAWOb  = wsb + 3145728;    // 1048576
    ushort_t* PL4b   = wsb + 4194304;    // 262144
    ushort_t* PL5b   = wsb + 4456448;    // 2097152
    ushort_t* PL6b   = wsb + 6553600;    // 2097152
    ushort_t* PL7b   = wsb + 8650752;    // 2097152
    ushort_t* L1b    = wsb + 10747904;   // 2097152
    ushort_t* L2b    = wsb + 12845056;   // 262144
    ushort_t* SRC1b  = wsb + 13107200;   // 294912
    ushort_t* HBIGb  = wsb + 13402112;   // 4718592 (2304x2048)
    ushort_t* SRC1_b = wsb + 18120704;   // 2359296 (2304x1024)
    ushort_t* QKVb   = wsb + 20480000;   // 6291456 (2048x3072)
    ushort_t* SBUFb  = wsb + 26771456;   // 8388608 (scores / cross scratch)
    ushort_t* OBUFb  = wsb + 35160064;   // 2097152
    ushort_t* SLb    = wsb + 37257216;   // 2097152
    ushort_t* SLPb   = wsb + 39354368;   // 2097152
    ushort_t* SOb    = wsb + 41451520;   // 2359296
    ushort_t* FFb    = wsb + 43810816;   // 294912
    // total ~93 MB

    // ---- one-time weight conversion ----
    cvt_go(stream, sa_wi, SAWIb, 3145728);
    cvt_go(stream, sa_wo, SAWOb, 1048576);
    cvt_go(stream, pl4_w, PL4b,  262144);
    cvt_go(stream, pl5_w, PL5b,  2097152);
    cvt_go(stream, pl6_w, PL6b,  2097152);
    cvt_go(stream, pl7_w, PL7b,  2097152);
    cvt_go(stream, l1_w,  L1b,   2097152);
    cvt_go(stream, l2_w,  L2b,   262144);

    // ---- collapsed feature-attention block ----
    precomp1<<<1, 384, 0, stream>>>(fa_wi, fa_bi, pl1_w, pl1_b, CONSTS);
    precomp2<<<1, 128, 0, stream>>>(fa_wo, fa_bo, CONSTS);
    precomp3<<<8, 256, 0, stream>>>(pl2_w, pl2_b, CONSTS);
    feat_attn_kernel<<<2304, 128, 0, stream>>>(src, CONSTS, T);
    mlp_ln_kernel<<<2304, 128, 0, stream>>>(T, CONSTS, src, pl3_w, pl3_b, pn1_g, pn1_b, SRC1b);

    // ---- src1_ = relu(src1@pl4^T+b)@pl5^T+b ----
    gemm_go(stream, SRC1b, PL4b, pl4_b, HBIGb, 2304, 2048, 128, 128, 128, 2048, 0, 0, 0, 1, 1.f, false, true);
    gemm_go(stream, HBIGb, PL5b, pl5_b, SRC1_b, 2304, 1024, 2048, 2048, 2048, 1024, 0, 0, 0, 1, 1.f, false, false);

    // ---- self-attention on li = src1_[:1024] (rows 0..2047) ----
    gemm_go(stream, SRC1_b, SAWIb, sa_bi, QKVb, 2048, 3072, 1024, 1024, 1024, 3072, 0, 0, 0, 1, 1.f, false, false);
    const float iscale = 0.08838834764831845f;   // 1/sqrt(128)
    for (int b = 0; b < 2; b++) {
        gemm_go(stream, QKVb + b * 3072, QKVb + b * 3072 + 1024, nullptr, SBUFb,
                1024, 1024, 128, 6144, 6144, 1024, 128, 128, 1048576, 8, iscale, false, false);
        softmax_bf16<<<8192, 256, 0, stream>>>(SBUFb);
        gemm_go(stream, SBUFb, QKVb + b * 3072 + 2048, nullptr, OBUFb + b * 1024,
                1024, 128, 1024, 1024, 6144, 2048, 1048576, 128, 128, 8, 1.f, true, false);
    }
    gemm_go(stream, OBUFb, SAWOb, sa_bo, HBIGb, 2048, 1024, 1024, 1024, 1024, 1024, 0, 0, 0, 1, 1.f, false, false);
    ln_bf16<false><<<2048, 256, 0, stream>>>(HBIGb, SRC1_b, nullptr, pn2_g, pn2_b, SLb, 1024);

    // ---- sl_ = ln(relu(sl@pl6^T)@pl7^T, pn2) + sl ----
    gemm_go(stream, SLb, PL6b, pl6_b, HBIGb, 2048, 2048, 1024, 1024, 1024, 2048, 0, 0, 0, 1, 1.f, false, true);
    gemm_go(stream, HBIGb, PL7b, pl7_b, OBUFb, 2048, 1024, 2048, 2048, 2048, 1024, 0, 0, 0, 1, 1.f, false, false);
    ln_bf16<false><<<2048, 256, 0, stream>>>(OBUFb, nullptr, SLb, pn2_g, pn2_b, SLPb, 1024);

    // ---- cross-attention: q from src1_[1024:], k/v from sl_ ----
    ushort_t* KV2 = SBUFb;               // 2048x2048 = 4194304
    ushort_t* Q2  = SBUFb + 4194304;     // 256x1024  = 262144
    ushort_t* S2  = SBUFb + 4456448;     // 2x1048576 = 2097152
    ushort_t* SR  = SBUFb + 6553600;     // 256x1024  = 262144
    gemm_go(stream, SLPb, SAWIb + 1024 * 1024, sa_bi + 1024, KV2, 2048, 2048, 1024, 1024, 1024, 2048, 0, 0, 0, 1, 1.f, false, false);
    gemm_go(stream, SRC1_b + 2048 * 1024, SAWIb, sa_bi, Q2, 256, 1024, 1024, 1024, 1024, 1024, 0, 0, 0, 1, 1.f, false, false);
    for (int b = 0; b < 2; b++) {
        gemm_go(stream, Q2 + b * 1024, KV2 + b * 2048, nullptr, S2 + (size_t)b * 1048576,
                128, 1024, 128, 2048, 4096, 1024, 128, 128, 131072, 8, iscale, false, false);
        softmax_bf16<<<1024, 256, 0, stream>>>(S2 + (size_t)b * 1048576);
        gemm_go(stream, S2 + (size_t)b * 1048576, KV2 + b * 2048 + 1024, nullptr, OBUFb + b * 1024,
                128, 128, 1024, 1024, 4096, 2048, 131072, 128, 128, 8, 1.f, true, false);
    }
    gemm_go(stream, OBUFb, SAWOb, sa_bo, SR, 256, 1024, 1024, 1024, 1024, 1024, 0, 0, 0, 1, 1.f, false, false);

    // ---- so = ln(concat(sl, sr) + src1_, n1) ----
    ln_bf16<false><<<2048, 256, 0, stream>>>(SLb, SRC1_b, nullptr, n1_g, n1_b, SOb, 1024);
    ln_bf16<false><<<256, 256, 0, stream>>>(SR, SRC1_b + 2048 * 1024, nullptr, n1_g, n1_b, SOb + 2048 * 1024, 1024);

    // ---- ff = relu(so@l1^T)@l2^T ; out = ln(src1 + ff, n2) ----
    gemm_go(stream, SOb, L1b, l1_b, HBIGb, 2304, 2048, 1024, 1024, 1024, 2048, 0, 0, 0, 1, 1.f, false, true);
    gemm_go(stream, HBIGb, L2b, l2_b, FFb, 2304, 128, 2048, 2048, 2048, 128, 0, 0, 0, 1, 1.f, false, false);
    ln_bf16<true><<<2304, 128, 0, stream>>>(FFb, SRC1b, nullptr, n2_g, n2_b, out, 128);
}

// Round 3
// 716.650 us; speedup vs baseline: 2.8899x; 1.2901x over previous
//
#include <hip/hip_runtime.h>

using s16x8 = __attribute__((ext_vector_type(8))) short;   // 8 bf16 (4 VGPRs)
using f32x4 = __attribute__((ext_vector_type(4))) float;   // MFMA accumulator
typedef unsigned short ushort_t;

__device__ __forceinline__ unsigned short f2bf(float f) {
    union { float f; unsigned u; } v; v.f = f;
    unsigned u = v.u + 0x7FFFu + ((v.u >> 16) & 1u);   // round-nearest-even
    return (unsigned short)(u >> 16);
}
__device__ __forceinline__ float bf2f(unsigned short h) {
    union { unsigned u; float f; } v; v.u = ((unsigned)h) << 16;
    return v.f;
}

// block reduction: op==0 sum, op==1 max.
__device__ __forceinline__ float block_reduce(float v, int op, float* lds) {
    const int lane = threadIdx.x & 63;
    const int w    = threadIdx.x >> 6;
    const int nw   = blockDim.x >> 6;
#pragma unroll
    for (int off = 32; off > 0; off >>= 1) {
        float o = __shfl_down(v, off, 64);
        v = op ? fmaxf(v, o) : (v + o);
    }
    __syncthreads();
    if (lane == 0) lds[w] = v;
    __syncthreads();
    float r = lds[0];
    for (int i = 1; i < nw; i++) r = op ? fmaxf(r, lds[i]) : (r + lds[i]);
    return r;
}

__device__ __forceinline__ void load_lds16(const void* g, void* l) {
    __builtin_amdgcn_global_load_lds(
        (const __attribute__((address_space(1))) unsigned int*)g,
        (__attribute__((address_space(3))) unsigned int*)l, 16, 0, 0);
}

// ---------------------------------------------------------------------------
// fp32 -> bf16 weight conversion, all 8 weights in one dispatch
// ---------------------------------------------------------------------------
struct CvtArgs { const float* src[8]; ushort_t* dst[8]; int end[8]; };

__global__ __launch_bounds__(256)
void cvt_all(CvtArgs a)
{
    int i = blockIdx.x * 256 + threadIdx.x;
    int j = 0;
    while (j < 8 && i >= a.end[j]) j++;
    if (j >= 8) return;
    int li = i - (j ? a.end[j - 1] : 0);
    float4 v = *(const float4*)&a.src[j][(size_t)li * 4];
    ushort_t u[4] = { f2bf(v.x), f2bf(v.y), f2bf(v.z), f2bf(v.w) };
    *(uint2*)&a.dst[j][(size_t)li * 4] = *(uint2*)u;
}

// ---------------------------------------------------------------------------
// bf16 GEMM (m97 structure): C[z] = act(alpha * A[z] @ B[z]^T + bias) bf16 out
//   z1 = z & ((1<<zshift)-1), z2 = z >> zshift; offsets z1*s?z + z2*s?2
//   BKN=false: B is N x K row-major (W layout)      [C = A @ W^T]
//   BKN=true : B is K x N row-major                 [C = A @ B]  (VALU-staged)
// M%128==0, N%128==0, K%32==0, lda/ldb multiples of 8, pointers 16B-aligned.
// ---------------------------------------------------------------------------
template<bool BKN, bool RELU>
__global__ __launch_bounds__(256, 2)
void gemm_bf16(const ushort_t* __restrict__ A, const ushort_t* __restrict__ B,
               const float* __restrict__ bias, ushort_t* __restrict__ C,
               int M, int N, int K, int lda, int ldb, int ldc,
               long sAz, long sBz, long sCz, long sA2, long sB2, long sC2,
               int zshift, float alpha)
{
    __shared__ ushort_t As[128 * 32];
    __shared__ ushort_t Bs[128 * 32];

    const int tid = threadIdx.x;
    const int z   = blockIdx.z;
    const int z1  = z & ((1 << zshift) - 1);
    const int z2  = z >> zshift;
    const int m0  = blockIdx.x * 128;
    const int n0  = blockIdx.y * 128;

    const ushort_t* Ab = A + (size_t)z1 * sAz + (size_t)z2 * sA2 + (size_t)m0 * lda;
    const ushort_t* Bb = B + (size_t)z1 * sBz + (size_t)z2 * sB2;

    const int wave = tid >> 6, lane = tid & 63;
    const int wm = (wave & 1) * 64, wn = (wave >> 1) * 64;
    const int mi = lane & 15, quad = lane >> 4;

    f32x4 acc[4][4];
#pragma unroll
    for (int i = 0; i < 4; i++)
#pragma unroll
        for (int j = 0; j < 4; j++) acc[i][j] = (f32x4)0.f;

    const int r0 = tid >> 2, c0 = (tid & 3) * 8;
    const int bk = tid >> 3, bn = (tid & 7) * 16;

    for (int k0 = 0; k0 < K; k0 += 32) {
        load_lds16(Ab + (size_t)r0 * lda + k0 + c0,            &As[tid * 8]);
        load_lds16(Ab + (size_t)(r0 + 64) * lda + k0 + c0,     &As[(tid + 256) * 8]);
        if (!BKN) {
            const ushort_t* Bb2 = Bb + (size_t)n0 * ldb;
            load_lds16(Bb2 + (size_t)r0 * ldb + k0 + c0,        &Bs[tid * 8]);
            load_lds16(Bb2 + (size_t)(r0 + 64) * ldb + k0 + c0, &Bs[(tid + 256) * 8]);
        } else {
#pragma unroll
            for (int c = 0; c < 2; c++) {
                s16x8 v = *(const s16x8*)(Bb + (size_t)(k0 + bk) * ldb + n0 + bn + c * 8);
#pragma unroll
                for (int j = 0; j < 8; j++)
                    Bs[(bn + c * 8 + j) * 32 + bk] = (ushort_t)v[j];
            }
        }
        __syncthreads();

        s16x8 af[4], bfr[4];
#pragma unroll
        for (int t = 0; t < 4; t++)
            af[t] = *(const s16x8*)&As[(wm + t * 16 + mi) * 32 + quad * 8];
#pragma unroll
        for (int t = 0; t < 4; t++)
            bfr[t] = *(const s16x8*)&Bs[(wn + t * 16 + mi) * 32 + quad * 8];
#pragma unroll
        for (int tm = 0; tm < 4; tm++)
#pragma unroll
            for (int tn = 0; tn < 4; tn++)
                acc[tm][tn] = __builtin_amdgcn_mfma_f32_16x16x32_bf16(af[tm], bfr[tn], acc[tm][tn], 0, 0, 0);
        __syncthreads();
    }

#pragma unroll
    for (int tn = 0; tn < 4; tn++) {
        int col = n0 + wn + tn * 16 + mi;
        float bv = bias ? bias[col] : 0.f;
#pragma unroll
        for (int tm = 0; tm < 4; tm++) {
#pragma unroll
            for (int r = 0; r < 4; r++) {
                int row = m0 + wm + tm * 16 + quad * 4 + r;
                float v = acc[tm][tn][r] * alpha + bv;
                if (RELU) v = fmaxf(v, 0.f);
                C[(size_t)z1 * sCz + (size_t)z2 * sC2 + (size_t)row * ldc + col] = f2bf(v);
            }
        }
    }
}

// ---------------------------------------------------------------------------
// Collapsed feature-attention precompute
// consts layout (floats): u@0(384) v@512(384) abcd@1024(16)
//                         wv@1088(4*128) c0@1600(128)
// Gb: bf16[2048][32] table: cols 0..3 = g[m][h], col 4 = g0[m], 5..31 = 0
// ---------------------------------------------------------------------------
__global__ void precomp1(const float* __restrict__ fa_wi, const float* __restrict__ fa_bi,
                         const float* __restrict__ pl1_w, const float* __restrict__ pl1_b,
                         float* __restrict__ consts)
{
    int j = threadIdx.x;
    if (j < 384) {
        float u = 0.f, v = 0.f;
        for (int k = 0; k < 128; k++) {
            float w = fa_wi[j * 128 + k];
            u = fmaf(w, pl1_w[k], u);
            v = fmaf(w, pl1_b[k], v);
        }
        consts[j]       = u;
        consts[512 + j] = v + fa_bi[j];
    }
}

__global__ void precomp2(const float* __restrict__ fa_wo, const float* __restrict__ fa_bo,
                         float* __restrict__ consts)
{
    int tid = threadIdx.x;  // 128
    const float* u = consts;
    const float* v = consts + 512;
    if (tid < 16) {
        int h = tid >> 2, w = tid & 3;
        const float* ql = (w < 2) ? u : v;
        const float* kr = ((w & 1) == 0) ? u : v;
        float acc = 0.f;
        for (int d = 0; d < 32; d++) acc += ql[h * 32 + d] * kr[128 + h * 32 + d];
        consts[1024 + tid] = acc * 0.17677669529663687f;
    }
#pragma unroll
    for (int h = 0; h < 4; h++) {
        float acc = 0.f;
        for (int d = 0; d < 32; d++)
            acc = fmaf(fa_wo[tid * 128 + h * 32 + d], u[256 + h * 32 + d], acc);
        consts[1088 + h * 128 + tid] = acc;
    }
    float c0 = fa_bo[tid];
    for (int idx = 0; idx < 128; idx++)
        c0 = fmaf(fa_wo[tid * 128 + idx], v[256 + idx], c0);
    consts[1600 + tid] = c0;
}

__global__ void precomp3(const float* __restrict__ pl2_w, const float* __restrict__ pl2_b,
                         const float* __restrict__ consts, ushort_t* __restrict__ Gb)
{
    int m = blockIdx.x * 256 + threadIdx.x;   // 2048
    const float* wv = consts + 1088;
    const float* c0 = consts + 1600;
    float a0 = 0.f, ah[4] = {0.f, 0.f, 0.f, 0.f};
    for (int j = 0; j < 128; j++) {
        float w = pl2_w[m * 128 + j];
        ah[0] = fmaf(w, wv[0 * 128 + j], ah[0]);
        ah[1] = fmaf(w, wv[1 * 128 + j], ah[1]);
        ah[2] = fmaf(w, wv[2 * 128 + j], ah[2]);
        ah[3] = fmaf(w, wv[3 * 128 + j], ah[3]);
        a0    = fmaf(w, c0[j], a0);
    }
    ushort_t* row = Gb + m * 32;
#pragma unroll
    for (int h = 0; h < 4; h++) row[h] = f2bf(ah[h]);
    row[4] = f2bf(a0 + pl2_b[m]);
#pragma unroll
    for (int j = 5; j < 32; j++) row[j] = 0;
}

// ---------------------------------------------------------------------------
// Fused: feature-attention (collapsed) + pl2/pl3 MLP (MFMA) + residual + LN
// One block per token n (0..2303), 256 threads (4 waves).
// ---------------------------------------------------------------------------
__global__ __launch_bounds__(256, 2)
void feat_mlp_ln(const float* __restrict__ src, const float* __restrict__ consts,
                 const ushort_t* __restrict__ Gb, const float* __restrict__ pl3_w,
                 const float* __restrict__ pl3_b, const float* __restrict__ pn1_g,
                 const float* __restrict__ pn1_b, ushort_t* __restrict__ src1)
{
    __shared__ ushort_t As[128 * 32];
    __shared__ ushort_t Bs[128 * 32];
    __shared__ float sv[128];
    __shared__ float ypart[2][128];
    __shared__ float red[4];

    const int n   = blockIdx.x;
    const int tid = threadIdx.x;
    const int f   = tid & 127;
    const int hp  = tid >> 7;          // 0: heads 0,1  1: heads 2,3

    if (tid < 128) sv[f] = src[n * 128 + f];
    __syncthreads();

    // ---- feature attention: t[n,f,h] for this thread's 2 heads ----
    const float si = sv[f];
#pragma unroll
    for (int hh = 0; hh < 2; hh++) {
        const int h = hp * 2 + hh;
        const float a = consts[1024 + h * 4 + 0];
        const float b = consts[1024 + h * 4 + 1];
        const float c = consts[1024 + h * 4 + 2];
        const float d = consts[1024 + h * 4 + 3];
        const float p = a * si + c;
        const float q = b * si + d;
        float mx = -3.4e38f;
        for (int j = 0; j < 128; j++) mx = fmaxf(mx, p * sv[j] + q);
        float l = 0.f, tt = 0.f;
        for (int j = 0; j < 128; j++) {
            float e = __expf(p * sv[j] + q - mx);
            l += e; tt = fmaf(e, sv[j], tt);
        }
        As[f * 32 + h] = f2bf(tt / l);
    }
    if (tid < 128) {
        As[f * 32 + 4] = 0x3F80;   // 1.0 (carries g0)
#pragma unroll
        for (int j = 5; j < 32; j++) As[f * 32 + j] = 0;
    }
    __syncthreads();

    const int wave = tid >> 6, lane = tid & 63;
    const int wm = (wave & 1) * 64, wn = (wave >> 1) * 64;
    const int mi = lane & 15, quad = lane >> 4;

    s16x8 af[4];
#pragma unroll
    for (int t = 0; t < 4; t++)
        af[t] = *(const s16x8*)&As[(wm + t * 16 + mi) * 32 + quad * 8];

    float partial[4][4];
#pragma unroll
    for (int i = 0; i < 4; i++)
#pragma unroll
        for (int j = 0; j < 4; j++) partial[i][j] = 0.f;

    for (int cchunk = 0; cchunk < 16; cchunk++) {
        // stage Gb rows [cchunk*128, +128) (contiguous 8 KB)
        const ushort_t* Gc = Gb + cchunk * 128 * 32;
        load_lds16(Gc + tid * 8,         &Bs[tid * 8]);
        load_lds16(Gc + (tid + 256) * 8, &Bs[(tid + 256) * 8]);
        __syncthreads();

        s16x8 bfr[4];
#pragma unroll
        for (int t = 0; t < 4; t++)
            bfr[t] = *(const s16x8*)&Bs[(wn + t * 16 + mi) * 32 + quad * 8];

        f32x4 acc[4][4];
#pragma unroll
        for (int tm = 0; tm < 4; tm++)
#pragma unroll
            for (int tn = 0; tn < 4; tn++)
                acc[tm][tn] = __builtin_amdgcn_mfma_f32_16x16x32_bf16(af[tm], bfr[tn], (f32x4)0.f, 0, 0, 0);

#pragma unroll
        for (int tn = 0; tn < 4; tn++) {
            int col = cchunk * 128 + wn + tn * 16 + mi;
            float w = pl3_w[col];
#pragma unroll
            for (int tm = 0; tm < 4; tm++)
#pragma unroll
                for (int r = 0; r < 4; r++)
                    partial[tm][r] = fmaf(fmaxf(acc[tm][tn][r], 0.f), w, partial[tm][r]);
        }
        __syncthreads();
    }

    // reduce partials across the 16 mi lanes (same rows)
#pragma unroll
    for (int tm = 0; tm < 4; tm++)
#pragma unroll
        for (int r = 0; r < 4; r++) {
            float v = partial[tm][r];
            v += __shfl_xor(v, 8);
            v += __shfl_xor(v, 4);
            v += __shfl_xor(v, 2);
            v += __shfl_xor(v, 1);
            if (mi == 0) ypart[wave >> 1][wm + tm * 16 + quad * 4 + r] = v;
        }
    __syncthreads();

    float yv = 0.f;
    if (tid < 128)
        yv = ypart[0][f] + ypart[1][f] + pl3_b[0] + sv[f];
    float s  = block_reduce(yv, 0, red);
    float ss = block_reduce(yv * yv, 0, red);
    float mean = s * (1.f / 128.f);
    float var  = ss * (1.f / 128.f) - mean * mean;
    float inv  = rsqrtf(var + 1e-5f);
    if (tid < 128)
        src1[n * 128 + f] = f2bf((yv - mean) * inv * pn1_g[f] + pn1_b[f]);
}

// LN over bf16: out = LN(a [+ b]) * g + beta [+ post];  out bf16 or fp32
template<bool OUTF32>
__global__ void ln_bf16(const ushort_t* __restrict__ a, const ushort_t* __restrict__ b,
                        const ushort_t* __restrict__ post, const float* __restrict__ g,
                        const float* __restrict__ beta, void* __restrict__ out, int D)
{
    __shared__ float red[4];
    const size_t row = blockIdx.x;
    const int tid = threadIdx.x;
    const int nit = D / blockDim.x;   // <= 4
    const ushort_t* ap = a + row * D;
    const ushort_t* bp = b ? b + row * D : nullptr;
    float xr[4];
    float s = 0.f, ss = 0.f;
    for (int i = 0; i < nit; i++) {
        int idx = i * blockDim.x + tid;
        float x = bf2f(ap[idx]) + (bp ? bf2f(bp[idx]) : 0.f);
        xr[i] = x; s += x; ss = fmaf(x, x, ss);
    }
    s  = block_reduce(s, 0, red);
    ss = block_reduce(ss, 0, red);
    float mean = s / D, var = ss / D - mean * mean;
    float inv = rsqrtf(var + 1e-5f);
    const ushort_t* pp = post ? post + row * D : nullptr;
    for (int i = 0; i < nit; i++) {
        int idx = i * blockDim.x + tid;
        float v = (xr[i] - mean) * inv * g[idx] + beta[idx];
        if (pp) v += bf2f(pp[idx]);
        if (OUTF32) ((float*)out)[row * D + idx] = v;
        else        ((ushort_t*)out)[row * D + idx] = f2bf(v);
    }
}

// row softmax in place, bf16, cols == 1024, 256 threads
__global__ __launch_bounds__(256)
void softmax_bf16(ushort_t* __restrict__ S)
{
    __shared__ float red[4];
    const size_t row = blockIdx.x;
    ushort_t* p = S + row * 1024;
    const int tid = threadIdx.x;
    uint2 u = *(const uint2*)&p[tid * 4];
    ushort_t* us = (ushort_t*)&u;
    float xr[4];
    float mx = -3.4e38f;
#pragma unroll
    for (int i = 0; i < 4; i++) { xr[i] = bf2f(us[i]); mx = fmaxf(mx, xr[i]); }
    mx = block_reduce(mx, 1, red);
    float sum = 0.f;
#pragma unroll
    for (int i = 0; i < 4; i++) { xr[i] = __expf(xr[i] - mx); sum += xr[i]; }
    sum = block_reduce(sum, 0, red);
    float inv = 1.f / sum;
#pragma unroll
    for (int i = 0; i < 4; i++) us[i] = f2bf(xr[i] * inv);
    *(uint2*)&p[tid * 4] = u;
}

// ---------------------------------------------------------------------------
// Host side
// ---------------------------------------------------------------------------
static inline void gemm_go(hipStream_t s, const ushort_t* A, const ushort_t* B,
                           const float* bias, ushort_t* C,
                           int M, int N, int K, int lda, int ldb, int ldc,
                           long sAz, long sBz, long sCz, int Z, float alpha,
                           bool bkn, bool relu,
                           long sA2 = 0, long sB2 = 0, long sC2 = 0, int zshift = 0)
{
    dim3 g(M / 128, N / 128, Z), b(256);
    if (bkn)       gemm_bf16<true,  false><<<g, b, 0, s>>>(A, B, bias, C, M, N, K, lda, ldb, ldc, sAz, sBz, sCz, sA2, sB2, sC2, zshift, alpha);
    else if (relu) gemm_bf16<false, true ><<<g, b, 0, s>>>(A, B, bias, C, M, N, K, lda, ldb, ldc, sAz, sBz, sCz, sA2, sB2, sC2, zshift, alpha);
    else           gemm_bf16<false, false><<<g, b, 0, s>>>(A, B, bias, C, M, N, K, lda, ldb, ldc, sAz, sBz, sCz, sA2, sB2, sC2, zshift, alpha);
}

extern "C" void kernel_launch(void* const* d_in, const int* in_sizes, int n_in,
                              void* d_out, int out_size, void* d_ws, size_t ws_size,
                              hipStream_t stream)
{
    const float* src   = (const float*)d_in[0];
    const float* sa_wi = (const float*)d_in[2];
    const float* sa_bi = (const float*)d_in[3];
    const float* sa_wo = (const float*)d_in[4];
    const float* sa_bo = (const float*)d_in[5];
    const float* fa_wi = (const float*)d_in[6];
    const float* fa_bi = (const float*)d_in[7];
    const float* fa_wo = (const float*)d_in[8];
    const float* fa_bo = (const float*)d_in[9];
    const float* pl1_w = (const float*)d_in[10];
    const float* pl1_b = (const float*)d_in[11];
    const float* pl2_w = (const float*)d_in[12];
    const float* pl2_b = (const float*)d_in[13];
    const float* pl3_w = (const float*)d_in[14];
    const float* pl3_b = (const float*)d_in[15];
    const float* pl4_w = (const float*)d_in[16];
    const float* pl4_b = (const float*)d_in[17];
    const float* pl5_w = (const float*)d_in[18];
    const float* pl5_b = (const float*)d_in[19];
    const float* pl6_w = (const float*)d_in[20];
    const float* pl6_b = (const float*)d_in[21];
    const float* pl7_w = (const float*)d_in[22];
    const float* pl7_b = (const float*)d_in[23];
    const float* l1_w  = (const float*)d_in[24];
    const float* l1_b  = (const float*)d_in[25];
    const float* l2_w  = (const float*)d_in[26];
    const float* l2_b  = (const float*)d_in[27];
    const float* pn1_g = (const float*)d_in[28];
    const float* pn1_b = (const float*)d_in[29];
    const float* pn2_g = (const float*)d_in[30];
    const float* pn2_b = (const float*)d_in[31];
    const float* n1_g  = (const float*)d_in[32];
    const float* n1_b  = (const float*)d_in[33];
    const float* n2_g  = (const float*)d_in[34];
    const float* n2_b  = (const float*)d_in[35];

    float* ws  = (float*)d_ws;
    float* out = (float*)d_out;

    float* CONSTS = ws;                   // 16384 floats
    ushort_t* wsb = (ushort_t*)(ws + 16384);
    ushort_t* SAWIb  = wsb + 0;           // 3145728
    ushort_t* SAWOb  = wsb + 3145728;     // 1048576
    ushort_t* PL4b   = wsb + 4194304;     // 262144
    ushort_t* PL5b   = wsb + 4456448;     // 2097152
    ushort_t* PL6b   = wsb + 6553600;     // 2097152
    ushort_t* PL7b   = wsb + 8650752;     // 2097152
    ushort_t* L1b    = wsb + 10747904;    // 2097152
    ushort_t* L2b    = wsb + 12845056;    // 262144
    ushort_t* Gbb    = wsb + 13107200;    // 65536
    ushort_t* SRC1b  = wsb + 13172736;    // 294912
    ushort_t* HBIGb  = wsb + 13467648;    // 4718592 (2304x2048)
    ushort_t* SRC1_b = wsb + 18186240;    // 2359296 (2304x1024)
    ushort_t* QKVb   = wsb + 20545536;    // 6291456 (2048x3072)
    ushort_t* SBUFb  = wsb + 26836992;    // 16777216 (scores; later cross scratch)
    ushort_t* OBUFb  = wsb + 43614208;    // 2097152
    ushort_t* SLb    = wsb + 45711360;    // 2097152
    ushort_t* SLPb   = wsb + 47808512;    // 2097152
    ushort_t* SOb    = wsb + 49905664;    // 2359296
    ushort_t* FFb    = wsb + 52264960;    // 294912
    // total ~105 MB

    // ---- one-time weight conversion (single dispatch) ----
    {
        CvtArgs a;
        const float* srcs[8] = { sa_wi, sa_wo, pl4_w, pl5_w, pl6_w, pl7_w, l1_w, l2_w };
        ushort_t*    dsts[8] = { SAWIb, SAWOb, PL4b, PL5b, PL6b, PL7b, L1b, L2b };
        int          ns[8]   = { 3145728, 1048576, 262144, 2097152, 2097152, 2097152, 2097152, 262144 };
        int cum = 0;
        for (int i = 0; i < 8; i++) { a.src[i] = srcs[i]; a.dst[i] = dsts[i]; cum += ns[i] / 4; a.end[i] = cum; }
        cvt_all<<<(cum + 255) / 256, 256, 0, stream>>>(a);
    }

    // ---- collapsed feature-attention block ----
    precomp1<<<1, 384, 0, stream>>>(fa_wi, fa_bi, pl1_w, pl1_b, CONSTS);
    precomp2<<<1, 128, 0, stream>>>(fa_wo, fa_bo, CONSTS);
    precomp3<<<8, 256, 0, stream>>>(pl2_w, pl2_b, CONSTS, Gbb);
    feat_mlp_ln<<<2304, 256, 0, stream>>>(src, CONSTS, Gbb, pl3_w, pl3_b, pn1_g, pn1_b, SRC1b);

    // ---- src1_ = relu(src1@pl4^T+b)@pl5^T+b ----
    gemm_go(stream, SRC1b, PL4b, pl4_b, HBIGb, 2304, 2048, 128, 128, 128, 2048, 0, 0, 0, 1, 1.f, false, true);
    gemm_go(stream, HBIGb, PL5b, pl5_b, SRC1_b, 2304, 1024, 2048, 2048, 2048, 1024, 0, 0, 0, 1, 1.f, false, false);

    // ---- self-attention on li = src1_[:1024] (rows 0..2047), z = h + 8*b ----
    gemm_go(stream, SRC1_b, SAWIb, sa_bi, QKVb, 2048, 3072, 1024, 1024, 1024, 3072, 0, 0, 0, 1, 1.f, false, false);
    const float iscale = 0.08838834764831845f;   // 1/sqrt(128)
    gemm_go(stream, QKVb, QKVb + 1024, nullptr, SBUFb,
            1024, 1024, 128, 6144, 6144, 1024, 128, 128, 1048576, 16, iscale, false, false,
            3072, 3072, 8388608, 3);
    softmax_bf16<<<16384, 256, 0, stream>>>(SBUFb);
    gemm_go(stream, SBUFb, QKVb + 2048, nullptr, OBUFb,
            1024, 128, 1024, 1024, 6144, 2048, 1048576, 128, 128, 16, 1.f, true, false,
            8388608, 3072, 1024, 3);
    gemm_go(stream, OBUFb, SAWOb, sa_bo, HBIGb, 2048, 1024, 1024, 1024, 1024, 1024, 0, 0, 0, 1, 1.f, false, false);
    ln_bf16<false><<<2048, 256, 0, stream>>>(HBIGb, SRC1_b, nullptr, pn2_g, pn2_b, SLb, 1024);

    // ---- sl_ = ln(relu(sl@pl6^T)@pl7^T, pn2) + sl ----
    gemm_go(stream, SLb, PL6b, pl6_b, HBIGb, 2048, 2048, 1024, 1024, 1024, 2048, 0, 0, 0, 1, 1.f, false, true);
    gemm_go(stream, HBIGb, PL7b, pl7_b, OBUFb, 2048, 1024, 2048, 2048, 2048, 1024, 0, 0, 0, 1, 1.f, false, false);
    ln_bf16<false><<<2048, 256, 0, stream>>>(OBUFb, nullptr, SLb, pn2_g, pn2_b, SLPb, 1024);

    // ---- cross-attention: q from src1_[1024:], k/v from sl_ ----
    ushort_t* KV2 = SBUFb;               // 2048x2048
    ushort_t* Q2  = SBUFb + 4194304;     // 256x1024
    ushort_t* S2  = SBUFb + 4456448;     // 2x8x128x1024
    ushort_t* SR  = SBUFb + 6553600;     // 256x1024
    gemm_go(stream, SLPb, SAWIb + 1024 * 1024, sa_bi + 1024, KV2, 2048, 2048, 1024, 1024, 1024, 2048, 0, 0, 0, 1, 1.f, false, false);
    gemm_go(stream, SRC1_b + 2048 * 1024, SAWIb, sa_bi, Q2, 256, 1024, 1024, 1024, 1024, 1024, 0, 0, 0, 1, 1.f, false, false);
    gemm_go(stream, Q2, KV2, nullptr, S2,
            128, 1024, 128, 2048, 4096, 1024, 128, 128, 131072, 16, iscale, false, false,
            1024, 2048, 1048576, 3);
    softmax_bf16<<<2048, 256, 0, stream>>>(S2);
    gemm_go(stream, S2, KV2 + 1024, nullptr, OBUFb,
            128, 128, 1024, 1024, 4096, 2048, 131072, 128, 128, 16, 1.f, true, false,
            1048576, 2048, 1024, 3);
    gemm_go(stream, OBUFb, SAWOb, sa_bo, SR, 256, 1024, 1024, 1024, 1024, 1024, 0, 0, 0, 1, 1.f, false, false);

    // ---- so = ln(concat(sl, sr) + src1_, n1) ----
    ln_bf16<false><<<2048, 256, 0, stream>>>(SLb, SRC1_b, nullptr, n1_g, n1_b, SOb, 1024);
    ln_bf16<false><<<256, 256, 0, stream>>>(SR, SRC1_b + 2048 * 1024, nullptr, n1_g, n1_b, SOb + 2048 * 1024, 1024);

    // ---- ff = relu(so@l1^T)@l2^T ; out = ln(src1 + ff, n2) ----
    gemm_go(stream, SOb, L1b, l1_b, HBIGb, 2304, 2048, 1024, 1024, 1024, 2048, 0, 0, 0, 1, 1.f, false, true);
    gemm_go(stream, HBIGb, L2b, l2_b, FFb, 2304, 128, 2048, 2048, 2048, 128, 0, 0, 0, 1, 1.f, false, false);
    ln_bf16<true><<<2304, 128, 0, stream>>>(FFb, SRC1b, nullptr, n2_g, n2_b, out, 128);
}

// Round 4
// 691.531 us; speedup vs baseline: 2.9949x; 1.0363x over previous
//
#include <hip/hip_runtime.h>

using s16x8 = __attribute__((ext_vector_type(8))) short;   // 8 bf16 (4 VGPRs)
using f32x4 = __attribute__((ext_vector_type(4))) float;   // MFMA accumulator
typedef unsigned short ushort_t;

__device__ __forceinline__ unsigned short f2bf(float f) {
    union { float f; unsigned u; } v; v.f = f;
    unsigned u = v.u + 0x7FFFu + ((v.u >> 16) & 1u);   // round-nearest-even
    return (unsigned short)(u >> 16);
}
__device__ __forceinline__ float bf2f(unsigned short h) {
    union { unsigned u; float f; } v; v.u = ((unsigned)h) << 16;
    return v.f;
}

// block reduction: op==0 sum, op==1 max.
__device__ __forceinline__ float block_reduce(float v, int op, float* lds) {
    const int lane = threadIdx.x & 63;
    const int w    = threadIdx.x >> 6;
    const int nw   = blockDim.x >> 6;
#pragma unroll
    for (int off = 32; off > 0; off >>= 1) {
        float o = __shfl_down(v, off, 64);
        v = op ? fmaxf(v, o) : (v + o);
    }
    __syncthreads();
    if (lane == 0) lds[w] = v;
    __syncthreads();
    float r = lds[0];
    for (int i = 1; i < nw; i++) r = op ? fmaxf(r, lds[i]) : (r + lds[i]);
    return r;
}

__device__ __forceinline__ void load_lds16(const void* g, void* l) {
    __builtin_amdgcn_global_load_lds(
        (const __attribute__((address_space(1))) unsigned int*)g,
        (__attribute__((address_space(3))) unsigned int*)l, 16, 0, 0);
}

// ---------------------------------------------------------------------------
// fp32 -> bf16 weight conversion, all 8 weights in one dispatch
// ---------------------------------------------------------------------------
struct CvtArgs { const float* src[8]; ushort_t* dst[8]; int end[8]; };

__global__ __launch_bounds__(256)
void cvt_all(CvtArgs a)
{
    int i = blockIdx.x * 256 + threadIdx.x;
    int j = 0;
    while (j < 8 && i >= a.end[j]) j++;
    if (j >= 8) return;
    int li = i - (j ? a.end[j - 1] : 0);
    float4 v = *(const float4*)&a.src[j][(size_t)li * 4];
    ushort_t u[4] = { f2bf(v.x), f2bf(v.y), f2bf(v.z), f2bf(v.w) };
    *(uint2*)&a.dst[j][(size_t)li * 4] = *(uint2*)u;
}

// ---------------------------------------------------------------------------
// bf16 GEMM, BK=64 K-loop: C[z] = act(alpha * A[z] @ B[z]^T + bias) bf16 out
//   z1 = z & ((1<<zshift)-1), z2 = z >> zshift; offsets z1*s?z + z2*s?2
//   BKN=false: B is N x K row-major (W layout)      [C = A @ W^T]
//   BKN=true : B is K x N row-major                 [C = A @ B]  (VALU-staged)
// M%128==0, N%128==0, K%64==0, lda/ldb multiples of 8, pointers 16B-aligned.
// ---------------------------------------------------------------------------
template<bool BKN, bool RELU>
__global__ __launch_bounds__(256, 2)
void gemm_bf16(const ushort_t* __restrict__ A, const ushort_t* __restrict__ B,
               const float* __restrict__ bias, ushort_t* __restrict__ C,
               int M, int N, int K, int lda, int ldb, int ldc,
               long sAz, long sBz, long sCz, long sA2, long sB2, long sC2,
               int zshift, float alpha)
{
    __shared__ ushort_t As[128 * 64];
    __shared__ ushort_t Bs[128 * 64];

    const int tid = threadIdx.x;
    const int z   = blockIdx.z;
    const int z1  = z & ((1 << zshift) - 1);
    const int z2  = z >> zshift;
    const int m0  = blockIdx.x * 128;
    const int n0  = blockIdx.y * 128;

    const ushort_t* Ab = A + (size_t)z1 * sAz + (size_t)z2 * sA2 + (size_t)m0 * lda;
    const ushort_t* Bb = B + (size_t)z1 * sBz + (size_t)z2 * sB2;

    const int wave = tid >> 6, lane = tid & 63;
    const int wm = (wave & 1) * 64, wn = (wave >> 1) * 64;
    const int mi = lane & 15, quad = lane >> 4;

    f32x4 acc[4][4];
#pragma unroll
    for (int i = 0; i < 4; i++)
#pragma unroll
        for (int j = 0; j < 4; j++) acc[i][j] = (f32x4)0.f;

    // staging map: 16B chunk c -> row c>>3, colgroup c&7 (64-wide rows)
    const int sr = tid >> 3, sc = (tid & 7) * 8;
    // BKN B staging map: 64 k-rows x 128 n
    const int bk = tid >> 2, bn0 = (tid & 3) * 32;

    for (int k0 = 0; k0 < K; k0 += 64) {
#pragma unroll
        for (int p = 0; p < 4; p++)
            load_lds16(Ab + (size_t)(sr + p * 32) * lda + k0 + sc, &As[(sr + p * 32) * 64 + sc]);
        if (!BKN) {
            const ushort_t* Bb2 = Bb + (size_t)n0 * ldb;
#pragma unroll
            for (int p = 0; p < 4; p++)
                load_lds16(Bb2 + (size_t)(sr + p * 32) * ldb + k0 + sc, &Bs[(sr + p * 32) * 64 + sc]);
        } else {
#pragma unroll
            for (int c = 0; c < 4; c++) {
                s16x8 v = *(const s16x8*)(Bb + (size_t)(k0 + bk) * ldb + n0 + bn0 + c * 8);
#pragma unroll
                for (int j = 0; j < 8; j++)
                    Bs[(bn0 + c * 8 + j) * 64 + bk] = (ushort_t)v[j];
            }
        }
        __syncthreads();

#pragma unroll
        for (int sub = 0; sub < 2; sub++) {
            s16x8 af[4], bfr[4];
#pragma unroll
            for (int t = 0; t < 4; t++)
                af[t] = *(const s16x8*)&As[(wm + t * 16 + mi) * 64 + sub * 32 + quad * 8];
#pragma unroll
            for (int t = 0; t < 4; t++)
                bfr[t] = *(const s16x8*)&Bs[(wn + t * 16 + mi) * 64 + sub * 32 + quad * 8];
#pragma unroll
            for (int tm = 0; tm < 4; tm++)
#pragma unroll
                for (int tn = 0; tn < 4; tn++)
                    acc[tm][tn] = __builtin_amdgcn_mfma_f32_16x16x32_bf16(af[tm], bfr[tn], acc[tm][tn], 0, 0, 0);
        }
        __syncthreads();
    }

#pragma unroll
    for (int tn = 0; tn < 4; tn++) {
        int col = n0 + wn + tn * 16 + mi;
        float bv = bias ? bias[col] : 0.f;
#pragma unroll
        for (int tm = 0; tm < 4; tm++) {
#pragma unroll
            for (int r = 0; r < 4; r++) {
                int row = m0 + wm + tm * 16 + quad * 4 + r;
                float v = acc[tm][tn][r] * alpha + bv;
                if (RELU) v = fmaxf(v, 0.f);
                C[(size_t)z1 * sCz + (size_t)z2 * sC2 + (size_t)row * ldc + col] = f2bf(v);
            }
        }
    }
}

// ---------------------------------------------------------------------------
// Collapsed feature-attention precompute
// consts layout (floats): u@0(384) v@512(384) abcd@1024(16)
//                         wv@1088(4*128) c0@1600(128)
// Gb: bf16[2048][32]: cols 0..3 = g[m][h], col 4 = g0[m], 5..31 = 0
// ---------------------------------------------------------------------------
__global__ void precomp1(const float* __restrict__ fa_wi, const float* __restrict__ fa_bi,
                         const float* __restrict__ pl1_w, const float* __restrict__ pl1_b,
                         float* __restrict__ consts)
{
    int j = threadIdx.x;
    if (j < 384) {
        float u = 0.f, v = 0.f;
        for (int k = 0; k < 128; k++) {
            float w = fa_wi[j * 128 + k];
            u = fmaf(w, pl1_w[k], u);
            v = fmaf(w, pl1_b[k], v);
        }
        consts[j]       = u;
        consts[512 + j] = v + fa_bi[j];
    }
}

__global__ void precomp2(const float* __restrict__ fa_wo, const float* __restrict__ fa_bo,
                         float* __restrict__ consts)
{
    int tid = threadIdx.x;  // 128
    const float* u = consts;
    const float* v = consts + 512;
    if (tid < 16) {
        int h = tid >> 2, w = tid & 3;
        const float* ql = (w < 2) ? u : v;
        const float* kr = ((w & 1) == 0) ? u : v;
        float acc = 0.f;
        for (int d = 0; d < 32; d++) acc += ql[h * 32 + d] * kr[128 + h * 32 + d];
        consts[1024 + tid] = acc * 0.17677669529663687f;
    }
#pragma unroll
    for (int h = 0; h < 4; h++) {
        float acc = 0.f;
        for (int d = 0; d < 32; d++)
            acc = fmaf(fa_wo[tid * 128 + h * 32 + d], u[256 + h * 32 + d], acc);
        consts[1088 + h * 128 + tid] = acc;
    }
    float c0 = fa_bo[tid];
    for (int idx = 0; idx < 128; idx++)
        c0 = fmaf(fa_wo[tid * 128 + idx], v[256 + idx], c0);
    consts[1600 + tid] = c0;
}

__global__ void precomp3(const float* __restrict__ pl2_w, const float* __restrict__ pl2_b,
                         const float* __restrict__ consts, ushort_t* __restrict__ Gb)
{
    int m = blockIdx.x * 256 + threadIdx.x;   // 2048
    const float* wv = consts + 1088;
    const float* c0 = consts + 1600;
    float a0 = 0.f, ah[4] = {0.f, 0.f, 0.f, 0.f};
    for (int j = 0; j < 128; j++) {
        float w = pl2_w[m * 128 + j];
        ah[0] = fmaf(w, wv[0 * 128 + j], ah[0]);
        ah[1] = fmaf(w, wv[1 * 128 + j], ah[1]);
        ah[2] = fmaf(w, wv[2 * 128 + j], ah[2]);
        ah[3] = fmaf(w, wv[3 * 128 + j], ah[3]);
        a0    = fmaf(w, c0[j], a0);
    }
    ushort_t* row = Gb + m * 32;
#pragma unroll
    for (int h = 0; h < 4; h++) row[h] = f2bf(ah[h]);
    row[4] = f2bf(a0 + pl2_b[m]);
#pragma unroll
    for (int j = 5; j < 32; j++) row[j] = 0;
}

// ---------------------------------------------------------------------------
// Fused: feature-attention (collapsed, q-cancelled) + pl2/pl3 MLP (MFMA) + LN
// One block per token n (0..2303), 256 threads (4 waves).
// ---------------------------------------------------------------------------
__global__ __launch_bounds__(256, 2)
void feat_mlp_ln(const float* __restrict__ src, const float* __restrict__ consts,
                 const ushort_t* __restrict__ Gb, const float* __restrict__ pl3_w,
                 const float* __restrict__ pl3_b, const float* __restrict__ pn1_g,
                 const float* __restrict__ pn1_b, ushort_t* __restrict__ src1)
{
    __shared__ ushort_t As[128 * 32];
    __shared__ ushort_t Bs[256 * 32];
    __shared__ float w_lds[2048];
    __shared__ float sv[128];
    __shared__ float ypart[2][128];
    __shared__ float red[4];

    const int n   = blockIdx.x;
    const int tid = threadIdx.x;
    const int f   = tid & 127;
    const int hp  = tid >> 7;          // 0: heads 0,1  1: heads 2,3

    // stage pl3_w into LDS (async; visible after the next __syncthreads)
    load_lds16(pl3_w + tid * 4,         &w_lds[tid * 4]);
    load_lds16(pl3_w + (tid + 256) * 4, &w_lds[(tid + 256) * 4]);

    if (tid < 128) sv[f] = src[n * 128 + f];
    __syncthreads();

    // block max/min of s (for exp stabilization: max_j p*s_j = max(p*smax, p*smin))
    float sval = (tid < 128) ? sv[f] : -3.4e38f;
    float smax = block_reduce(sval, 1, red);
    __syncthreads();
    sval = (tid < 128) ? -sv[f] : -3.4e38f;
    float smin = -block_reduce(sval, 1, red);
    __syncthreads();

    // ---- feature attention: t depends only on p = a*s_i + c (q cancels) ----
    const float si = sv[f];
#pragma unroll
    for (int hh = 0; hh < 2; hh++) {
        const int h = hp * 2 + hh;
        const float a = consts[1024 + h * 4 + 0];
        const float c = consts[1024 + h * 4 + 2];
        const float p = a * si + c;
        const float m = fmaxf(p * smax, p * smin);
        float l = 0.f, tt = 0.f;
        for (int j = 0; j < 128; j++) {
            float e = __expf(fmaf(p, sv[j], -m));
            l += e; tt = fmaf(e, sv[j], tt);
        }
        As[f * 32 + h] = f2bf(tt / l);
    }
    if (tid < 128) {
        As[f * 32 + 4] = 0x3F80;   // 1.0 (carries g0)
#pragma unroll
        for (int j = 5; j < 32; j++) As[f * 32 + j] = 0;
    }
    __syncthreads();

    const int wave = tid >> 6, lane = tid & 63;
    const int wm = (wave & 1) * 64, wn = (wave >> 1) * 64;
    const int mi = lane & 15, quad = lane >> 4;

    s16x8 af[4];
#pragma unroll
    for (int t = 0; t < 4; t++)
        af[t] = *(const s16x8*)&As[(wm + t * 16 + mi) * 32 + quad * 8];

    float partial[4][4];
#pragma unroll
    for (int i = 0; i < 4; i++)
#pragma unroll
        for (int j = 0; j < 4; j++) partial[i][j] = 0.f;

    for (int cchunk = 0; cchunk < 8; cchunk++) {
        // stage Gb rows [cchunk*256, +256) = 16 KB contiguous
        const ushort_t* Gc = Gb + cchunk * 256 * 32;
#pragma unroll
        for (int p = 0; p < 4; p++)
            load_lds16(Gc + (tid + p * 256) * 8, &Bs[(tid + p * 256) * 8]);
        __syncthreads();

#pragma unroll
        for (int sub = 0; sub < 2; sub++) {
            s16x8 bfr[4];
#pragma unroll
            for (int t = 0; t < 4; t++)
                bfr[t] = *(const s16x8*)&Bs[(sub * 128 + wn + t * 16 + mi) * 32 + quad * 8];

            f32x4 acc[4][4];
#pragma unroll
            for (int tm = 0; tm < 4; tm++)
#pragma unroll
                for (int tn = 0; tn < 4; tn++)
                    acc[tm][tn] = __builtin_amdgcn_mfma_f32_16x16x32_bf16(af[tm], bfr[tn], (f32x4)0.f, 0, 0, 0);

#pragma unroll
            for (int tn = 0; tn < 4; tn++) {
                float w = w_lds[cchunk * 256 + sub * 128 + wn + tn * 16 + mi];
#pragma unroll
                for (int tm = 0; tm < 4; tm++)
#pragma unroll
                    for (int r = 0; r < 4; r++)
                        partial[tm][r] = fmaf(fmaxf(acc[tm][tn][r], 0.f), w, partial[tm][r]);
            }
        }
        __syncthreads();
    }

    // reduce partials across the 16 mi lanes (same rows)
#pragma unroll
    for (int tm = 0; tm < 4; tm++)
#pragma unroll
        for (int r = 0; r < 4; r++) {
            float v = partial[tm][r];
            v += __shfl_xor(v, 8);
            v += __shfl_xor(v, 4);
            v += __shfl_xor(v, 2);
            v += __shfl_xor(v, 1);
            if (mi == 0) ypart[wave >> 1][wm + tm * 16 + quad * 4 + r] = v;
        }
    __syncthreads();

    float yv = 0.f;
    if (tid < 128)
        yv = ypart[0][f] + ypart[1][f] + pl3_b[0] + sv[f];
    float s  = block_reduce(yv, 0, red);
    float ss = block_reduce(yv * yv, 0, red);
    float mean = s * (1.f / 128.f);
    float var  = ss * (1.f / 128.f) - mean * mean;
    float inv  = rsqrtf(var + 1e-5f);
    if (tid < 128)
        src1[n * 128 + f] = f2bf((yv - mean) * inv * pn1_g[f] + pn1_b[f]);
}

// LN over bf16: out = LN(a [+ b]) * g + beta [+ post];  out bf16 or fp32
template<bool OUTF32>
__global__ void ln_bf16(const ushort_t* __restrict__ a, const ushort_t* __restrict__ b,
                        const ushort_t* __restrict__ post, const float* __restrict__ g,
                        const float* __restrict__ beta, void* __restrict__ out, int D)
{
    __shared__ float red[4];
    const size_t row = blockIdx.x;
    const int tid = threadIdx.x;
    const int nit = D / blockDim.x;   // <= 4
    const ushort_t* ap = a + row * D;
    const ushort_t* bp = b ? b + row * D : nullptr;
    float xr[4];
    float s = 0.f, ss = 0.f;
    for (int i = 0; i < nit; i++) {
        int idx = i * blockDim.x + tid;
        float x = bf2f(ap[idx]) + (bp ? bf2f(bp[idx]) : 0.f);
        xr[i] = x; s += x; ss = fmaf(x, x, ss);
    }
    s  = block_reduce(s, 0, red);
    ss = block_reduce(ss, 0, red);
    float mean = s / D, var = ss / D - mean * mean;
    float inv = rsqrtf(var + 1e-5f);
    const ushort_t* pp = post ? post + row * D : nullptr;
    for (int i = 0; i < nit; i++) {
        int idx = i * blockDim.x + tid;
        float v = (xr[i] - mean) * inv * g[idx] + beta[idx];
        if (pp) v += bf2f(pp[idx]);
        if (OUTF32) ((float*)out)[row * D + idx] = v;
        else        ((ushort_t*)out)[row * D + idx] = f2bf(v);
    }
}

// LN over concat(a1[0:split], a2[split:]) + b  -> out (bf16), D=1024
__global__ void ln_cat(const ushort_t* __restrict__ a1, const ushort_t* __restrict__ a2,
                       int split, const ushort_t* __restrict__ b,
                       const float* __restrict__ g, const float* __restrict__ beta,
                       ushort_t* __restrict__ out, int D)
{
    __shared__ float red[4];
    const int row = blockIdx.x;
    const int tid = threadIdx.x;
    const int nit = D / blockDim.x;
    const ushort_t* ap = (row < split) ? a1 + (size_t)row * D : a2 + (size_t)(row - split) * D;
    const ushort_t* bp = b + (size_t)row * D;
    float xr[4];
    float s = 0.f, ss = 0.f;
    for (int i = 0; i < nit; i++) {
        int idx = i * blockDim.x + tid;
        float x = bf2f(ap[idx]) + bf2f(bp[idx]);
        xr[i] = x; s += x; ss = fmaf(x, x, ss);
    }
    s  = block_reduce(s, 0, red);
    ss = block_reduce(ss, 0, red);
    float mean = s / D, var = ss / D - mean * mean;
    float inv = rsqrtf(var + 1e-5f);
    for (int i = 0; i < nit; i++) {
        int idx = i * blockDim.x + tid;
        out[(size_t)row * D + idx] = f2bf((xr[i] - mean) * inv * g[idx] + beta[idx]);
    }
}

// row softmax in place, bf16, cols == 1024, 256 threads
__global__ __launch_bounds__(256)
void softmax_bf16(ushort_t* __restrict__ S)
{
    __shared__ float red[4];
    const size_t row = blockIdx.x;
    ushort_t* p = S + row * 1024;
    const int tid = threadIdx.x;
    uint2 u = *(const uint2*)&p[tid * 4];
    ushort_t* us = (ushort_t*)&u;
    float xr[4];
    float mx = -3.4e38f;
#pragma unroll
    for (int i = 0; i < 4; i++) { xr[i] = bf2f(us[i]); mx = fmaxf(mx, xr[i]); }
    mx = block_reduce(mx, 1, red);
    float sum = 0.f;
#pragma unroll
    for (int i = 0; i < 4; i++) { xr[i] = __expf(xr[i] - mx); sum += xr[i]; }
    sum = block_reduce(sum, 0, red);
    float inv = 1.f / sum;
#pragma unroll
    for (int i = 0; i < 4; i++) us[i] = f2bf(xr[i] * inv);
    *(uint2*)&p[tid * 4] = u;
}

// ---------------------------------------------------------------------------
// Host side
// ---------------------------------------------------------------------------
static inline void gemm_go(hipStream_t s, const ushort_t* A, const ushort_t* B,
                           const float* bias, ushort_t* C,
                           int M, int N, int K, int lda, int ldb, int ldc,
                           long sAz, long sBz, long sCz, int Z, float alpha,
                           bool bkn, bool relu,
                           long sA2 = 0, long sB2 = 0, long sC2 = 0, int zshift = 0)
{
    dim3 g(M / 128, N / 128, Z), b(256);
    if (bkn)       gemm_bf16<true,  false><<<g, b, 0, s>>>(A, B, bias, C, M, N, K, lda, ldb, ldc, sAz, sBz, sCz, sA2, sB2, sC2, zshift, alpha);
    else if (relu) gemm_bf16<false, true ><<<g, b, 0, s>>>(A, B, bias, C, M, N, K, lda, ldb, ldc, sAz, sBz, sCz, sA2, sB2, sC2, zshift, alpha);
    else           gemm_bf16<false, false><<<g, b, 0, s>>>(A, B, bias, C, M, N, K, lda, ldb, ldc, sAz, sBz, sCz, sA2, sB2, sC2, zshift, alpha);
}

extern "C" void kernel_launch(void* const* d_in, const int* in_sizes, int n_in,
                              void* d_out, int out_size, void* d_ws, size_t ws_size,
                              hipStream_t stream)
{
    const float* src   = (const float*)d_in[0];
    const float* sa_wi = (const float*)d_in[2];
    const float* sa_bi = (const float*)d_in[3];
    const float* sa_wo = (const float*)d_in[4];
    const float* sa_bo = (const float*)d_in[5];
    const float* fa_wi = (const float*)d_in[6];
    const float* fa_bi = (const float*)d_in[7];
    const float* fa_wo = (const float*)d_in[8];
    const float* fa_bo = (const float*)d_in[9];
    const float* pl1_w = (const float*)d_in[10];
    const float* pl1_b = (const float*)d_in[11];
    const float* pl2_w = (const float*)d_in[12];
    const float* pl2_b = (const float*)d_in[13];
    const float* pl3_w = (const float*)d_in[14];
    const float* pl3_b = (const float*)d_in[15];
    const float* pl4_w = (const float*)d_in[16];
    const float* pl4_b = (const float*)d_in[17];
    const float* pl5_w = (const float*)d_in[18];
    const float* pl5_b = (const float*)d_in[19];
    const float* pl6_w = (const float*)d_in[20];
    const float* pl6_b = (const float*)d_in[21];
    const float* pl7_w = (const float*)d_in[22];
    const float* pl7_b = (const float*)d_in[23];
    const float* l1_w  = (const float*)d_in[24];
    const float* l1_b  = (const float*)d_in[25];
    const float* l2_w  = (const float*)d_in[26];
    const float* l2_b  = (const float*)d_in[27];
    const float* pn1_g = (const float*)d_in[28];
    const float* pn1_b = (const float*)d_in[29];
    const float* pn2_g = (const float*)d_in[30];
    const float* pn2_b = (const float*)d_in[31];
    const float* n1_g  = (const float*)d_in[32];
    const float* n1_b  = (const float*)d_in[33];
    const float* n2_g  = (const float*)d_in[34];
    const float* n2_b  = (const float*)d_in[35];

    float* ws  = (float*)d_ws;
    float* out = (float*)d_out;

    float* CONSTS = ws;                   // 16384 floats
    ushort_t* wsb = (ushort_t*)(ws + 16384);
    ushort_t* SAWIb  = wsb + 0;           // 3145728
    ushort_t* SAWOb  = wsb + 3145728;     // 1048576
    ushort_t* PL4b   = wsb + 4194304;     // 262144
    ushort_t* PL5b   = wsb + 4456448;     // 2097152
    ushort_t* PL6b   = wsb + 6553600;     // 2097152
    ushort_t* PL7b   = wsb + 8650752;     // 2097152
    ushort_t* L1b    = wsb + 10747904;    // 2097152
    ushort_t* L2b    = wsb + 12845056;    // 262144
    ushort_t* Gbb    = wsb + 13107200;    // 65536
    ushort_t* SRC1b  = wsb + 13172736;    // 294912
    ushort_t* HBIGb  = wsb + 13467648;    // 4718592 (2304x2048)
    ushort_t* SRC1_b = wsb + 18186240;    // 2359296 (2304x1024)
    ushort_t* QKVb   = wsb + 20545536;    // 7077888 (2304x3072)
    ushort_t* SBUFb  = wsb + 27623424;    // 16777216 (scores; later cross scratch)
    ushort_t* OBUFb  = wsb + 44400640;    // 2097152
    ushort_t* SLb    = wsb + 46497792;    // 2097152
    ushort_t* SLPb   = wsb + 48594944;    // 2097152
    ushort_t* SOb    = wsb + 50692096;    // 2359296
    ushort_t* FFb    = wsb + 53051392;    // 294912
    // total ~107 MB

    // ---- one-time weight conversion (single dispatch) ----
    {
        CvtArgs a;
        const float* srcs[8] = { sa_wi, sa_wo, pl4_w, pl5_w, pl6_w, pl7_w, l1_w, l2_w };
        ushort_t*    dsts[8] = { SAWIb, SAWOb, PL4b, PL5b, PL6b, PL7b, L1b, L2b };
        int          ns[8]   = { 3145728, 1048576, 262144, 2097152, 2097152, 2097152, 2097152, 262144 };
        int cum = 0;
        for (int i = 0; i < 8; i++) { a.src[i] = srcs[i]; a.dst[i] = dsts[i]; cum += ns[i] / 4; a.end[i] = cum; }
        cvt_all<<<(cum + 255) / 256, 256, 0, stream>>>(a);
    }

    // ---- collapsed feature-attention block ----
    precomp1<<<1, 384, 0, stream>>>(fa_wi, fa_bi, pl1_w, pl1_b, CONSTS);
    precomp2<<<1, 128, 0, stream>>>(fa_wo, fa_bo, CONSTS);
    precomp3<<<8, 256, 0, stream>>>(pl2_w, pl2_b, CONSTS, Gbb);
    feat_mlp_ln<<<2304, 256, 0, stream>>>(src, CONSTS, Gbb, pl3_w, pl3_b, pn1_g, pn1_b, SRC1b);

    // ---- src1_ = relu(src1@pl4^T+b)@pl5^T+b ----
    gemm_go(stream, SRC1b, PL4b, pl4_b, HBIGb, 2304, 2048, 128, 128, 128, 2048, 0, 0, 0, 1, 1.f, false, true);
    gemm_go(stream, HBIGb, PL5b, pl5_b, SRC1_b, 2304, 1024, 2048, 2048, 2048, 1024, 0, 0, 0, 1, 1.f, false, false);

    // ---- qkv over ALL 2304 rows (rows 2048+ give cross-attn Q for free) ----
    gemm_go(stream, SRC1_b, SAWIb, sa_bi, QKVb, 2304, 3072, 1024, 1024, 1024, 3072, 0, 0, 0, 1, 1.f, false, false);
    const float iscale = 0.08838834764831845f;   // 1/sqrt(128)
    // self-attention on rows 0..2047, z = h + 8*b
    gemm_go(stream, QKVb, QKVb + 1024, nullptr, SBUFb,
            1024, 1024, 128, 6144, 6144, 1024, 128, 128, 1048576, 16, iscale, false, false,
            3072, 3072, 8388608, 3);
    softmax_bf16<<<16384, 256, 0, stream>>>(SBUFb);
    gemm_go(stream, SBUFb, QKVb + 2048, nullptr, OBUFb,
            1024, 128, 1024, 1024, 6144, 2048, 1048576, 128, 128, 16, 1.f, true, false,
            8388608, 3072, 1024, 3);
    gemm_go(stream, OBUFb, SAWOb, sa_bo, HBIGb, 2048, 1024, 1024, 1024, 1024, 1024, 0, 0, 0, 1, 1.f, false, false);
    ln_bf16<false><<<2048, 256, 0, stream>>>(HBIGb, SRC1_b, nullptr, pn2_g, pn2_b, SLb, 1024);

    // ---- sl_ = ln(relu(sl@pl6^T)@pl7^T, pn2) + sl ----
    gemm_go(stream, SLb, PL6b, pl6_b, HBIGb, 2048, 2048, 1024, 1024, 1024, 2048, 0, 0, 0, 1, 1.f, false, true);
    gemm_go(stream, HBIGb, PL7b, pl7_b, OBUFb, 2048, 1024, 2048, 2048, 2048, 1024, 0, 0, 0, 1, 1.f, false, false);
    ln_bf16<false><<<2048, 256, 0, stream>>>(OBUFb, nullptr, SLb, pn2_g, pn2_b, SLPb, 1024);

    // ---- cross-attention: q from qkv rows 2048+, k/v from sl_ ----
    ushort_t* KV2 = SBUFb;               // 2048x2048
    ushort_t* S2  = SBUFb + 4456448;     // 2x8x128x1024
    ushort_t* SR  = SBUFb + 6553600;     // 256x1024
    gemm_go(stream, SLPb, SAWIb + 1024 * 1024, sa_bi + 1024, KV2, 2048, 2048, 1024, 1024, 1024, 2048, 0, 0, 0, 1, 1.f, false, false);
    gemm_go(stream, QKVb + 2048 * 3072, KV2, nullptr, S2,
            128, 1024, 128, 6144, 4096, 1024, 128, 128, 131072, 16, iscale, false, false,
            3072, 2048, 1048576, 3);
    softmax_bf16<<<2048, 256, 0, stream>>>(S2);
    gemm_go(stream, S2, KV2 + 1024, nullptr, OBUFb,
            128, 128, 1024, 1024, 4096, 2048, 131072, 128, 128, 16, 1.f, true, false,
            1048576, 2048, 1024, 3);
    gemm_go(stream, OBUFb, SAWOb, sa_bo, SR, 256, 1024, 1024, 1024, 1024, 1024, 0, 0, 0, 1, 1.f, false, false);

    // ---- so = ln(concat(sl, sr) + src1_, n1)  (single dispatch) ----
    ln_cat<<<2304, 256, 0, stream>>>(SLb, SR, 2048, SRC1_b, n1_g, n1_b, SOb, 1024);

    // ---- ff = relu(so@l1^T)@l2^T ; out = ln(src1 + ff, n2) ----
    gemm_go(stream, SOb, L1b, l1_b, HBIGb, 2304, 2048, 1024, 1024, 1024, 2048, 0, 0, 0, 1, 1.f, false, true);
    gemm_go(stream, HBIGb, L2b, l2_b, FFb, 2304, 128, 2048, 2048, 2048, 128, 0, 0, 0, 1, 1.f, false, false);
    ln_bf16<true><<<2304, 128, 0, stream>>>(FFb, SRC1b, nullptr, n2_g, n2_b, out, 128);
}

// Round 5
// 665.359 us; speedup vs baseline: 3.1127x; 1.0393x over previous
//
#include <hip/hip_runtime.h>

using s16x8 = __attribute__((ext_vector_type(8))) short;   // 8 bf16 (4 VGPRs)
using f32x4 = __attribute__((ext_vector_type(4))) float;   // MFMA accumulator
typedef unsigned short ushort_t;

__device__ __forceinline__ unsigned short f2bf(float f) {
    union { float f; unsigned u; } v; v.f = f;
    unsigned u = v.u + 0x7FFFu + ((v.u >> 16) & 1u);   // round-nearest-even
    return (unsigned short)(u >> 16);
}
__device__ __forceinline__ float bf2f(unsigned short h) {
    union { unsigned u; float f; } v; v.u = ((unsigned)h) << 16;
    return v.f;
}

// block reduction: op==0 sum, op==1 max.
__device__ __forceinline__ float block_reduce(float v, int op, float* lds) {
    const int lane = threadIdx.x & 63;
    const int w    = threadIdx.x >> 6;
    const int nw   = blockDim.x >> 6;
#pragma unroll
    for (int off = 32; off > 0; off >>= 1) {
        float o = __shfl_down(v, off, 64);
        v = op ? fmaxf(v, o) : (v + o);
    }
    __syncthreads();
    if (lane == 0) lds[w] = v;
    __syncthreads();
    float r = lds[0];
    for (int i = 1; i < nw; i++) r = op ? fmaxf(r, lds[i]) : (r + lds[i]);
    return r;
}

__device__ __forceinline__ void load_lds16(const void* g, void* l) {
    __builtin_amdgcn_global_load_lds(
        (const __attribute__((address_space(1))) unsigned int*)g,
        (__attribute__((address_space(3))) unsigned int*)l, 16, 0, 0);
}

// ---------------------------------------------------------------------------
// fp32 -> bf16 weight conversion, all 8 weights in one dispatch
// ---------------------------------------------------------------------------
struct CvtArgs { const float* src[8]; ushort_t* dst[8]; int end[8]; };

__global__ __launch_bounds__(256)
void cvt_all(CvtArgs a)
{
    int i = blockIdx.x * 256 + threadIdx.x;
    int j = 0;
    while (j < 8 && i >= a.end[j]) j++;
    if (j >= 8) return;
    int li = i - (j ? a.end[j - 1] : 0);
    float4 v = *(const float4*)&a.src[j][(size_t)li * 4];
    ushort_t u[4] = { f2bf(v.x), f2bf(v.y), f2bf(v.z), f2bf(v.w) };
    *(uint2*)&a.dst[j][(size_t)li * 4] = *(uint2*)u;
}

// ---------------------------------------------------------------------------
// bf16 GEMM, BK=32, XOR-swizzled LDS (bank-conflict-free fragment reads):
//   LDS slot (row, g') holds global 16B-chunk (row, g' ^ ((row>>1)&3)).
//   C[z] = act(alpha * A[z] @ B[z]^T + bias), bf16 out.
//   z1 = z & ((1<<zshift)-1), z2 = z >> zshift; offsets z1*s?z + z2*s?2
//   BKN=false: B is N x K row-major (W layout)      [C = A @ W^T]
//   BKN=true : B is K x N row-major                 [C = A @ B]  (VALU-staged)
// M%128==0, N%128==0, K%32==0, lda/ldb multiples of 8, pointers 16B-aligned.
// ---------------------------------------------------------------------------
template<bool BKN, bool RELU>
__global__ __launch_bounds__(256, 2)
void gemm_bf16(const ushort_t* __restrict__ A, const ushort_t* __restrict__ B,
               const float* __restrict__ bias, ushort_t* __restrict__ C,
               int M, int N, int K, int lda, int ldb, int ldc,
               long sAz, long sBz, long sCz, long sA2, long sB2, long sC2,
               int zshift, float alpha)
{
    __shared__ ushort_t As[128 * 32];
    __shared__ ushort_t Bs[128 * 32];

    const int tid = threadIdx.x;
    const int z   = blockIdx.z;
    const int z1  = z & ((1 << zshift) - 1);
    const int z2  = z >> zshift;
    const int m0  = blockIdx.x * 128;
    const int n0  = blockIdx.y * 128;

    const ushort_t* Ab = A + (size_t)z1 * sAz + (size_t)z2 * sA2 + (size_t)m0 * lda;
    const ushort_t* Bb = B + (size_t)z1 * sBz + (size_t)z2 * sB2;

    const int wave = tid >> 6, lane = tid & 63;
    const int wm = (wave & 1) * 64, wn = (wave >> 1) * 64;
    const int mi = lane & 15, quad = lane >> 4;

    f32x4 acc[4][4];
#pragma unroll
    for (int i = 0; i < 4; i++)
#pragma unroll
        for (int j = 0; j < 4; j++) acc[i][j] = (f32x4)0.f;

    // staging chunk ids (LDS dest is base + lane*16B, fixed by HW):
    // chunk ci -> LDS slot (r=ci>>2, g'=ci&3); fetch global group g'^((r>>1)&3)
    const int r_0 = tid >> 2,           g_0 = (tid & 3) ^ ((r_0 >> 1) & 3);
    const int r_1 = (tid + 256) >> 2,   g_1 = (tid & 3) ^ ((r_1 >> 1) & 3);
    // BKN B staging map (VALU scatter)
    const int bk = tid >> 3, bn = (tid & 7) * 16;

    for (int k0 = 0; k0 < K; k0 += 32) {
        load_lds16(Ab + (size_t)r_0 * lda + k0 + g_0 * 8, &As[tid * 8]);
        load_lds16(Ab + (size_t)r_1 * lda + k0 + g_1 * 8, &As[(tid + 256) * 8]);
        if (!BKN) {
            const ushort_t* Bb2 = Bb + (size_t)n0 * ldb;
            load_lds16(Bb2 + (size_t)r_0 * ldb + k0 + g_0 * 8, &Bs[tid * 8]);
            load_lds16(Bb2 + (size_t)r_1 * ldb + k0 + g_1 * 8, &Bs[(tid + 256) * 8]);
        } else {
#pragma unroll
            for (int c = 0; c < 2; c++) {
                s16x8 v = *(const s16x8*)(Bb + (size_t)(k0 + bk) * ldb + n0 + bn + c * 8);
#pragma unroll
                for (int j = 0; j < 8; j++) {
                    int nr = bn + c * 8 + j;
                    Bs[nr * 32 + (((bk >> 3) ^ ((nr >> 1) & 3)) * 8) + (bk & 7)] = (ushort_t)v[j];
                }
            }
        }
        __syncthreads();

        s16x8 af[4], bfr[4];
#pragma unroll
        for (int t = 0; t < 4; t++) {
            int r = wm + t * 16 + mi;
            af[t] = *(const s16x8*)&As[r * 32 + ((quad ^ ((r >> 1) & 3)) * 8)];
        }
#pragma unroll
        for (int t = 0; t < 4; t++) {
            int r = wn + t * 16 + mi;
            bfr[t] = *(const s16x8*)&Bs[r * 32 + ((quad ^ ((r >> 1) & 3)) * 8)];
        }
#pragma unroll
        for (int tm = 0; tm < 4; tm++)
#pragma unroll
            for (int tn = 0; tn < 4; tn++)
                acc[tm][tn] = __builtin_amdgcn_mfma_f32_16x16x32_bf16(af[tm], bfr[tn], acc[tm][tn], 0, 0, 0);
        __syncthreads();
    }

#pragma unroll
    for (int tn = 0; tn < 4; tn++) {
        int col = n0 + wn + tn * 16 + mi;
        float bv = bias ? bias[col] : 0.f;
#pragma unroll
        for (int tm = 0; tm < 4; tm++) {
#pragma unroll
            for (int r = 0; r < 4; r++) {
                int row = m0 + wm + tm * 16 + quad * 4 + r;
                float v = acc[tm][tn][r] * alpha + bv;
                if (RELU) v = fmaxf(v, 0.f);
                C[(size_t)z1 * sCz + (size_t)z2 * sC2 + (size_t)row * ldc + col] = f2bf(v);
            }
        }
    }
}

// ---------------------------------------------------------------------------
// Collapsed feature-attention precompute
// consts layout (floats): u@0(384) v@512(384) abcd@1024(16)
//                         wv@1088(4*128) c0@1600(128)
// Gb: bf16[2048][32]: cols 0..3 = g[m][h], col 4 = g0[m], 5..31 = 0
// ---------------------------------------------------------------------------
__global__ void precomp1(const float* __restrict__ fa_wi, const float* __restrict__ fa_bi,
                         const float* __restrict__ pl1_w, const float* __restrict__ pl1_b,
                         float* __restrict__ consts)
{
    int j = threadIdx.x;
    if (j < 384) {
        float u = 0.f, v = 0.f;
        for (int k = 0; k < 128; k++) {
            float w = fa_wi[j * 128 + k];
            u = fmaf(w, pl1_w[k], u);
            v = fmaf(w, pl1_b[k], v);
        }
        consts[j]       = u;
        consts[512 + j] = v + fa_bi[j];
    }
}

__global__ void precomp2(const float* __restrict__ fa_wo, const float* __restrict__ fa_bo,
                         float* __restrict__ consts)
{
    int tid = threadIdx.x;  // 128
    const float* u = consts;
    const float* v = consts + 512;
    if (tid < 16) {
        int h = tid >> 2, w = tid & 3;
        const float* ql = (w < 2) ? u : v;
        const float* kr = ((w & 1) == 0) ? u : v;
        float acc = 0.f;
        for (int d = 0; d < 32; d++) acc += ql[h * 32 + d] * kr[128 + h * 32 + d];
        consts[1024 + tid] = acc * 0.17677669529663687f;
    }
#pragma unroll
    for (int h = 0; h < 4; h++) {
        float acc = 0.f;
        for (int d = 0; d < 32; d++)
            acc = fmaf(fa_wo[tid * 128 + h * 32 + d], u[256 + h * 32 + d], acc);
        consts[1088 + h * 128 + tid] = acc;
    }
    float c0 = fa_bo[tid];
    for (int idx = 0; idx < 128; idx++)
        c0 = fmaf(fa_wo[tid * 128 + idx], v[256 + idx], c0);
    consts[1600 + tid] = c0;
}

__global__ void precomp3(const float* __restrict__ pl2_w, const float* __restrict__ pl2_b,
                         const float* __restrict__ consts, ushort_t* __restrict__ Gb)
{
    int m = blockIdx.x * 256 + threadIdx.x;   // 2048
    const float* wv = consts + 1088;
    const float* c0 = consts + 1600;
    float a0 = 0.f, ah[4] = {0.f, 0.f, 0.f, 0.f};
    for (int j = 0; j < 128; j++) {
        float w = pl2_w[m * 128 + j];
        ah[0] = fmaf(w, wv[0 * 128 + j], ah[0]);
        ah[1] = fmaf(w, wv[1 * 128 + j], ah[1]);
        ah[2] = fmaf(w, wv[2 * 128 + j], ah[2]);
        ah[3] = fmaf(w, wv[3 * 128 + j], ah[3]);
        a0    = fmaf(w, c0[j], a0);
    }
    ushort_t* row = Gb + m * 32;
#pragma unroll
    for (int h = 0; h < 4; h++) row[h] = f2bf(ah[h]);
    row[4] = f2bf(a0 + pl2_b[m]);
#pragma unroll
    for (int j = 5; j < 32; j++) row[j] = 0;
}

// ---------------------------------------------------------------------------
// Fused: feature-attention (moment-form softmax) + pl2/pl3 MLP (MFMA) + LN
// One block per token n (0..2303), 256 threads (4 waves).
// t = (S1 + p S2 + p^2/2 S3 + p^3/6 S4) / (128 + p S1 + p^2/2 S2 + p^3/6 S3)
// valid when |p|*max|s| small; exact-exp fallback otherwise (block-uniform).
// ---------------------------------------------------------------------------
__global__ __launch_bounds__(256, 3)
void feat_mlp_ln(const float* __restrict__ src, const float* __restrict__ consts,
                 const ushort_t* __restrict__ Gb, const float* __restrict__ pl3_w,
                 const float* __restrict__ pl3_b, const float* __restrict__ pn1_g,
                 const float* __restrict__ pn1_b, ushort_t* __restrict__ src1)
{
    __shared__ ushort_t As[128 * 32];
    __shared__ ushort_t Bs[256 * 32];
    __shared__ float sv[128];
    __shared__ float ypart[2][128];
    __shared__ float red[4];

    const int n   = blockIdx.x;
    const int tid = threadIdx.x;
    const int f   = tid & 127;
    const int hp  = tid >> 7;          // 0: heads 0,1  1: heads 2,3

    // zero As (8 KB): 256 threads x 32 B
    *(uint4*)&As[tid * 16]     = (uint4){0, 0, 0, 0};
    *(uint4*)&As[tid * 16 + 8] = (uint4){0, 0, 0, 0};
    if (tid < 128) sv[f] = src[n * 128 + f];
    __syncthreads();

    const float si = sv[f];
    const bool act = (tid < 128);
    float S1 = block_reduce(act ? si : 0.f, 0, red);
    float S2 = block_reduce(act ? si * si : 0.f, 0, red);
    float S3 = block_reduce(act ? si * si * si : 0.f, 0, red);
    float S4 = block_reduce(act ? si * si * si * si : 0.f, 0, red);
    float amax = block_reduce(act ? fabsf(si) : 0.f, 1, red);

    float ph[2];
#pragma unroll
    for (int hh = 0; hh < 2; hh++) {
        const int h = hp * 2 + hh;
        ph[hh] = consts[1024 + h * 4 + 0] * si + consts[1024 + h * 4 + 2];
    }
    float pmax = block_reduce(fmaxf(fabsf(ph[0]), fabsf(ph[1])), 1, red);

    float tt[2];
    if (pmax * amax < 0.25f) {   // Taylor regime (block-uniform)
#pragma unroll
        for (int hh = 0; hh < 2; hh++) {
            float p = ph[hh];
            float num = fmaf(p, fmaf(p, fmaf(p, S4 * (1.f / 6.f), 0.5f * S3), S2), S1);
            float den = fmaf(p, fmaf(p, fmaf(p, S3 * (1.f / 6.f), 0.5f * S2), S1), 128.f);
            tt[hh] = num / den;
        }
    } else {                     // exact fallback
        float smax = block_reduce(act ? si : -3.4e38f, 1, red);
        float smin = -block_reduce(act ? -si : -3.4e38f, 1, red);
#pragma unroll
        for (int hh = 0; hh < 2; hh++) {
            float p = ph[hh];
            float m = fmaxf(p * smax, p * smin);
            float l = 0.f, t = 0.f;
            for (int j = 0; j < 128; j++) {
                float e = __expf(fmaf(p, sv[j], -m));
                l += e; t = fmaf(e, sv[j], t);
            }
            tt[hh] = t / l;
        }
    }

    // write A row f (swizzled: t-cols live in group 0 -> slot g' = (f>>1)&3)
    {
        int base = f * 32 + (((f >> 1) & 3) * 8);
        As[base + hp * 2 + 0] = f2bf(tt[0]);
        As[base + hp * 2 + 1] = f2bf(tt[1]);
        if (act) As[base + 4] = 0x3F80;   // 1.0 (carries g0)
    }
    __syncthreads();

    const int wave = tid >> 6, lane = tid & 63;
    const int wm = (wave & 1) * 64, wn = (wave >> 1) * 64;
    const int mi = lane & 15, quad = lane >> 4;

    s16x8 af[4];
#pragma unroll
    for (int t = 0; t < 4; t++) {
        int r = wm + t * 16 + mi;
        af[t] = *(const s16x8*)&As[r * 32 + ((quad ^ ((r >> 1) & 3)) * 8)];
    }

    float partial[4][4];
#pragma unroll
    for (int i = 0; i < 4; i++)
#pragma unroll
        for (int j = 0; j < 4; j++) partial[i][j] = 0.f;

    for (int cchunk = 0; cchunk < 8; cchunk++) {
        const ushort_t* Gc = Gb + cchunk * 256 * 32;
#pragma unroll
        for (int p = 0; p < 4; p++) {
            int ci = tid + p * 256;
            int r  = ci >> 2;
            int g  = (ci & 3) ^ ((r >> 1) & 3);
            load_lds16(Gc + (size_t)r * 32 + g * 8, &Bs[ci * 8]);
        }
        __syncthreads();

#pragma unroll
        for (int sub = 0; sub < 2; sub++) {
            s16x8 bfr[4];
#pragma unroll
            for (int t = 0; t < 4; t++) {
                int r = sub * 128 + wn + t * 16 + mi;
                bfr[t] = *(const s16x8*)&Bs[r * 32 + ((quad ^ ((r >> 1) & 3)) * 8)];
            }

            f32x4 acc[4][4];
#pragma unroll
            for (int tm = 0; tm < 4; tm++)
#pragma unroll
                for (int tn = 0; tn < 4; tn++)
                    acc[tm][tn] = __builtin_amdgcn_mfma_f32_16x16x32_bf16(af[tm], bfr[tn], (f32x4)0.f, 0, 0, 0);

#pragma unroll
            for (int tn = 0; tn < 4; tn++) {
                float w = pl3_w[cchunk * 256 + sub * 128 + wn + tn * 16 + mi];
#pragma unroll
                for (int tm = 0; tm < 4; tm++)
#pragma unroll
                    for (int r = 0; r < 4; r++)
                        partial[tm][r] = fmaf(fmaxf(acc[tm][tn][r], 0.f), w, partial[tm][r]);
            }
        }
        __syncthreads();
    }

    // reduce partials across the 16 mi lanes (same rows)
#pragma unroll
    for (int tm = 0; tm < 4; tm++)
#pragma unroll
        for (int r = 0; r < 4; r++) {
            float v = partial[tm][r];
            v += __shfl_xor(v, 8);
            v += __shfl_xor(v, 4);
            v += __shfl_xor(v, 2);
            v += __shfl_xor(v, 1);
            if (mi == 0) ypart[wave >> 1][wm + tm * 16 + quad * 4 + r] = v;
        }
    __syncthreads();

    float yv = 0.f;
    if (act)
        yv = ypart[0][f] + ypart[1][f] + pl3_b[0] + sv[f];
    float s  = block_reduce(yv, 0, red);
    float ss = block_reduce(yv * yv, 0, red);
    float mean = s * (1.f / 128.f);
    float var  = ss * (1.f / 128.f) - mean * mean;
    float inv  = rsqrtf(var + 1e-5f);
    if (act)
        src1[n * 128 + f] = f2bf((yv - mean) * inv * pn1_g[f] + pn1_b[f]);
}

// LN over bf16: out = LN(a [+ b]) * g + beta [+ post];  out bf16 or fp32
template<bool OUTF32>
__global__ void ln_bf16(const ushort_t* __restrict__ a, const ushort_t* __restrict__ b,
                        const ushort_t* __restrict__ post, const float* __restrict__ g,
                        const float* __restrict__ beta, void* __restrict__ out, int D)
{
    __shared__ float red[4];
    const size_t row = blockIdx.x;
    const int tid = threadIdx.x;
    const int nit = D / blockDim.x;   // <= 4
    const ushort_t* ap = a + row * D;
    const ushort_t* bp = b ? b + row * D : nullptr;
    float xr[4];
    float s = 0.f, ss = 0.f;
    for (int i = 0; i < nit; i++) {
        int idx = i * blockDim.x + tid;
        float x = bf2f(ap[idx]) + (bp ? bf2f(bp[idx]) : 0.f);
        xr[i] = x; s += x; ss = fmaf(x, x, ss);
    }
    s  = block_reduce(s, 0, red);
    ss = block_reduce(ss, 0, red);
    float mean = s / D, var = ss / D - mean * mean;
    float inv = rsqrtf(var + 1e-5f);
    const ushort_t* pp = post ? post + row * D : nullptr;
    for (int i = 0; i < nit; i++) {
        int idx = i * blockDim.x + tid;
        float v = (xr[i] - mean) * inv * g[idx] + beta[idx];
        if (pp) v += bf2f(pp[idx]);
        if (OUTF32) ((float*)out)[row * D + idx] = v;
        else        ((ushort_t*)out)[row * D + idx] = f2bf(v);
    }
}

// LN over concat(a1[0:split], a2[split:]) + b  -> out (bf16), D=1024
__global__ void ln_cat(const ushort_t* __restrict__ a1, const ushort_t* __restrict__ a2,
                       int split, const ushort_t* __restrict__ b,
                       const float* __restrict__ g, const float* __restrict__ beta,
                       ushort_t* __restrict__ out, int D)
{
    __shared__ float red[4];
    const int row = blockIdx.x;
    const int tid = threadIdx.x;
    const int nit = D / blockDim.x;
    const ushort_t* ap = (row < split) ? a1 + (size_t)row * D : a2 + (size_t)(row - split) * D;
    const ushort_t* bp = b + (size_t)row * D;
    float xr[4];
    float s = 0.f, ss = 0.f;
    for (int i = 0; i < nit; i++) {
        int idx = i * blockDim.x + tid;
        float x = bf2f(ap[idx]) + bf2f(bp[idx]);
        xr[i] = x; s += x; ss = fmaf(x, x, ss);
    }
    s  = block_reduce(s, 0, red);
    ss = block_reduce(ss, 0, red);
    float mean = s / D, var = ss / D - mean * mean;
    float inv = rsqrtf(var + 1e-5f);
    for (int i = 0; i < nit; i++) {
        int idx = i * blockDim.x + tid;
        out[(size_t)row * D + idx] = f2bf((xr[i] - mean) * inv * g[idx] + beta[idx]);
    }
}

// row softmax in place, bf16, cols == 1024, 256 threads
__global__ __launch_bounds__(256)
void softmax_bf16(ushort_t* __restrict__ S)
{
    __shared__ float red[4];
    const size_t row = blockIdx.x;
    ushort_t* p = S + row * 1024;
    const int tid = threadIdx.x;
    uint2 u = *(const uint2*)&p[tid * 4];
    ushort_t* us = (ushort_t*)&u;
    float xr[4];
    float mx = -3.4e38f;
#pragma unroll
    for (int i = 0; i < 4; i++) { xr[i] = bf2f(us[i]); mx = fmaxf(mx, xr[i]); }
    mx = block_reduce(mx, 1, red);
    float sum = 0.f;
#pragma unroll
    for (int i = 0; i < 4; i++) { xr[i] = __expf(xr[i] - mx); sum += xr[i]; }
    sum = block_reduce(sum, 0, red);
    float inv = 1.f / sum;
#pragma unroll
    for (int i = 0; i < 4; i++) us[i] = f2bf(xr[i] * inv);
    *(uint2*)&p[tid * 4] = u;
}

// ---------------------------------------------------------------------------
// Host side
// ---------------------------------------------------------------------------
static inline void gemm_go(hipStream_t s, const ushort_t* A, const ushort_t* B,
                           const float* bias, ushort_t* C,
                           int M, int N, int K, int lda, int ldb, int ldc,
                           long sAz, long sBz, long sCz, int Z, float alpha,
                           bool bkn, bool relu,
                           long sA2 = 0, long sB2 = 0, long sC2 = 0, int zshift = 0)
{
    dim3 g(M / 128, N / 128, Z), b(256);
    if (bkn)       gemm_bf16<true,  false><<<g, b, 0, s>>>(A, B, bias, C, M, N, K, lda, ldb, ldc, sAz, sBz, sCz, sA2, sB2, sC2, zshift, alpha);
    else if (relu) gemm_bf16<false, true ><<<g, b, 0, s>>>(A, B, bias, C, M, N, K, lda, ldb, ldc, sAz, sBz, sCz, sA2, sB2, sC2, zshift, alpha);
    else           gemm_bf16<false, false><<<g, b, 0, s>>>(A, B, bias, C, M, N, K, lda, ldb, ldc, sAz, sBz, sCz, sA2, sB2, sC2, zshift, alpha);
}

extern "C" void kernel_launch(void* const* d_in, const int* in_sizes, int n_in,
                              void* d_out, int out_size, void* d_ws, size_t ws_size,
                              hipStream_t stream)
{
    const float* src   = (const float*)d_in[0];
    const float* sa_wi = (const float*)d_in[2];
    const float* sa_bi = (const float*)d_in[3];
    const float* sa_wo = (const float*)d_in[4];
    const float* sa_bo = (const float*)d_in[5];
    const float* fa_wi = (const float*)d_in[6];
    const float* fa_bi = (const float*)d_in[7];
    const float* fa_wo = (const float*)d_in[8];
    const float* fa_bo = (const float*)d_in[9];
    const float* pl1_w = (const float*)d_in[10];
    const float* pl1_b = (const float*)d_in[11];
    const float* pl2_w = (const float*)d_in[12];
    const float* pl2_b = (const float*)d_in[13];
    const float* pl3_w = (const float*)d_in[14];
    const float* pl3_b = (const float*)d_in[15];
    const float* pl4_w = (const float*)d_in[16];
    const float* pl4_b = (const float*)d_in[17];
    const float* pl5_w = (const float*)d_in[18];
    const float* pl5_b = (const float*)d_in[19];
    const float* pl6_w = (const float*)d_in[20];
    const float* pl6_b = (const float*)d_in[21];
    const float* pl7_w = (const float*)d_in[22];
    const float* pl7_b = (const float*)d_in[23];
    const float* l1_w  = (const float*)d_in[24];
    const float* l1_b  = (const float*)d_in[25];
    const float* l2_w  = (const float*)d_in[26];
    const float* l2_b  = (const float*)d_in[27];
    const float* pn1_g = (const float*)d_in[28];
    const float* pn1_b = (const float*)d_in[29];
    const float* pn2_g = (const float*)d_in[30];
    const float* pn2_b = (const float*)d_in[31];
    const float* n1_g  = (const float*)d_in[32];
    const float* n1_b  = (const float*)d_in[33];
    const float* n2_g  = (const float*)d_in[34];
    const float* n2_b  = (const float*)d_in[35];

    float* ws  = (float*)d_ws;
    float* out = (float*)d_out;

    float* CONSTS = ws;                   // 16384 floats
    ushort_t* wsb = (ushort_t*)(ws + 16384);
    ushort_t* SAWIb  = wsb + 0;           // 3145728
    ushort_t* SAWOb  = wsb + 3145728;     // 1048576
    ushort_t* PL4b   = wsb + 4194304;     // 262144
    ushort_t* PL5b   = wsb + 4456448;     // 2097152
    ushort_t* PL6b   = wsb + 6553600;     // 2097152
    ushort_t* PL7b   = wsb + 8650752;     // 2097152
    ushort_t* L1b    = wsb + 10747904;    // 2097152
    ushort_t* L2b    = wsb + 12845056;    // 262144
    ushort_t* Gbb    = wsb + 13107200;    // 65536
    ushort_t* SRC1b  = wsb + 13172736;    // 294912
    ushort_t* HBIGb  = wsb + 13467648;    // 4718592 (2304x2048)
    ushort_t* SRC1_b = wsb + 18186240;    // 2359296 (2304x1024)
    ushort_t* QKVb   = wsb + 20545536;    // 7077888 (2304x3072)
    ushort_t* SBUFb  = wsb + 27623424;    // 16777216 (scores; later cross scratch)
    ushort_t* OBUFb  = wsb + 44400640;    // 2097152
    ushort_t* SLb    = wsb + 46497792;    // 2097152
    ushort_t* SLPb   = wsb + 48594944;    // 2097152
    ushort_t* SOb    = wsb + 50692096;    // 2359296
    ushort_t* FFb    = wsb + 53051392;    // 294912
    // total ~107 MB

    // ---- one-time weight conversion (single dispatch) ----
    {
        CvtArgs a;
        const float* srcs[8] = { sa_wi, sa_wo, pl4_w, pl5_w, pl6_w, pl7_w, l1_w, l2_w };
        ushort_t*    dsts[8] = { SAWIb, SAWOb, PL4b, PL5b, PL6b, PL7b, L1b, L2b };
        int          ns[8]   = { 3145728, 1048576, 262144, 2097152, 2097152, 2097152, 2097152, 262144 };
        int cum = 0;
        for (int i = 0; i < 8; i++) { a.src[i] = srcs[i]; a.dst[i] = dsts[i]; cum += ns[i] / 4; a.end[i] = cum; }
        cvt_all<<<(cum + 255) / 256, 256, 0, stream>>>(a);
    }

    // ---- collapsed feature-attention block ----
    precomp1<<<1, 384, 0, stream>>>(fa_wi, fa_bi, pl1_w, pl1_b, CONSTS);
    precomp2<<<1, 128, 0, stream>>>(fa_wo, fa_bo, CONSTS);
    precomp3<<<8, 256, 0, stream>>>(pl2_w, pl2_b, CONSTS, Gbb);
    feat_mlp_ln<<<2304, 256, 0, stream>>>(src, CONSTS, Gbb, pl3_w, pl3_b, pn1_g, pn1_b, SRC1b);

    // ---- src1_ = relu(src1@pl4^T+b)@pl5^T+b ----
    gemm_go(stream, SRC1b, PL4b, pl4_b, HBIGb, 2304, 2048, 128, 128, 128, 2048, 0, 0, 0, 1, 1.f, false, true);
    gemm_go(stream, HBIGb, PL5b, pl5_b, SRC1_b, 2304, 1024, 2048, 2048, 2048, 1024, 0, 0, 0, 1, 1.f, false, false);

    // ---- qkv over ALL 2304 rows (rows 2048+ give cross-attn Q for free) ----
    gemm_go(stream, SRC1_b, SAWIb, sa_bi, QKVb, 2304, 3072, 1024, 1024, 1024, 3072, 0, 0, 0, 1, 1.f, false, false);
    const float iscale = 0.08838834764831845f;   // 1/sqrt(128)
    // self-attention on rows 0..2047, z = h + 8*b
    gemm_go(stream, QKVb, QKVb + 1024, nullptr, SBUFb,
            1024, 1024, 128, 6144, 6144, 1024, 128, 128, 1048576, 16, iscale, false, false,
            3072, 3072, 8388608, 3);
    softmax_bf16<<<16384, 256, 0, stream>>>(SBUFb);
    gemm_go(stream, SBUFb, QKVb + 2048, nullptr, OBUFb,
            1024, 128, 1024, 1024, 6144, 2048, 1048576, 128, 128, 16, 1.f, true, false,
            8388608, 3072, 1024, 3);
    gemm_go(stream, OBUFb, SAWOb, sa_bo, HBIGb, 2048, 1024, 1024, 1024, 1024, 1024, 0, 0, 0, 1, 1.f, false, false);
    ln_bf16<false><<<2048, 256, 0, stream>>>(HBIGb, SRC1_b, nullptr, pn2_g, pn2_b, SLb, 1024);

    // ---- sl_ = ln(relu(sl@pl6^T)@pl7^T, pn2) + sl ----
    gemm_go(stream, SLb, PL6b, pl6_b, HBIGb, 2048, 2048, 1024, 1024, 1024, 2048, 0, 0, 0, 1, 1.f, false, true);
    gemm_go(stream, HBIGb, PL7b, pl7_b, OBUFb, 2048, 1024, 2048, 2048, 2048, 1024, 0, 0, 0, 1, 1.f, false, false);
    ln_bf16<false><<<2048, 256, 0, stream>>>(OBUFb, nullptr, SLb, pn2_g, pn2_b, SLPb, 1024);

    // ---- cross-attention: q from qkv rows 2048+, k/v from sl_ ----
    ushort_t* KV2 = SBUFb;               // 2048x2048
    ushort_t* S2  = SBUFb + 4456448;     // 2x8x128x1024
    ushort_t* SR  = SBUFb + 6553600;     // 256x1024
    gemm_go(stream, SLPb, SAWIb + 1024 * 1024, sa_bi + 1024, KV2, 2048, 2048, 1024, 1024, 1024, 2048, 0, 0, 0, 1, 1.f, false, false);
    gemm_go(stream, QKVb + 2048 * 3072, KV2, nullptr, S2,
            128, 1024, 128, 6144, 4096, 1024, 128, 128, 131072, 16, iscale, false, false,
            3072, 2048, 1048576, 3);
    softmax_bf16<<<2048, 256, 0, stream>>>(S2);
    gemm_go(stream, S2, KV2 + 1024, nullptr, OBUFb,
            128, 128, 1024, 1024, 4096, 2048, 131072, 128, 128, 16, 1.f, true, false,
            1048576, 2048, 1024, 3);
    gemm_go(stream, OBUFb, SAWOb, sa_bo, SR, 256, 1024, 1024, 1024, 1024, 1024, 0, 0, 0, 1, 1.f, false, false);

    // ---- so = ln(concat(sl, sr) + src1_, n1)  (single dispatch) ----
    ln_cat<<<2304, 256, 0, stream>>>(SLb, SR, 2048, SRC1_b, n1_g, n1_b, SOb, 1024);

    // ---- ff = relu(so@l1^T)@l2^T ; out = ln(src1 + ff, n2) ----
    gemm_go(stream, SOb, L1b, l1_b, HBIGb, 2304, 2048, 1024, 1024, 1024, 2048, 0, 0, 0, 1, 1.f, false, true);
    gemm_go(stream, HBIGb, L2b, l2_b, FFb, 2304, 128, 2048, 2048, 2048, 128, 0, 0, 0, 1, 1.f, false, false);
    ln_bf16<true><<<2304, 128, 0, stream>>>(FFb, SRC1b, nullptr, n2_g, n2_b, out, 128);
}

// Round 6
// 639.254 us; speedup vs baseline: 3.2398x; 1.0408x over previous
//
#include <hip/hip_runtime.h>

using s16x8 = __attribute__((ext_vector_type(8))) short;   // 8 bf16 (4 VGPRs)
using f32x4 = __attribute__((ext_vector_type(4))) float;   // MFMA accumulator
typedef unsigned short ushort_t;

__device__ __forceinline__ unsigned short f2bf(float f) {
    union { float f; unsigned u; } v; v.f = f;
    unsigned u = v.u + 0x7FFFu + ((v.u >> 16) & 1u);   // round-nearest-even
    return (unsigned short)(u >> 16);
}
__device__ __forceinline__ float bf2f(unsigned short h) {
    union { unsigned u; float f; } v; v.u = ((unsigned)h) << 16;
    return v.f;
}

// block reduction: op==0 sum, op==1 max.
__device__ __forceinline__ float block_reduce(float v, int op, float* lds) {
    const int lane = threadIdx.x & 63;
    const int w    = threadIdx.x >> 6;
    const int nw   = blockDim.x >> 6;
#pragma unroll
    for (int off = 32; off > 0; off >>= 1) {
        float o = __shfl_down(v, off, 64);
        v = op ? fmaxf(v, o) : (v + o);
    }
    __syncthreads();
    if (lane == 0) lds[w] = v;
    __syncthreads();
    float r = lds[0];
    for (int i = 1; i < nw; i++) r = op ? fmaxf(r, lds[i]) : (r + lds[i]);
    return r;
}

__device__ __forceinline__ void load_lds16(const void* g, void* l) {
    __builtin_amdgcn_global_load_lds(
        (const __attribute__((address_space(1))) unsigned int*)g,
        (__attribute__((address_space(3))) unsigned int*)l, 16, 0, 0);
}

// ---------------------------------------------------------------------------
// fp32 -> bf16 weight conversion, all 8 weights in one dispatch
// ---------------------------------------------------------------------------
struct CvtArgs { const float* src[8]; ushort_t* dst[8]; int end[8]; };

__global__ __launch_bounds__(256)
void cvt_all(CvtArgs a)
{
    int i = blockIdx.x * 256 + threadIdx.x;
    int j = 0;
    while (j < 8 && i >= a.end[j]) j++;
    if (j >= 8) return;
    int li = i - (j ? a.end[j - 1] : 0);
    float4 v = *(const float4*)&a.src[j][(size_t)li * 4];
    ushort_t u[4] = { f2bf(v.x), f2bf(v.y), f2bf(v.z), f2bf(v.w) };
    *(uint2*)&a.dst[j][(size_t)li * 4] = *(uint2*)u;
}

// ---------------------------------------------------------------------------
// bf16 GEMM, BK=32, XOR-swizzled LDS: C[z] = act(alpha*A[z]@B[z]^T + bias)
//   B is N x K row-major (W layout). z1 = z&((1<<zshift)-1), z2 = z>>zshift.
// M%128==0, N%128==0, K%32==0, lda/ldb multiples of 8, pointers 16B-aligned.
// ---------------------------------------------------------------------------
template<bool RELU>
__global__ __launch_bounds__(256, 2)
void gemm_bf16(const ushort_t* __restrict__ A, const ushort_t* __restrict__ B,
               const float* __restrict__ bias, ushort_t* __restrict__ C,
               int M, int N, int K, int lda, int ldb, int ldc,
               long sAz, long sBz, long sCz, long sA2, long sB2, long sC2,
               int zshift, float alpha)
{
    __shared__ ushort_t As[128 * 32];
    __shared__ ushort_t Bs[128 * 32];

    const int tid = threadIdx.x;
    const int z   = blockIdx.z;
    const int z1  = z & ((1 << zshift) - 1);
    const int z2  = z >> zshift;
    const int m0  = blockIdx.x * 128;
    const int n0  = blockIdx.y * 128;

    const ushort_t* Ab = A + (size_t)z1 * sAz + (size_t)z2 * sA2 + (size_t)m0 * lda;
    const ushort_t* Bb = B + (size_t)z1 * sBz + (size_t)z2 * sB2 + (size_t)n0 * ldb;

    const int wave = tid >> 6, lane = tid & 63;
    const int wm = (wave & 1) * 64, wn = (wave >> 1) * 64;
    const int mi = lane & 15, quad = lane >> 4;

    f32x4 acc[4][4];
#pragma unroll
    for (int i = 0; i < 4; i++)
#pragma unroll
        for (int j = 0; j < 4; j++) acc[i][j] = (f32x4)0.f;

    // chunk ci -> LDS slot (r=ci>>2, g'=ci&3); fetch global group g'^((r>>1)&3)
    const int r_0 = tid >> 2,           g_0 = (tid & 3) ^ ((r_0 >> 1) & 3);
    const int r_1 = (tid + 256) >> 2,   g_1 = (tid & 3) ^ ((r_1 >> 1) & 3);

    for (int k0 = 0; k0 < K; k0 += 32) {
        load_lds16(Ab + (size_t)r_0 * lda + k0 + g_0 * 8, &As[tid * 8]);
        load_lds16(Ab + (size_t)r_1 * lda + k0 + g_1 * 8, &As[(tid + 256) * 8]);
        load_lds16(Bb + (size_t)r_0 * ldb + k0 + g_0 * 8, &Bs[tid * 8]);
        load_lds16(Bb + (size_t)r_1 * ldb + k0 + g_1 * 8, &Bs[(tid + 256) * 8]);
        __syncthreads();

        s16x8 af[4], bfr[4];
#pragma unroll
        for (int t = 0; t < 4; t++) {
            int r = wm + t * 16 + mi;
            af[t] = *(const s16x8*)&As[r * 32 + ((quad ^ ((r >> 1) & 3)) * 8)];
        }
#pragma unroll
        for (int t = 0; t < 4; t++) {
            int r = wn + t * 16 + mi;
            bfr[t] = *(const s16x8*)&Bs[r * 32 + ((quad ^ ((r >> 1) & 3)) * 8)];
        }
#pragma unroll
        for (int tm = 0; tm < 4; tm++)
#pragma unroll
            for (int tn = 0; tn < 4; tn++)
                acc[tm][tn] = __builtin_amdgcn_mfma_f32_16x16x32_bf16(af[tm], bfr[tn], acc[tm][tn], 0, 0, 0);
        __syncthreads();
    }

#pragma unroll
    for (int tn = 0; tn < 4; tn++) {
        int col = n0 + wn + tn * 16 + mi;
        float bv = bias ? bias[col] : 0.f;
#pragma unroll
        for (int tm = 0; tm < 4; tm++) {
#pragma unroll
            for (int r = 0; r < 4; r++) {
                int row = m0 + wm + tm * 16 + quad * 4 + r;
                float v = acc[tm][tn][r] * alpha + bv;
                if (RELU) v = fmaxf(v, 0.f);
                C[(size_t)z1 * sCz + (size_t)z2 * sC2 + (size_t)row * ldc + col] = f2bf(v);
            }
        }
    }
}

// ---------------------------------------------------------------------------
// V transpose: out[z][d][n] = in[z1*inz1 + z2*inz2 + n*ldin + d], d<128.
// One block: 64 n x 128 d. z = blockIdx.z (z1 = z&7, z2 = z>>3).
// ---------------------------------------------------------------------------
__global__ __launch_bounds__(256)
void transp128(const ushort_t* __restrict__ in, ushort_t* __restrict__ out,
               int ldin, long inz1, long inz2, long outz)
{
    __shared__ ushort_t T[64][136];   // 272 B row stride (16B-aligned)
    const int z = blockIdx.z, z1 = z & 7, z2 = z >> 3;
    const int n0 = blockIdx.x * 64;
    const ushort_t* ip = in + (size_t)z1 * inz1 + (size_t)z2 * inz2;
    const int rr = threadIdx.x >> 2, cg = (threadIdx.x & 3) * 32;
#pragma unroll
    for (int c = 0; c < 4; c++) {
        s16x8 v = *(const s16x8*)(ip + (size_t)(n0 + rr) * ldin + cg + c * 8);
        *(s16x8*)&T[rr][cg + c * 8] = v;
    }
    __syncthreads();
    const int d = threadIdx.x >> 1, j0 = (threadIdx.x & 1) * 32;
    ushort_t* op = out + (size_t)z * outz + (size_t)d * 1024 + n0 + j0;
#pragma unroll
    for (int c = 0; c < 4; c++) {
        s16x8 v;
#pragma unroll
        for (int j = 0; j < 8; j++) v[j] = (short)T[j0 + c * 8 + j][d];
        *(s16x8*)(op + c * 8) = v;
    }
}

// ---------------------------------------------------------------------------
// Collapsed feature-attention precompute
// consts layout (floats): u@0(384) v@512(384) abcd@1024(16)
//                         wv@1088(4*128) c0@1600(128)
// Gb packed: bf16[2048][8]: cols 0..3 = g[m][h], col 4 = g0[m], 5..7 = 0
// ---------------------------------------------------------------------------
__global__ void precomp1(const float* __restrict__ fa_wi, const float* __restrict__ fa_bi,
                         const float* __restrict__ pl1_w, const float* __restrict__ pl1_b,
                         float* __restrict__ consts)
{
    int j = threadIdx.x;
    if (j < 384) {
        float u = 0.f, v = 0.f;
        for (int k = 0; k < 128; k++) {
            float w = fa_wi[j * 128 + k];
            u = fmaf(w, pl1_w[k], u);
            v = fmaf(w, pl1_b[k], v);
        }
        consts[j]       = u;
        consts[512 + j] = v + fa_bi[j];
    }
}

__global__ void precomp2(const float* __restrict__ fa_wo, const float* __restrict__ fa_bo,
                         float* __restrict__ consts)
{
    int tid = threadIdx.x;  // 128
    const float* u = consts;
    const float* v = consts + 512;
    if (tid < 16) {
        int h = tid >> 2, w = tid & 3;
        const float* ql = (w < 2) ? u : v;
        const float* kr = ((w & 1) == 0) ? u : v;
        float acc = 0.f;
        for (int d = 0; d < 32; d++) acc += ql[h * 32 + d] * kr[128 + h * 32 + d];
        consts[1024 + tid] = acc * 0.17677669529663687f;
    }
#pragma unroll
    for (int h = 0; h < 4; h++) {
        float acc = 0.f;
        for (int d = 0; d < 32; d++)
            acc = fmaf(fa_wo[tid * 128 + h * 32 + d], u[256 + h * 32 + d], acc);
        consts[1088 + h * 128 + tid] = acc;
    }
    float c0 = fa_bo[tid];
    for (int idx = 0; idx < 128; idx++)
        c0 = fmaf(fa_wo[tid * 128 + idx], v[256 + idx], c0);
    consts[1600 + tid] = c0;
}

__global__ void precomp3(const float* __restrict__ pl2_w, const float* __restrict__ pl2_b,
                         const float* __restrict__ consts, ushort_t* __restrict__ Gb)
{
    int m = blockIdx.x * 256 + threadIdx.x;   // 2048
    const float* wv = consts + 1088;
    const float* c0 = consts + 1600;
    float a0 = 0.f, ah[4] = {0.f, 0.f, 0.f, 0.f};
    for (int j = 0; j < 128; j++) {
        float w = pl2_w[m * 128 + j];
        ah[0] = fmaf(w, wv[0 * 128 + j], ah[0]);
        ah[1] = fmaf(w, wv[1 * 128 + j], ah[1]);
        ah[2] = fmaf(w, wv[2 * 128 + j], ah[2]);
        ah[3] = fmaf(w, wv[3 * 128 + j], ah[3]);
        a0    = fmaf(w, c0[j], a0);
    }
    ushort_t row[8];
#pragma unroll
    for (int h = 0; h < 4; h++) row[h] = f2bf(ah[h]);
    row[4] = f2bf(a0 + pl2_b[m]);
    row[5] = row[6] = row[7] = 0;
    *(uint4*)&Gb[m * 8] = *(uint4*)row;
}

// ---------------------------------------------------------------------------
// Fused: feature-attention (moment softmax) + pl2/pl3 MLP (MFMA) + LN.
// Whole packed G table (32 KB) + pl3_w (8 KB) staged to LDS once; the m-loop
// has NO barriers. One block per token n, 256 threads (4 waves):
// wave = (mhalf, fhalf); each wave covers 64 f-rows x 1024 m.
// ---------------------------------------------------------------------------
__global__ __launch_bounds__(256, 3)
void feat_mlp_ln(const float* __restrict__ src, const float* __restrict__ consts,
                 const ushort_t* __restrict__ Gb, const float* __restrict__ pl3_w,
                 const float* __restrict__ pl3_b, const float* __restrict__ pn1_g,
                 const float* __restrict__ pn1_b, ushort_t* __restrict__ src1)
{
    __shared__ ushort_t Gs[2048 * 8];   // 32 KB packed G
    __shared__ ushort_t Ts[128 * 8];    // 2 KB packed T
    __shared__ float    wlds[2048];     // 8 KB pl3_w
    __shared__ float    sv[128];
    __shared__ float    ypart[2][128];
    __shared__ float    red[4];

    const int n   = blockIdx.x;
    const int tid = threadIdx.x;
    const int f   = tid & 127;
    const int hp  = tid >> 7;          // 0: heads 0,1  1: heads 2,3
    const bool act = (tid < 128);

    // ---- stage G (2048 chunks) + pl3_w (512 chunks) once ----
#pragma unroll
    for (int p = 0; p < 8; p++) {
        int ci = tid + p * 256;
        load_lds16(Gb + (size_t)ci * 8, &Gs[ci * 8]);
    }
    load_lds16(pl3_w + tid * 4,          &wlds[tid * 4]);
    load_lds16(pl3_w + (tid + 256) * 4,  &wlds[(tid + 256) * 4]);

    if (act) sv[f] = src[n * 128 + f];
    __syncthreads();

    const float si = sv[f];
    float S1 = block_reduce(act ? si : 0.f, 0, red);
    float S2 = block_reduce(act ? si * si : 0.f, 0, red);
    float S3 = block_reduce(act ? si * si * si : 0.f, 0, red);
    float S4 = block_reduce(act ? si * si * si * si : 0.f, 0, red);
    float amax = block_reduce(act ? fabsf(si) : 0.f, 1, red);

    float ph[2];
#pragma unroll
    for (int hh = 0; hh < 2; hh++) {
        const int h = hp * 2 + hh;
        ph[hh] = consts[1024 + h * 4 + 0] * si + consts[1024 + h * 4 + 2];
    }
    float pmax = block_reduce(fmaxf(fabsf(ph[0]), fabsf(ph[1])), 1, red);

    float tt[2];
    if (pmax * amax < 0.25f) {   // Taylor regime (block-uniform)
#pragma unroll
        for (int hh = 0; hh < 2; hh++) {
            float p = ph[hh];
            float num = fmaf(p, fmaf(p, fmaf(p, S4 * (1.f / 6.f), 0.5f * S3), S2), S1);
            float den = fmaf(p, fmaf(p, fmaf(p, S3 * (1.f / 6.f), 0.5f * S2), S1), 128.f);
            tt[hh] = num / den;
        }
    } else {                     // exact fallback
        float smax = block_reduce(act ? si : -3.4e38f, 1, red);
        float smin = -block_reduce(act ? -si : -3.4e38f, 1, red);
#pragma unroll
        for (int hh = 0; hh < 2; hh++) {
            float p = ph[hh];
            float m = fmaxf(p * smax, p * smin);
            float l = 0.f, t = 0.f;
            for (int j = 0; j < 128; j++) {
                float e = __expf(fmaf(p, sv[j], -m));
                l += e; t = fmaf(e, sv[j], t);
            }
            tt[hh] = t / l;
        }
    }

    // pack T row f: [t0 t1 t2 t3 1 0 0 0]
    Ts[f * 8 + hp * 2 + 0] = f2bf(tt[0]);
    Ts[f * 8 + hp * 2 + 1] = f2bf(tt[1]);
    if (act) {
        Ts[f * 8 + 4] = 0x3F80;
        Ts[f * 8 + 5] = 0; Ts[f * 8 + 6] = 0; Ts[f * 8 + 7] = 0;
    }
    __syncthreads();

    const int wave = tid >> 6, lane = tid & 63;
    const int mhalf = wave >> 1, wm = (wave & 1) * 64;
    const int mi = lane & 15, quad = lane >> 4;

    // A fragments: quad 0 carries data, quads 1..3 must be EXACT zero
    // (B fragments are broadcast-read with garbage beyond k=7).
    s16x8 af[4];
#pragma unroll
    for (int t = 0; t < 4; t++) {
        s16x8 v = *(const s16x8*)&Ts[(wm + t * 16 + mi) * 8];
        af[t] = (quad == 0) ? v : (s16x8)0;
    }

    float partial[4][4];
#pragma unroll
    for (int i = 0; i < 4; i++)
#pragma unroll
        for (int j = 0; j < 4; j++) partial[i][j] = 0.f;

#pragma unroll 2
    for (int mt = 0; mt < 64; mt++) {
        const int m0 = mhalf * 1024 + mt * 16;
        s16x8 bfr = *(const s16x8*)&Gs[(m0 + mi) * 8];   // broadcast across quads
        f32x4 acc[4];
#pragma unroll
        for (int tm = 0; tm < 4; tm++)
            acc[tm] = __builtin_amdgcn_mfma_f32_16x16x32_bf16(af[tm], bfr, (f32x4)0.f, 0, 0, 0);
        float w = wlds[m0 + mi];
#pragma unroll
        for (int tm = 0; tm < 4; tm++)
#pragma unroll
            for (int r = 0; r < 4; r++)
                partial[tm][r] = fmaf(fmaxf(acc[tm][r], 0.f), w, partial[tm][r]);
    }

    // reduce across the 16 mi lanes (same f rows)
#pragma unroll
    for (int tm = 0; tm < 4; tm++)
#pragma unroll
        for (int r = 0; r < 4; r++) {
            float v = partial[tm][r];
            v += __shfl_xor(v, 8);
            v += __shfl_xor(v, 4);
            v += __shfl_xor(v, 2);
            v += __shfl_xor(v, 1);
            if (mi == 0) ypart[mhalf][wm + tm * 16 + quad * 4 + r] = v;
        }
    __syncthreads();

    float yv = 0.f;
    if (act)
        yv = ypart[0][f] + ypart[1][f] + pl3_b[0] + sv[f];
    float s  = block_reduce(yv, 0, red);
    float ss = block_reduce(yv * yv, 0, red);
    float mean = s * (1.f / 128.f);
    float var  = ss * (1.f / 128.f) - mean * mean;
    float inv  = rsqrtf(var + 1e-5f);
    if (act)
        src1[n * 128 + f] = f2bf((yv - mean) * inv * pn1_g[f] + pn1_b[f]);
}

// LN over bf16: out = LN(a [+ b]) * g + beta;  out bf16 or fp32
template<bool OUTF32>
__global__ void ln_bf16(const ushort_t* __restrict__ a, const ushort_t* __restrict__ b,
                        const ushort_t* __restrict__ post, const float* __restrict__ g,
                        const float* __restrict__ beta, void* __restrict__ out, int D)
{
    __shared__ float red[4];
    const size_t row = blockIdx.x;
    const int tid = threadIdx.x;
    const int nit = D / blockDim.x;   // <= 4
    const ushort_t* ap = a + row * D;
    const ushort_t* bp = b ? b + row * D : nullptr;
    float xr[4];
    float s = 0.f, ss = 0.f;
    for (int i = 0; i < nit; i++) {
        int idx = i * blockDim.x + tid;
        float x = bf2f(ap[idx]) + (bp ? bf2f(bp[idx]) : 0.f);
        xr[i] = x; s += x; ss = fmaf(x, x, ss);
    }
    s  = block_reduce(s, 0, red);
    ss = block_reduce(ss, 0, red);
    float mean = s / D, var = ss / D - mean * mean;
    float inv = rsqrtf(var + 1e-5f);
    const ushort_t* pp = post ? post + row * D : nullptr;
    for (int i = 0; i < nit; i++) {
        int idx = i * blockDim.x + tid;
        float v = (xr[i] - mean) * inv * g[idx] + beta[idx];
        if (pp) v += bf2f(pp[idx]);
        if (OUTF32) ((float*)out)[row * D + idx] = v;
        else        ((ushort_t*)out)[row * D + idx] = f2bf(v);
    }
}

// LN over concat(a1[0:split], a2[split:]) + b  -> out (bf16), D=1024
__global__ void ln_cat(const ushort_t* __restrict__ a1, const ushort_t* __restrict__ a2,
                       int split, const ushort_t* __restrict__ b,
                       const float* __restrict__ g, const float* __restrict__ beta,
                       ushort_t* __restrict__ out, int D)
{
    __shared__ float red[4];
    const int row = blockIdx.x;
    const int tid = threadIdx.x;
    const int nit = D / blockDim.x;
    const ushort_t* ap = (row < split) ? a1 + (size_t)row * D : a2 + (size_t)(row - split) * D;
    const ushort_t* bp = b + (size_t)row * D;
    float xr[4];
    float s = 0.f, ss = 0.f;
    for (int i = 0; i < nit; i++) {
        int idx = i * blockDim.x + tid;
        float x = bf2f(ap[idx]) + bf2f(bp[idx]);
        xr[i] = x; s += x; ss = fmaf(x, x, ss);
    }
    s  = block_reduce(s, 0, red);
    ss = block_reduce(ss, 0, red);
    float mean = s / D, var = ss / D - mean * mean;
    float inv = rsqrtf(var + 1e-5f);
    for (int i = 0; i < nit; i++) {
        int idx = i * blockDim.x + tid;
        out[(size_t)row * D + idx] = f2bf((xr[i] - mean) * inv * g[idx] + beta[idx]);
    }
}

// row softmax in place, bf16, cols == 1024, 256 threads
__global__ __launch_bounds__(256)
void softmax_bf16(ushort_t* __restrict__ S)
{
    __shared__ float red[4];
    const size_t row = blockIdx.x;
    ushort_t* p = S + row * 1024;
    const int tid = threadIdx.x;
    uint2 u = *(const uint2*)&p[tid * 4];
    ushort_t* us = (ushort_t*)&u;
    float xr[4];
    float mx = -3.4e38f;
#pragma unroll
    for (int i = 0; i < 4; i++) { xr[i] = bf2f(us[i]); mx = fmaxf(mx, xr[i]); }
    mx = block_reduce(mx, 1, red);
    float sum = 0.f;
#pragma unroll
    for (int i = 0; i < 4; i++) { xr[i] = __expf(xr[i] - mx); sum += xr[i]; }
    sum = block_reduce(sum, 0, red);
    float inv = 1.f / sum;
#pragma unroll
    for (int i = 0; i < 4; i++) us[i] = f2bf(xr[i] * inv);
    *(uint2*)&p[tid * 4] = u;
}

// ---------------------------------------------------------------------------
// Host side
// ---------------------------------------------------------------------------
static inline void gemm_go(hipStream_t s, const ushort_t* A, const ushort_t* B,
                           const float* bias, ushort_t* C,
                           int M, int N, int K, int lda, int ldb, int ldc,
                           long sAz, long sBz, long sCz, int Z, float alpha,
                           bool relu,
                           long sA2 = 0, long sB2 = 0, long sC2 = 0, int zshift = 0)
{
    dim3 g(M / 128, N / 128, Z), b(256);
    if (relu) gemm_bf16<true ><<<g, b, 0, s>>>(A, B, bias, C, M, N, K, lda, ldb, ldc, sAz, sBz, sCz, sA2, sB2, sC2, zshift, alpha);
    else      gemm_bf16<false><<<g, b, 0, s>>>(A, B, bias, C, M, N, K, lda, ldb, ldc, sAz, sBz, sCz, sA2, sB2, sC2, zshift, alpha);
}

extern "C" void kernel_launch(void* const* d_in, const int* in_sizes, int n_in,
                              void* d_out, int out_size, void* d_ws, size_t ws_size,
                              hipStream_t stream)
{
    const float* src   = (const float*)d_in[0];
    const float* sa_wi = (const float*)d_in[2];
    const float* sa_bi = (const float*)d_in[3];
    const float* sa_wo = (const float*)d_in[4];
    const float* sa_bo = (const float*)d_in[5];
    const float* fa_wi = (const float*)d_in[6];
    const float* fa_bi = (const float*)d_in[7];
    const float* fa_wo = (const float*)d_in[8];
    const float* fa_bo = (const float*)d_in[9];
    const float* pl1_w = (const float*)d_in[10];
    const float* pl1_b = (const float*)d_in[11];
    const float* pl2_w = (const float*)d_in[12];
    const float* pl2_b = (const float*)d_in[13];
    const float* pl3_w = (const float*)d_in[14];
    const float* pl3_b = (const float*)d_in[15];
    const float* pl4_w = (const float*)d_in[16];
    const float* pl4_b = (const float*)d_in[17];
    const float* pl5_w = (const float*)d_in[18];
    const float* pl5_b = (const float*)d_in[19];
    const float* pl6_w = (const float*)d_in[20];
    const float* pl6_b = (const float*)d_in[21];
    const float* pl7_w = (const float*)d_in[22];
    const float* pl7_b = (const float*)d_in[23];
    const float* l1_w  = (const float*)d_in[24];
    const float* l1_b  = (const float*)d_in[25];
    const float* l2_w  = (const float*)d_in[26];
    const float* l2_b  = (const float*)d_in[27];
    const float* pn1_g = (const float*)d_in[28];
    const float* pn1_b = (const float*)d_in[29];
    const float* pn2_g = (const float*)d_in[30];
    const float* pn2_b = (const float*)d_in[31];
    const float* n1_g  = (const float*)d_in[32];
    const float* n1_b  = (const float*)d_in[33];
    const float* n2_g  = (const float*)d_in[34];
    const float* n2_b  = (const float*)d_in[35];

    float* ws  = (float*)d_ws;
    float* out = (float*)d_out;

    float* CONSTS = ws;                   // 16384 floats
    ushort_t* wsb = (ushort_t*)(ws + 16384);
    ushort_t* SAWIb  = wsb + 0;           // 3145728
    ushort_t* SAWOb  = wsb + 3145728;     // 1048576
    ushort_t* PL4b   = wsb + 4194304;     // 262144
    ushort_t* PL5b   = wsb + 4456448;     // 2097152
    ushort_t* PL6b   = wsb + 6553600;     // 2097152
    ushort_t* PL7b   = wsb + 8650752;     // 2097152
    ushort_t* L1b    = wsb + 10747904;    // 2097152
    ushort_t* L2b    = wsb + 12845056;    // 262144
    ushort_t* Gbb    = wsb + 13107200;    // 65536 (packed 2048x8 used)
    ushort_t* SRC1b  = wsb + 13172736;    // 294912
    ushort_t* HBIGb  = wsb + 13467648;    // 4718592 (2304x2048; also VT scratch)
    ushort_t* SRC1_b = wsb + 18186240;    // 2359296 (2304x1024)
    ushort_t* QKVb   = wsb + 20545536;    // 7077888 (2304x3072)
    ushort_t* SBUFb  = wsb + 27623424;    // 16777216 (scores; later cross scratch)
    ushort_t* OBUFb  = wsb + 44400640;    // 2097152
    ushort_t* SLb    = wsb + 46497792;    // 2097152
    ushort_t* SLPb   = wsb + 48594944;    // 2097152
    ushort_t* SOb    = wsb + 50692096;    // 2359296
    ushort_t* FFb    = wsb + 53051392;    // 294912
    // total ~107 MB

    // ---- one-time weight conversion (single dispatch) ----
    {
        CvtArgs a;
        const float* srcs[8] = { sa_wi, sa_wo, pl4_w, pl5_w, pl6_w, pl7_w, l1_w, l2_w };
        ushort_t*    dsts[8] = { SAWIb, SAWOb, PL4b, PL5b, PL6b, PL7b, L1b, L2b };
        int          ns[8]   = { 3145728, 1048576, 262144, 2097152, 2097152, 2097152, 2097152, 262144 };
        int cum = 0;
        for (int i = 0; i < 8; i++) { a.src[i] = srcs[i]; a.dst[i] = dsts[i]; cum += ns[i] / 4; a.end[i] = cum; }
        cvt_all<<<(cum + 255) / 256, 256, 0, stream>>>(a);
    }

    // ---- collapsed feature-attention block ----
    precomp1<<<1, 384, 0, stream>>>(fa_wi, fa_bi, pl1_w, pl1_b, CONSTS);
    precomp2<<<1, 128, 0, stream>>>(fa_wo, fa_bo, CONSTS);
    precomp3<<<8, 256, 0, stream>>>(pl2_w, pl2_b, CONSTS, Gbb);
    feat_mlp_ln<<<2304, 256, 0, stream>>>(src, CONSTS, Gbb, pl3_w, pl3_b, pn1_g, pn1_b, SRC1b);

    // ---- src1_ = relu(src1@pl4^T+b)@pl5^T+b ----
    gemm_go(stream, SRC1b, PL4b, pl4_b, HBIGb, 2304, 2048, 128, 128, 128, 2048, 0, 0, 0, 1, 1.f, true);
    gemm_go(stream, HBIGb, PL5b, pl5_b, SRC1_b, 2304, 1024, 2048, 2048, 2048, 1024, 0, 0, 0, 1, 1.f, false);

    // ---- qkv over ALL 2304 rows (rows 2048+ give cross-attn Q for free) ----
    gemm_go(stream, SRC1_b, SAWIb, sa_bi, QKVb, 2304, 3072, 1024, 1024, 1024, 3072, 0, 0, 0, 1, 1.f, false);
    const float iscale = 0.08838834764831845f;   // 1/sqrt(128)
    // V^T for self-attn (VT1 in dead HBIG region)
    ushort_t* VT1 = HBIGb;
    transp128<<<dim3(16, 1, 16), 256, 0, stream>>>(QKVb + 2048, VT1, 6144, 128, 3072, 131072);
    // self-attention on rows 0..2047, z = h + 8*b
    gemm_go(stream, QKVb, QKVb + 1024, nullptr, SBUFb,
            1024, 1024, 128, 6144, 6144, 1024, 128, 128, 1048576, 16, iscale, false,
            3072, 3072, 8388608, 3);
    softmax_bf16<<<16384, 256, 0, stream>>>(SBUFb);
    gemm_go(stream, SBUFb, VT1, nullptr, OBUFb,
            1024, 128, 1024, 1024, 1024, 2048, 1048576, 131072, 128, 16, 1.f, false,
            8388608, 1048576, 1024, 3);
    gemm_go(stream, OBUFb, SAWOb, sa_bo, HBIGb, 2048, 1024, 1024, 1024, 1024, 1024, 0, 0, 0, 1, 1.f, false);
    ln_bf16<false><<<2048, 256, 0, stream>>>(HBIGb, SRC1_b, nullptr, pn2_g, pn2_b, SLb, 1024);

    // ---- sl_ = ln(relu(sl@pl6^T)@pl7^T, pn2) + sl ----
    gemm_go(stream, SLb, PL6b, pl6_b, HBIGb, 2048, 2048, 1024, 1024, 1024, 2048, 0, 0, 0, 1, 1.f, true);
    gemm_go(stream, HBIGb, PL7b, pl7_b, OBUFb, 2048, 1024, 2048, 2048, 2048, 1024, 0, 0, 0, 1, 1.f, false);
    ln_bf16<false><<<2048, 256, 0, stream>>>(OBUFb, nullptr, SLb, pn2_g, pn2_b, SLPb, 1024);

    // ---- cross-attention: q from qkv rows 2048+, k/v from sl_ ----
    ushort_t* KV2 = SBUFb;               // 2048x2048
    ushort_t* S2  = SBUFb + 4456448;     // 16x128x1024
    ushort_t* SR  = SBUFb + 6553600;     // 256x1024
    gemm_go(stream, SLPb, SAWIb + 1024 * 1024, sa_bi + 1024, KV2, 2048, 2048, 1024, 1024, 1024, 2048, 0, 0, 0, 1, 1.f, false);
    ushort_t* VT2 = HBIGb;               // HBIG dead until l1
    transp128<<<dim3(16, 1, 16), 256, 0, stream>>>(KV2 + 1024, VT2, 4096, 128, 2048, 131072);
    gemm_go(stream, QKVb + 2048 * 3072, KV2, nullptr, S2,
            128, 1024, 128, 6144, 4096, 1024, 128, 128, 131072, 16, iscale, false,
            3072, 2048, 1048576, 3);
    softmax_bf16<<<2048, 256, 0, stream>>>(S2);
    gemm_go(stream, S2, VT2, nullptr, OBUFb,
            128, 128, 1024, 1024, 1024, 2048, 131072, 131072, 128, 16, 1.f, false,
            1048576, 1048576, 1024, 3);
    gemm_go(stream, OBUFb, SAWOb, sa_bo, SR, 256, 1024, 1024, 1024, 1024, 1024, 0, 0, 0, 1, 1.f, false);

    // ---- so = ln(concat(sl, sr) + src1_, n1)  (single dispatch) ----
    ln_cat<<<2304, 256, 0, stream>>>(SLb, SR, 2048, SRC1_b, n1_g, n1_b, SOb, 1024);

    // ---- ff = relu(so@l1^T)@l2^T ; out = ln(src1 + ff, n2) ----
    gemm_go(stream, SOb, L1b, l1_b, HBIGb, 2304, 2048, 1024, 1024, 1024, 2048, 0, 0, 0, 1, 1.f, true);
    gemm_go(stream, HBIGb, L2b, l2_b, FFb, 2304, 128, 2048, 2048, 2048, 128, 0, 0, 0, 1, 1.f, false);
    ln_bf16<true><<<2304, 128, 0, stream>>>(FFb, SRC1b, nullptr, n2_g, n2_b, out, 128);
}

// Round 7
// 591.010 us; speedup vs baseline: 3.5043x; 1.0816x over previous
//
#include <hip/hip_runtime.h>

using s16x8 = __attribute__((ext_vector_type(8))) short;   // 8 bf16 (4 VGPRs)
using f32x4 = __attribute__((ext_vector_type(4))) float;   // MFMA accumulator
typedef unsigned short ushort_t;

__device__ __forceinline__ unsigned short f2bf(float f) {
    union { float f; unsigned u; } v; v.f = f;
    unsigned u = v.u + 0x7FFFu + ((v.u >> 16) & 1u);   // round-nearest-even
    return (unsigned short)(u >> 16);
}
__device__ __forceinline__ float bf2f(unsigned short h) {
    union { unsigned u; float f; } v; v.u = ((unsigned)h) << 16;
    return v.f;
}

// block reduction: op==0 sum, op==1 max. lds >= blockDim/64 floats.
__device__ __forceinline__ float block_reduce(float v, int op, float* lds) {
    const int lane = threadIdx.x & 63;
    const int w    = threadIdx.x >> 6;
    const int nw   = blockDim.x >> 6;
#pragma unroll
    for (int off = 32; off > 0; off >>= 1) {
        float o = __shfl_down(v, off, 64);
        v = op ? fmaxf(v, o) : (v + o);
    }
    __syncthreads();
    if (lane == 0) lds[w] = v;
    __syncthreads();
    float r = lds[0];
    for (int i = 1; i < nw; i++) r = op ? fmaxf(r, lds[i]) : (r + lds[i]);
    return r;
}

__device__ __forceinline__ void load_lds16(const void* g, void* l) {
    __builtin_amdgcn_global_load_lds(
        (const __attribute__((address_space(1))) unsigned int*)g,
        (__attribute__((address_space(3))) unsigned int*)l, 16, 0, 0);
}

// ---------------------------------------------------------------------------
// fp32 -> bf16 weight conversion, all 8 weights in one dispatch
// ---------------------------------------------------------------------------
struct CvtArgs { const float* src[8]; ushort_t* dst[8]; int end[8]; };

__global__ __launch_bounds__(256)
void cvt_all(CvtArgs a)
{
    int i = blockIdx.x * 256 + threadIdx.x;
    int j = 0;
    while (j < 8 && i >= a.end[j]) j++;
    if (j >= 8) return;
    int li = i - (j ? a.end[j - 1] : 0);
    float4 v = *(const float4*)&a.src[j][(size_t)li * 4];
    ushort_t u[4] = { f2bf(v.x), f2bf(v.y), f2bf(v.z), f2bf(v.w) };
    *(uint2*)&a.dst[j][(size_t)li * 4] = *(uint2*)u;
}

// ---------------------------------------------------------------------------
// bf16 GEMM, BK=32, XOR-swizzled LDS.
//   Normal:  C[z] = act(alpha*A[z]@B[z]^T + bias), bf16 out.
//   SPLITK:  blockIdx.z = ks*zmod + zb; computes K-chunk [ks*ksplen, +ksplen)
//            and writes raw fp32 (alpha applied, no bias/act) to
//            Cp + ks*pstride + usual index.
// M%128==0, N%128==0, K%32==0, lda/ldb multiples of 8, pointers 16B-aligned.
// ---------------------------------------------------------------------------
template<bool RELU, bool SPLITK>
__global__ __launch_bounds__(256, 2)
void gemm_bf16(const ushort_t* __restrict__ A, const ushort_t* __restrict__ B,
               const float* __restrict__ bias, ushort_t* __restrict__ C,
               float* __restrict__ Cp, long pstride, int ksplen, int zmod,
               int M, int N, int K, int lda, int ldb, int ldc,
               long sAz, long sBz, long sCz, long sA2, long sB2, long sC2,
               int zshift, float alpha)
{
    __shared__ ushort_t As[128 * 32];
    __shared__ ushort_t Bs[128 * 32];

    const int tid = threadIdx.x;
    int zz = blockIdx.z;
    int ks = 0, z = zz;
    if (SPLITK) { ks = zz / zmod; z = zz - ks * zmod; }
    const int z1  = z & ((1 << zshift) - 1);
    const int z2  = z >> zshift;
    const int m0  = blockIdx.x * 128;
    const int n0  = blockIdx.y * 128;

    const ushort_t* Ab = A + (size_t)z1 * sAz + (size_t)z2 * sA2 + (size_t)m0 * lda;
    const ushort_t* Bb = B + (size_t)z1 * sBz + (size_t)z2 * sB2 + (size_t)n0 * ldb;

    const int wave = tid >> 6, lane = tid & 63;
    const int wm = (wave & 1) * 64, wn = (wave >> 1) * 64;
    const int mi = lane & 15, quad = lane >> 4;

    f32x4 acc[4][4];
#pragma unroll
    for (int i = 0; i < 4; i++)
#pragma unroll
        for (int j = 0; j < 4; j++) acc[i][j] = (f32x4)0.f;

    // chunk ci -> LDS slot (r=ci>>2, g'=ci&3); fetch global group g'^((r>>1)&3)
    const int r_0 = tid >> 2,           g_0 = (tid & 3) ^ ((r_0 >> 1) & 3);
    const int r_1 = (tid + 256) >> 2,   g_1 = (tid & 3) ^ ((r_1 >> 1) & 3);

    const int kbeg = SPLITK ? ks * ksplen : 0;
    const int kend = SPLITK ? kbeg + ksplen : K;

    for (int k0 = kbeg; k0 < kend; k0 += 32) {
        load_lds16(Ab + (size_t)r_0 * lda + k0 + g_0 * 8, &As[tid * 8]);
        load_lds16(Ab + (size_t)r_1 * lda + k0 + g_1 * 8, &As[(tid + 256) * 8]);
        load_lds16(Bb + (size_t)r_0 * ldb + k0 + g_0 * 8, &Bs[tid * 8]);
        load_lds16(Bb + (size_t)r_1 * ldb + k0 + g_1 * 8, &Bs[(tid + 256) * 8]);
        __syncthreads();

        s16x8 af[4], bfr[4];
#pragma unroll
        for (int t = 0; t < 4; t++) {
            int r = wm + t * 16 + mi;
            af[t] = *(const s16x8*)&As[r * 32 + ((quad ^ ((r >> 1) & 3)) * 8)];
        }
#pragma unroll
        for (int t = 0; t < 4; t++) {
            int r = wn + t * 16 + mi;
            bfr[t] = *(const s16x8*)&Bs[r * 32 + ((quad ^ ((r >> 1) & 3)) * 8)];
        }
#pragma unroll
        for (int tm = 0; tm < 4; tm++)
#pragma unroll
            for (int tn = 0; tn < 4; tn++)
                acc[tm][tn] = __builtin_amdgcn_mfma_f32_16x16x32_bf16(af[tm], bfr[tn], acc[tm][tn], 0, 0, 0);
        __syncthreads();
    }

    if (SPLITK) {
        float* Cf = Cp + (size_t)ks * pstride + (size_t)z1 * sCz + (size_t)z2 * sC2;
#pragma unroll
        for (int tn = 0; tn < 4; tn++) {
            int col = n0 + wn + tn * 16 + mi;
#pragma unroll
            for (int tm = 0; tm < 4; tm++)
#pragma unroll
                for (int r = 0; r < 4; r++) {
                    int row = m0 + wm + tm * 16 + quad * 4 + r;
                    Cf[(size_t)row * ldc + col] = acc[tm][tn][r] * alpha;
                }
        }
    } else {
#pragma unroll
        for (int tn = 0; tn < 4; tn++) {
            int col = n0 + wn + tn * 16 + mi;
            float bv = bias ? bias[col] : 0.f;
#pragma unroll
            for (int tm = 0; tm < 4; tm++) {
#pragma unroll
                for (int r = 0; r < 4; r++) {
                    int row = m0 + wm + tm * 16 + quad * 4 + r;
                    float v = acc[tm][tn][r] * alpha + bv;
                    if (RELU) v = fmaxf(v, 0.f);
                    C[(size_t)z1 * sCz + (size_t)z2 * sC2 + (size_t)row * ldc + col] = f2bf(v);
                }
            }
        }
    }
}

// sum P fp32 partials (+bias per col) -> bf16
__global__ __launch_bounds__(256)
void sum_cvt(const float* __restrict__ parts, long pstride, int P,
             const float* __restrict__ bias, int ldc,
             ushort_t* __restrict__ out, int total4)
{
    int i = blockIdx.x * 256 + threadIdx.x;
    if (i >= total4) return;
    size_t idx = (size_t)i * 4;
    float4 s = *(const float4*)&parts[idx];
    for (int p = 1; p < P; p++) {
        float4 v = *(const float4*)&parts[(size_t)p * pstride + idx];
        s.x += v.x; s.y += v.y; s.z += v.z; s.w += v.w;
    }
    if (bias) {
        int col = (int)(idx % (size_t)ldc);
        s.x += bias[col]; s.y += bias[col + 1]; s.z += bias[col + 2]; s.w += bias[col + 3];
    }
    ushort_t u[4] = { f2bf(s.x), f2bf(s.y), f2bf(s.z), f2bf(s.w) };
    *(uint2*)&out[idx] = *(uint2*)u;
}

// final LN over (sum of P fp32 partials + bias + bf16 residual), D=128, fp32 out
__global__ __launch_bounds__(128)
void ln_part(const float* __restrict__ parts, long pstride, int P,
             const float* __restrict__ bias, const ushort_t* __restrict__ resid,
             const float* __restrict__ g, const float* __restrict__ beta,
             float* __restrict__ out)
{
    __shared__ float red[4];
    const int r = blockIdx.x, c = threadIdx.x;
    float x = bias[c] + bf2f(resid[r * 128 + c]);
    for (int p = 0; p < P; p++) x += parts[(size_t)p * pstride + (size_t)r * 128 + c];
    float s  = block_reduce(x, 0, red);
    float ss = block_reduce(x * x, 0, red);
    float mean = s * (1.f / 128.f);
    float var  = ss * (1.f / 128.f) - mean * mean;
    float inv  = rsqrtf(var + 1e-5f);
    out[(size_t)r * 128 + c] = (x - mean) * inv * g[c] + beta[c];
}

// ---------------------------------------------------------------------------
// V transpose: out[z][d][n] = in[z1*inz1 + z2*inz2 + n*ldin + d], d<128.
// ---------------------------------------------------------------------------
__global__ __launch_bounds__(256)
void transp128(const ushort_t* __restrict__ in, ushort_t* __restrict__ out,
               int ldin, long inz1, long inz2, long outz)
{
    __shared__ ushort_t T[64][136];
    const int z = blockIdx.z, z1 = z & 7, z2 = z >> 3;
    const int n0 = blockIdx.x * 64;
    const ushort_t* ip = in + (size_t)z1 * inz1 + (size_t)z2 * inz2;
    const int rr = threadIdx.x >> 2, cg = (threadIdx.x & 3) * 32;
#pragma unroll
    for (int c = 0; c < 4; c++) {
        s16x8 v = *(const s16x8*)(ip + (size_t)(n0 + rr) * ldin + cg + c * 8);
        *(s16x8*)&T[rr][cg + c * 8] = v;
    }
    __syncthreads();
    const int d = threadIdx.x >> 1, j0 = (threadIdx.x & 1) * 32;
    ushort_t* op = out + (size_t)z * outz + (size_t)d * 1024 + n0 + j0;
#pragma unroll
    for (int c = 0; c < 4; c++) {
        s16x8 v;
#pragma unroll
        for (int j = 0; j < 8; j++) v[j] = (short)T[j0 + c * 8 + j][d];
        *(s16x8*)(op + c * 8) = v;
    }
}

// ---------------------------------------------------------------------------
// Collapsed feature-attention precompute
// consts (floats): u@0(384) v@512(384) abcd@1024(16) wv@1088(512) c0@1600(128)
// Gb packed: bf16[2048][8]: cols 0..3 = g[m][h], col 4 = g0[m], 5..7 = 0
// ---------------------------------------------------------------------------
__global__ void precomp1(const float* __restrict__ fa_wi, const float* __restrict__ fa_bi,
                         const float* __restrict__ pl1_w, const float* __restrict__ pl1_b,
                         float* __restrict__ consts)
{
    int j = threadIdx.x;
    if (j < 384) {
        float u = 0.f, v = 0.f;
        for (int k = 0; k < 128; k++) {
            float w = fa_wi[j * 128 + k];
            u = fmaf(w, pl1_w[k], u);
            v = fmaf(w, pl1_b[k], v);
        }
        consts[j]       = u;
        consts[512 + j] = v + fa_bi[j];
    }
}

__global__ void precomp2(const float* __restrict__ fa_wo, const float* __restrict__ fa_bo,
                         float* __restrict__ consts)
{
    int tid = threadIdx.x;  // 128
    const float* u = consts;
    const float* v = consts + 512;
    if (tid < 16) {
        int h = tid >> 2, w = tid & 3;
        const float* ql = (w < 2) ? u : v;
        const float* kr = ((w & 1) == 0) ? u : v;
        float acc = 0.f;
        for (int d = 0; d < 32; d++) acc += ql[h * 32 + d] * kr[128 + h * 32 + d];
        consts[1024 + tid] = acc * 0.17677669529663687f;
    }
#pragma unroll
    for (int h = 0; h < 4; h++) {
        float acc = 0.f;
        for (int d = 0; d < 32; d++)
            acc = fmaf(fa_wo[tid * 128 + h * 32 + d], u[256 + h * 32 + d], acc);
        consts[1088 + h * 128 + tid] = acc;
    }
    float c0 = fa_bo[tid];
    for (int idx = 0; idx < 128; idx++)
        c0 = fmaf(fa_wo[tid * 128 + idx], v[256 + idx], c0);
    consts[1600 + tid] = c0;
}

__global__ void precomp3(const float* __restrict__ pl2_w, const float* __restrict__ pl2_b,
                         const float* __restrict__ consts, ushort_t* __restrict__ Gb)
{
    int m = blockIdx.x * 256 + threadIdx.x;   // 2048
    const float* wv = consts + 1088;
    const float* c0 = consts + 1600;
    float a0 = 0.f, ah[4] = {0.f, 0.f, 0.f, 0.f};
    for (int j = 0; j < 128; j++) {
        float w = pl2_w[m * 128 + j];
        ah[0] = fmaf(w, wv[0 * 128 + j], ah[0]);
        ah[1] = fmaf(w, wv[1 * 128 + j], ah[1]);
        ah[2] = fmaf(w, wv[2 * 128 + j], ah[2]);
        ah[3] = fmaf(w, wv[3 * 128 + j], ah[3]);
        a0    = fmaf(w, c0[j], a0);
    }
    ushort_t row[8];
#pragma unroll
    for (int h = 0; h < 4; h++) row[h] = f2bf(ah[h]);
    row[4] = f2bf(a0 + pl2_b[m]);
    row[5] = row[6] = row[7] = 0;
    *(uint4*)&Gb[m * 8] = *(uint4*)row;
}

// ---------------------------------------------------------------------------
// Fused: feature-attention (moment softmax) + pl2/pl3 MLP (MFMA) + LN.
// 512 threads (8 waves): wave = (mq, fhalf); each wave 64 f-rows x 512 m,
// 32 barrier-free m-iterations. G (32 KB) + T (2 KB) in LDS; pl3_w from L1.
// ---------------------------------------------------------------------------
__global__ __launch_bounds__(512, 4)
void feat_mlp_ln(const float* __restrict__ src, const float* __restrict__ consts,
                 const ushort_t* __restrict__ Gb, const float* __restrict__ pl3_w,
                 const float* __restrict__ pl3_b, const float* __restrict__ pn1_g,
                 const float* __restrict__ pn1_b, ushort_t* __restrict__ src1)
{
    __shared__ ushort_t Gs[2048 * 8];   // 32 KB packed G
    __shared__ ushort_t Ts[128 * 8];    // 2 KB packed T
    __shared__ float    sv[128];
    __shared__ float    ypart[4][128];
    __shared__ float    red[8];

    const int n   = blockIdx.x;
    const int tid = threadIdx.x;        // 0..511
    const int f   = tid & 127;
    const int h   = tid >> 7;           // head 0..3 (one per thread)
    const bool act = (tid < 128);

    // ---- stage G once ----
#pragma unroll
    for (int p = 0; p < 4; p++) {
        int ci = tid + p * 512;
        load_lds16(Gb + (size_t)ci * 8, &Gs[ci * 8]);
    }
    if (act) sv[f] = src[n * 128 + f];
    __syncthreads();

    const float si = sv[f];
    float S1 = block_reduce(act ? si : 0.f, 0, red);
    float S2 = block_reduce(act ? si * si : 0.f, 0, red);
    float S3 = block_reduce(act ? si * si * si : 0.f, 0, red);
    float S4 = block_reduce(act ? si * si * si * si : 0.f, 0, red);
    float amax = block_reduce(act ? fabsf(si) : 0.f, 1, red);

    const float p_ = consts[1024 + h * 4 + 0] * si + consts[1024 + h * 4 + 2];
    float pmax = block_reduce(fabsf(p_), 1, red);

    float tt;
    if (pmax * amax < 0.25f) {   // Taylor regime (block-uniform)
        float num = fmaf(p_, fmaf(p_, fmaf(p_, S4 * (1.f / 6.f), 0.5f * S3), S2), S1);
        float den = fmaf(p_, fmaf(p_, fmaf(p_, S3 * (1.f / 6.f), 0.5f * S2), S1), 128.f);
        tt = num / den;
    } else {                     // exact fallback
        float smax = block_reduce(act ? si : -3.4e38f, 1, red);
        float smin = -block_reduce(act ? -si : -3.4e38f, 1, red);
        float m = fmaxf(p_ * smax, p_ * smin);
        float l = 0.f, t = 0.f;
        for (int j = 0; j < 128; j++) {
            float e = __expf(fmaf(p_, sv[j], -m));
            l += e; t = fmaf(e, sv[j], t);
        }
        tt = t / l;
    }

    // pack T row f: [t0 t1 t2 t3 1 0 0 0]
    Ts[f * 8 + h] = f2bf(tt);
    if (act) {
        Ts[f * 8 + 4] = 0x3F80;
        Ts[f * 8 + 5] = 0; Ts[f * 8 + 6] = 0; Ts[f * 8 + 7] = 0;
    }
    __syncthreads();

    const int wave = tid >> 6, lane = tid & 63;
    const int wm = (wave & 1) * 64;     // f half
    const int mq = wave >> 1;           // m quarter (0..3)
    const int mi = lane & 15, quad = lane >> 4;

    // A fragments: quad 0 carries data, quads 1..3 exact zero (B is broadcast).
    s16x8 af[4];
#pragma unroll
    for (int t = 0; t < 4; t++) {
        s16x8 v = *(const s16x8*)&Ts[(wm + t * 16 + mi) * 8];
        af[t] = (quad == 0) ? v : (s16x8)0;
    }

    float partial[4][4];
#pragma unroll
    for (int i = 0; i < 4; i++)
#pragma unroll
        for (int j = 0; j < 4; j++) partial[i][j] = 0.f;

#pragma unroll 4
    for (int mt = 0; mt < 32; mt++) {
        const int m0 = mq * 512 + mt * 16;
        s16x8 bfr = *(const s16x8*)&Gs[(m0 + mi) * 8];   // bcast across quads
        float w = pl3_w[m0 + mi];                        // L1-resident
        f32x4 acc[4];
#pragma unroll
        for (int tm = 0; tm < 4; tm++)
            acc[tm] = __builtin_amdgcn_mfma_f32_16x16x32_bf16(af[tm], bfr, (f32x4)0.f, 0, 0, 0);
#pragma unroll
        for (int tm = 0; tm < 4; tm++)
#pragma unroll
            for (int r = 0; r < 4; r++)
                partial[tm][r] = fmaf(fmaxf(acc[tm][r], 0.f), w, partial[tm][r]);
    }

    // reduce across the 16 mi lanes (same f rows)
#pragma unroll
    for (int tm = 0; tm < 4; tm++)
#pragma unroll
        for (int r = 0; r < 4; r++) {
            float v = partial[tm][r];
            v += __shfl_xor(v, 8);
            v += __shfl_xor(v, 4);
            v += __shfl_xor(v, 2);
            v += __shfl_xor(v, 1);
            if (mi == 0) ypart[mq][wm + tm * 16 + quad * 4 + r] = v;
        }
    __syncthreads();

    float yv = 0.f;
    if (act)
        yv = ypart[0][f] + ypart[1][f] + ypart[2][f] + ypart[3][f] + pl3_b[0] + sv[f];
    float s  = block_reduce(yv, 0, red);
    float ss = block_reduce(yv * yv, 0, red);
    float mean = s * (1.f / 128.f);
    float var  = ss * (1.f / 128.f) - mean * mean;
    float inv  = rsqrtf(var + 1e-5f);
    if (act)
        src1[n * 128 + f] = f2bf((yv - mean) * inv * pn1_g[f] + pn1_b[f]);
}

// LN over bf16: out = LN(a [+ b]) * g + beta;  out bf16 or fp32
template<bool OUTF32>
__global__ void ln_bf16(const ushort_t* __restrict__ a, const ushort_t* __restrict__ b,
                        const ushort_t* __restrict__ post, const float* __restrict__ g,
                        const float* __restrict__ beta, void* __restrict__ out, int D)
{
    __shared__ float red[4];
    const size_t row = blockIdx.x;
    const int tid = threadIdx.x;
    const int nit = D / blockDim.x;   // <= 4
    const ushort_t* ap = a + row * D;
    const ushort_t* bp = b ? b + row * D : nullptr;
    float xr[4];
    float s = 0.f, ss = 0.f;
    for (int i = 0; i < nit; i++) {
        int idx = i * blockDim.x + tid;
        float x = bf2f(ap[idx]) + (bp ? bf2f(bp[idx]) : 0.f);
        xr[i] = x; s += x; ss = fmaf(x, x, ss);
    }
    s  = block_reduce(s, 0, red);
    ss = block_reduce(ss, 0, red);
    float mean = s / D, var = ss / D - mean * mean;
    float inv = rsqrtf(var + 1e-5f);
    const ushort_t* pp = post ? post + row * D : nullptr;
    for (int i = 0; i < nit; i++) {
        int idx = i * blockDim.x + tid;
        float v = (xr[i] - mean) * inv * g[idx] + beta[idx];
        if (pp) v += bf2f(pp[idx]);
        if (OUTF32) ((float*)out)[row * D + idx] = v;
        else        ((ushort_t*)out)[row * D + idx] = f2bf(v);
    }
}

// LN over concat(a1[0:split], a2[split:]) + b  -> out (bf16), D=1024
__global__ void ln_cat(const ushort_t* __restrict__ a1, const ushort_t* __restrict__ a2,
                       int split, const ushort_t* __restrict__ b,
                       const float* __restrict__ g, const float* __restrict__ beta,
                       ushort_t* __restrict__ out, int D)
{
    __shared__ float red[4];
    const int row = blockIdx.x;
    const int tid = threadIdx.x;
    const int nit = D / blockDim.x;
    const ushort_t* ap = (row < split) ? a1 + (size_t)row * D : a2 + (size_t)(row - split) * D;
    const ushort_t* bp = b + (size_t)row * D;
    float xr[4];
    float s = 0.f, ss = 0.f;
    for (int i = 0; i < nit; i++) {
        int idx = i * blockDim.x + tid;
        float x = bf2f(ap[idx]) + bf2f(bp[idx]);
        xr[i] = x; s += x; ss = fmaf(x, x, ss);
    }
    s  = block_reduce(s, 0, red);
    ss = block_reduce(ss, 0, red);
    float mean = s / D, var = ss / D - mean * mean;
    float inv = rsqrtf(var + 1e-5f);
    for (int i = 0; i < nit; i++) {
        int idx = i * blockDim.x + tid;
        out[(size_t)row * D + idx] = f2bf((xr[i] - mean) * inv * g[idx] + beta[idx]);
    }
}

// row softmax in place, bf16, cols == 1024, 256 threads
__global__ __launch_bounds__(256)
void softmax_bf16(ushort_t* __restrict__ S)
{
    __shared__ float red[4];
    const size_t row = blockIdx.x;
    ushort_t* p = S + row * 1024;
    const int tid = threadIdx.x;
    uint2 u = *(const uint2*)&p[tid * 4];
    ushort_t* us = (ushort_t*)&u;
    float xr[4];
    float mx = -3.4e38f;
#pragma unroll
    for (int i = 0; i < 4; i++) { xr[i] = bf2f(us[i]); mx = fmaxf(mx, xr[i]); }
    mx = block_reduce(mx, 1, red);
    float sum = 0.f;
#pragma unroll
    for (int i = 0; i < 4; i++) { xr[i] = __expf(xr[i] - mx); sum += xr[i]; }
    sum = block_reduce(sum, 0, red);
    float inv = 1.f / sum;
#pragma unroll
    for (int i = 0; i < 4; i++) us[i] = f2bf(xr[i] * inv);
    *(uint2*)&p[tid * 4] = u;
}

// ---------------------------------------------------------------------------
// Host side
// ---------------------------------------------------------------------------
static inline void gemm_go(hipStream_t s, const ushort_t* A, const ushort_t* B,
                           const float* bias, ushort_t* C,
                           int M, int N, int K, int lda, int ldb, int ldc,
                           long sAz, long sBz, long sCz, int Z, float alpha,
                           bool relu,
                           long sA2 = 0, long sB2 = 0, long sC2 = 0, int zshift = 0,
                           int ksplit = 1, float* Cp = nullptr, long pstride = 0)
{
    dim3 g(M / 128, N / 128, Z * ksplit), b(256);
    int ksplen = K / ksplit;
    if (ksplit > 1)
        gemm_bf16<false, true ><<<g, b, 0, s>>>(A, B, nullptr, nullptr, Cp, pstride, ksplen, Z,
            M, N, K, lda, ldb, ldc, sAz, sBz, sCz, sA2, sB2, sC2, zshift, alpha);
    else if (relu)
        gemm_bf16<true,  false><<<g, b, 0, s>>>(A, B, bias, C, nullptr, 0, 0, Z,
            M, N, K, lda, ldb, ldc, sAz, sBz, sCz, sA2, sB2, sC2, zshift, alpha);
    else
        gemm_bf16<false, false><<<g, b, 0, s>>>(A, B, bias, C, nullptr, 0, 0, Z,
            M, N, K, lda, ldb, ldc, sAz, sBz, sCz, sA2, sB2, sC2, zshift, alpha);
}

extern "C" void kernel_launch(void* const* d_in, const int* in_sizes, int n_in,
                              void* d_out, int out_size, void* d_ws, size_t ws_size,
                              hipStream_t stream)
{
    const float* src   = (const float*)d_in[0];
    const float* sa_wi = (const float*)d_in[2];
    const float* sa_bi = (const float*)d_in[3];
    const float* sa_wo = (const float*)d_in[4];
    const float* sa_bo = (const float*)d_in[5];
    const float* fa_wi = (const float*)d_in[6];
    const float* fa_bi = (const float*)d_in[7];
    const float* fa_wo = (const float*)d_in[8];
    const float* fa_bo = (const float*)d_in[9];
    const float* pl1_w = (const float*)d_in[10];
    const float* pl1_b = (const float*)d_in[11];
    const float* pl2_w = (const float*)d_in[12];
    const float* pl2_b = (const float*)d_in[13];
    const float* pl3_w = (const float*)d_in[14];
    const float* pl3_b = (const float*)d_in[15];
    const float* pl4_w = (const float*)d_in[16];
    const float* pl4_b = (const float*)d_in[17];
    const float* pl5_w = (const float*)d_in[18];
    const float* pl5_b = (const float*)d_in[19];
    const float* pl6_w = (const float*)d_in[20];
    const float* pl6_b = (const float*)d_in[21];
    const float* pl7_w = (const float*)d_in[22];
    const float* pl7_b = (const float*)d_in[23];
    const float* l1_w  = (const float*)d_in[24];
    const float* l1_b  = (const float*)d_in[25];
    const float* l2_w  = (const float*)d_in[26];
    const float* l2_b  = (const float*)d_in[27];
    const float* pn1_g = (const float*)d_in[28];
    const float* pn1_b = (const float*)d_in[29];
    const float* pn2_g = (const float*)d_in[30];
    const float* pn2_b = (const float*)d_in[31];
    const float* n1_g  = (const float*)d_in[32];
    const float* n1_b  = (const float*)d_in[33];
    const float* n2_g  = (const float*)d_in[34];
    const float* n2_b  = (const float*)d_in[35];

    float* ws  = (float*)d_ws;
    float* out = (float*)d_out;

    float* CONSTS = ws;                   // 16384 floats
    ushort_t* wsb = (ushort_t*)(ws + 16384);
    ushort_t* SAWIb  = wsb + 0;           // 3145728
    ushort_t* SAWOb  = wsb + 3145728;     // 1048576
    ushort_t* PL4b   = wsb + 4194304;     // 262144
    ushort_t* PL5b   = wsb + 4456448;     // 2097152
    ushort_t* PL6b   = wsb + 6553600;     // 2097152
    ushort_t* PL7b   = wsb + 8650752;     // 2097152
    ushort_t* L1b    = wsb + 10747904;    // 2097152
    ushort_t* L2b    = wsb + 12845056;    // 262144
    ushort_t* Gbb    = wsb + 13107200;    // 65536 (packed 2048x8 used)
    ushort_t* SRC1b  = wsb + 13172736;    // 294912
    ushort_t* HBIGb  = wsb + 13467648;    // 4718592 (2304x2048; also VT scratch)
    ushort_t* SRC1_b = wsb + 18186240;    // 2359296 (2304x1024)
    ushort_t* QKVb   = wsb + 20545536;    // 7077888 (2304x3072)
    ushort_t* SBUFb  = wsb + 27623424;    // 16777216 (scores / cross scratch / splitK partials)
    ushort_t* OBUFb  = wsb + 44400640;    // 2097152
    ushort_t* SLb    = wsb + 46497792;    // 2097152
    ushort_t* SLPb   = wsb + 48594944;    // 2097152
    ushort_t* SOb    = wsb + 50692096;    // 2359296
    // total ~107 MB
    float* PARTS = (float*)SBUFb;         // fp32 split-K partials (time-shared)

    // ---- one-time weight conversion (single dispatch) ----
    {
        CvtArgs a;
        const float* srcs[8] = { sa_wi, sa_wo, pl4_w, pl5_w, pl6_w, pl7_w, l1_w, l2_w };
        ushort_t*    dsts[8] = { SAWIb, SAWOb, PL4b, PL5b, PL6b, PL7b, L1b, L2b };
        int          ns[8]   = { 3145728, 1048576, 262144, 2097152, 2097152, 2097152, 2097152, 262144 };
        int cum = 0;
        for (int i = 0; i < 8; i++) { a.src[i] = srcs[i]; a.dst[i] = dsts[i]; cum += ns[i] / 4; a.end[i] = cum; }
        cvt_all<<<(cum + 255) / 256, 256, 0, stream>>>(a);
    }

    // ---- collapsed feature-attention block ----
    precomp1<<<1, 384, 0, stream>>>(fa_wi, fa_bi, pl1_w, pl1_b, CONSTS);
    precomp2<<<1, 128, 0, stream>>>(fa_wo, fa_bo, CONSTS);
    precomp3<<<8, 256, 0, stream>>>(pl2_w, pl2_b, CONSTS, Gbb);
    feat_mlp_ln<<<2304, 512, 0, stream>>>(src, CONSTS, Gbb, pl3_w, pl3_b, pn1_g, pn1_b, SRC1b);

    // ---- src1_ = relu(src1@pl4^T+b)@pl5^T+b  (pl5 split-K x2: 144->288 blocks) ----
    gemm_go(stream, SRC1b, PL4b, pl4_b, HBIGb, 2304, 2048, 128, 128, 128, 2048, 0, 0, 0, 1, 1.f, true);
    gemm_go(stream, HBIGb, PL5b, nullptr, nullptr, 2304, 1024, 2048, 2048, 2048, 1024, 0, 0, 0, 1, 1.f, false,
            0, 0, 0, 0, 2, PARTS, 2359296);
    sum_cvt<<<2304, 256, 0, stream>>>(PARTS, 2359296, 2, pl5_b, 1024, SRC1_b, 589824);

    // ---- qkv over ALL 2304 rows (rows 2048+ give cross-attn Q for free) ----
    gemm_go(stream, SRC1_b, SAWIb, sa_bi, QKVb, 2304, 3072, 1024, 1024, 1024, 3072, 0, 0, 0, 1, 1.f, false);
    const float iscale = 0.08838834764831845f;   // 1/sqrt(128)
    ushort_t* VT1 = HBIGb;
    transp128<<<dim3(16, 1, 16), 256, 0, stream>>>(QKVb + 2048, VT1, 6144, 128, 3072, 131072);
    // self-attention on rows 0..2047, z = h + 8*b
    gemm_go(stream, QKVb, QKVb + 1024, nullptr, SBUFb,
            1024, 1024, 128, 6144, 6144, 1024, 128, 128, 1048576, 16, iscale, false,
            3072, 3072, 8388608, 3);
    softmax_bf16<<<16384, 256, 0, stream>>>(SBUFb);
    gemm_go(stream, SBUFb, VT1, nullptr, OBUFb,
            1024, 128, 1024, 1024, 1024, 2048, 1048576, 131072, 128, 16, 1.f, false,
            8388608, 1048576, 1024, 3);
    gemm_go(stream, OBUFb, SAWOb, sa_bo, HBIGb, 2048, 1024, 1024, 1024, 1024, 1024, 0, 0, 0, 1, 1.f, false);
    ln_bf16<false><<<2048, 256, 0, stream>>>(HBIGb, SRC1_b, nullptr, pn2_g, pn2_b, SLb, 1024);

    // ---- sl_ = ln(relu(sl@pl6^T)@pl7^T, pn2) + sl ----
    gemm_go(stream, SLb, PL6b, pl6_b, HBIGb, 2048, 2048, 1024, 1024, 1024, 2048, 0, 0, 0, 1, 1.f, true);
    gemm_go(stream, HBIGb, PL7b, pl7_b, OBUFb, 2048, 1024, 2048, 2048, 2048, 1024, 0, 0, 0, 1, 1.f, false);
    ln_bf16<false><<<2048, 256, 0, stream>>>(OBUFb, nullptr, SLb, pn2_g, pn2_b, SLPb, 1024);

    // ---- cross-attention: q from qkv rows 2048+, k/v from sl_ ----
    ushort_t* KV2 = SBUFb;               // 2048x2048
    ushort_t* S2  = SBUFb + 4456448;     // 16x128x1024
    ushort_t* SR  = SBUFb + 6553600;     // 256x1024
    gemm_go(stream, SLPb, SAWIb + 1024 * 1024, sa_bi + 1024, KV2, 2048, 2048, 1024, 1024, 1024, 2048, 0, 0, 0, 1, 1.f, false);
    ushort_t* VT2 = HBIGb;
    transp128<<<dim3(16, 1, 16), 256, 0, stream>>>(KV2 + 1024, VT2, 4096, 128, 2048, 131072);
    gemm_go(stream, QKVb + 2048 * 3072, KV2, nullptr, S2,
            128, 1024, 128, 6144, 4096, 1024, 128, 128, 131072, 16, iscale, false,
            3072, 2048, 1048576, 3);
    softmax_bf16<<<2048, 256, 0, stream>>>(S2);
    // S2-PV split-K x8: 16 -> 128 blocks (partials in dead KV2 region = SBUF base)
    gemm_go(stream, S2, VT2, nullptr, nullptr,
            128, 128, 1024, 1024, 1024, 2048, 131072, 131072, 128, 16, 1.f, false,
            1048576, 1048576, 1024, 3, 8, PARTS, 262144);
    sum_cvt<<<256, 256, 0, stream>>>(PARTS, 262144, 8, nullptr, 2048, OBUFb, 65536);
    // sr-out split-K x8: 16 -> 128 blocks
    gemm_go(stream, OBUFb, SAWOb, nullptr, nullptr, 256, 1024, 1024, 1024, 1024, 1024, 0, 0, 0, 1, 1.f, false,
            0, 0, 0, 0, 8, PARTS, 262144);
    sum_cvt<<<256, 256, 0, stream>>>(PARTS, 262144, 8, sa_bo, 1024, SR, 65536);

    // ---- so = ln(concat(sl, sr) + src1_, n1)  (single dispatch) ----
    ln_cat<<<2304, 256, 0, stream>>>(SLb, SR, 2048, SRC1_b, n1_g, n1_b, SOb, 1024);

    // ---- ff = relu(so@l1^T)@l2^T ; out = ln(src1 + ff, n2) ----
    gemm_go(stream, SOb, L1b, l1_b, HBIGb, 2304, 2048, 1024, 1024, 1024, 2048, 0, 0, 0, 1, 1.f, true);
    // l2 split-K x8: 18 -> 144 blocks; final LN reads the partials directly
    gemm_go(stream, HBIGb, L2b, nullptr, nullptr, 2304, 128, 2048, 2048, 2048, 128, 0, 0, 0, 1, 1.f, false,
            0, 0, 0, 0, 8, PARTS, 294912);
    ln_part<<<2304, 128, 0, stream>>>(PARTS, 294912, 8, l2_b, SRC1b, n2_g, n2_b, out);
}

// Round 8
// 588.969 us; speedup vs baseline: 3.5164x; 1.0035x over previous
//
#include <hip/hip_runtime.h>

using s16x8 = __attribute__((ext_vector_type(8))) short;   // 8 bf16 (4 VGPRs)
using f32x4 = __attribute__((ext_vector_type(4))) float;   // MFMA accumulator
using f32x2 = __attribute__((ext_vector_type(2))) float;   // packed fp32
typedef unsigned short ushort_t;

__device__ __forceinline__ unsigned short f2bf(float f) {
    union { float f; unsigned u; } v; v.f = f;
    unsigned u = v.u + 0x7FFFu + ((v.u >> 16) & 1u);   // round-nearest-even
    return (unsigned short)(u >> 16);
}
__device__ __forceinline__ float bf2f(unsigned short h) {
    union { unsigned u; float f; } v; v.u = ((unsigned)h) << 16;
    return v.f;
}

// block reduction: op==0 sum, op==1 max. lds >= blockDim/64 floats.
__device__ __forceinline__ float block_reduce(float v, int op, float* lds) {
    const int lane = threadIdx.x & 63;
    const int w    = threadIdx.x >> 6;
    const int nw   = blockDim.x >> 6;
#pragma unroll
    for (int off = 32; off > 0; off >>= 1) {
        float o = __shfl_down(v, off, 64);
        v = op ? fmaxf(v, o) : (v + o);
    }
    __syncthreads();
    if (lane == 0) lds[w] = v;
    __syncthreads();
    float r = lds[0];
    for (int i = 1; i < nw; i++) r = op ? fmaxf(r, lds[i]) : (r + lds[i]);
    return r;
}

__device__ __forceinline__ void load_lds16(const void* g, void* l) {
    __builtin_amdgcn_global_load_lds(
        (const __attribute__((address_space(1))) unsigned int*)g,
        (__attribute__((address_space(3))) unsigned int*)l, 16, 0, 0);
}

// ---------------------------------------------------------------------------
// fp32 -> bf16 weight conversion, all 8 weights in one dispatch
// ---------------------------------------------------------------------------
struct CvtArgs { const float* src[8]; ushort_t* dst[8]; int end[8]; };

__global__ __launch_bounds__(256)
void cvt_all(CvtArgs a)
{
    int i = blockIdx.x * 256 + threadIdx.x;
    int j = 0;
    while (j < 8 && i >= a.end[j]) j++;
    if (j >= 8) return;
    int li = i - (j ? a.end[j - 1] : 0);
    float4 v = *(const float4*)&a.src[j][(size_t)li * 4];
    ushort_t u[4] = { f2bf(v.x), f2bf(v.y), f2bf(v.z), f2bf(v.w) };
    *(uint2*)&a.dst[j][(size_t)li * 4] = *(uint2*)u;
}

// ---------------------------------------------------------------------------
// bf16 GEMM, BK=32, XOR-swizzled LDS.
//   Normal:  C[z] = act(alpha*A[z]@B[z]^T + bias), bf16 out.
//   SPLITK:  blockIdx.z = ks*zmod + zb; K-chunk [ks*ksplen,+ksplen), raw fp32
//            (alpha applied, no bias/act) to Cp + ks*pstride + usual index.
// ---------------------------------------------------------------------------
template<bool RELU, bool SPLITK>
__global__ __launch_bounds__(256, 2)
void gemm_bf16(const ushort_t* __restrict__ A, const ushort_t* __restrict__ B,
               const float* __restrict__ bias, ushort_t* __restrict__ C,
               float* __restrict__ Cp, long pstride, int ksplen, int zmod,
               int M, int N, int K, int lda, int ldb, int ldc,
               long sAz, long sBz, long sCz, long sA2, long sB2, long sC2,
               int zshift, float alpha)
{
    __shared__ ushort_t As[128 * 32];
    __shared__ ushort_t Bs[128 * 32];

    const int tid = threadIdx.x;
    int zz = blockIdx.z;
    int ks = 0, z = zz;
    if (SPLITK) { ks = zz / zmod; z = zz - ks * zmod; }
    const int z1  = z & ((1 << zshift) - 1);
    const int z2  = z >> zshift;
    const int m0  = blockIdx.x * 128;
    const int n0  = blockIdx.y * 128;

    const ushort_t* Ab = A + (size_t)z1 * sAz + (size_t)z2 * sA2 + (size_t)m0 * lda;
    const ushort_t* Bb = B + (size_t)z1 * sBz + (size_t)z2 * sB2 + (size_t)n0 * ldb;

    const int wave = tid >> 6, lane = tid & 63;
    const int wm = (wave & 1) * 64, wn = (wave >> 1) * 64;
    const int mi = lane & 15, quad = lane >> 4;

    f32x4 acc[4][4];
#pragma unroll
    for (int i = 0; i < 4; i++)
#pragma unroll
        for (int j = 0; j < 4; j++) acc[i][j] = (f32x4)0.f;

    const int r_0 = tid >> 2,           g_0 = (tid & 3) ^ ((r_0 >> 1) & 3);
    const int r_1 = (tid + 256) >> 2,   g_1 = (tid & 3) ^ ((r_1 >> 1) & 3);

    const int kbeg = SPLITK ? ks * ksplen : 0;
    const int kend = SPLITK ? kbeg + ksplen : K;

    for (int k0 = kbeg; k0 < kend; k0 += 32) {
        load_lds16(Ab + (size_t)r_0 * lda + k0 + g_0 * 8, &As[tid * 8]);
        load_lds16(Ab + (size_t)r_1 * lda + k0 + g_1 * 8, &As[(tid + 256) * 8]);
        load_lds16(Bb + (size_t)r_0 * ldb + k0 + g_0 * 8, &Bs[tid * 8]);
        load_lds16(Bb + (size_t)r_1 * ldb + k0 + g_1 * 8, &Bs[(tid + 256) * 8]);
        __syncthreads();

        s16x8 af[4], bfr[4];
#pragma unroll
        for (int t = 0; t < 4; t++) {
            int r = wm + t * 16 + mi;
            af[t] = *(const s16x8*)&As[r * 32 + ((quad ^ ((r >> 1) & 3)) * 8)];
        }
#pragma unroll
        for (int t = 0; t < 4; t++) {
            int r = wn + t * 16 + mi;
            bfr[t] = *(const s16x8*)&Bs[r * 32 + ((quad ^ ((r >> 1) & 3)) * 8)];
        }
#pragma unroll
        for (int tm = 0; tm < 4; tm++)
#pragma unroll
            for (int tn = 0; tn < 4; tn++)
                acc[tm][tn] = __builtin_amdgcn_mfma_f32_16x16x32_bf16(af[tm], bfr[tn], acc[tm][tn], 0, 0, 0);
        __syncthreads();
    }

    if (SPLITK) {
        float* Cf = Cp + (size_t)ks * pstride + (size_t)z1 * sCz + (size_t)z2 * sC2;
#pragma unroll
        for (int tn = 0; tn < 4; tn++) {
            int col = n0 + wn + tn * 16 + mi;
#pragma unroll
            for (int tm = 0; tm < 4; tm++)
#pragma unroll
                for (int r = 0; r < 4; r++) {
                    int row = m0 + wm + tm * 16 + quad * 4 + r;
                    Cf[(size_t)row * ldc + col] = acc[tm][tn][r] * alpha;
                }
        }
    } else {
#pragma unroll
        for (int tn = 0; tn < 4; tn++) {
            int col = n0 + wn + tn * 16 + mi;
            float bv = bias ? bias[col] : 0.f;
#pragma unroll
            for (int tm = 0; tm < 4; tm++) {
#pragma unroll
                for (int r = 0; r < 4; r++) {
                    int row = m0 + wm + tm * 16 + quad * 4 + r;
                    float v = acc[tm][tn][r] * alpha + bv;
                    if (RELU) v = fmaxf(v, 0.f);
                    C[(size_t)z1 * sCz + (size_t)z2 * sC2 + (size_t)row * ldc + col] = f2bf(v);
                }
            }
        }
    }
}

// sum P fp32 partials (+bias per col) [relu] -> bf16
template<bool RELU>
__global__ __launch_bounds__(256)
void sum_cvt(const float* __restrict__ parts, long pstride, int P,
             const float* __restrict__ bias, int ldc,
             ushort_t* __restrict__ out, int total4)
{
    int i = blockIdx.x * 256 + threadIdx.x;
    if (i >= total4) return;
    size_t idx = (size_t)i * 4;
    float4 s = *(const float4*)&parts[idx];
    for (int p = 1; p < P; p++) {
        float4 v = *(const float4*)&parts[(size_t)p * pstride + idx];
        s.x += v.x; s.y += v.y; s.z += v.z; s.w += v.w;
    }
    if (bias) {
        int col = (int)(idx % (size_t)ldc);
        s.x += bias[col]; s.y += bias[col + 1]; s.z += bias[col + 2]; s.w += bias[col + 3];
    }
    if (RELU) {
        s.x = fmaxf(s.x, 0.f); s.y = fmaxf(s.y, 0.f);
        s.z = fmaxf(s.z, 0.f); s.w = fmaxf(s.w, 0.f);
    }
    ushort_t u[4] = { f2bf(s.x), f2bf(s.y), f2bf(s.z), f2bf(s.w) };
    *(uint2*)&out[idx] = *(uint2*)u;
}

// final LN over (sum of P fp32 partials + bias + bf16 residual), D=128, fp32 out
__global__ __launch_bounds__(128)
void ln_part(const float* __restrict__ parts, long pstride, int P,
             const float* __restrict__ bias, const ushort_t* __restrict__ resid,
             const float* __restrict__ g, const float* __restrict__ beta,
             float* __restrict__ out)
{
    __shared__ float red[4];
    const int r = blockIdx.x, c = threadIdx.x;
    float x = bias[c] + bf2f(resid[r * 128 + c]);
    for (int p = 0; p < P; p++) x += parts[(size_t)p * pstride + (size_t)r * 128 + c];
    float s  = block_reduce(x, 0, red);
    float ss = block_reduce(x * x, 0, red);
    float mean = s * (1.f / 128.f);
    float var  = ss * (1.f / 128.f) - mean * mean;
    float inv  = rsqrtf(var + 1e-5f);
    out[(size_t)r * 128 + c] = (x - mean) * inv * g[c] + beta[c];
}

// ---------------------------------------------------------------------------
// V transpose: out[z][d][n] = in[z1*inz1 + z2*inz2 + n*ldin + d], d<128.
// ---------------------------------------------------------------------------
__global__ __launch_bounds__(256)
void transp128(const ushort_t* __restrict__ in, ushort_t* __restrict__ out,
               int ldin, long inz1, long inz2, long outz)
{
    __shared__ ushort_t T[64][136];
    const int z = blockIdx.z, z1 = z & 7, z2 = z >> 3;
    const int n0 = blockIdx.x * 64;
    const ushort_t* ip = in + (size_t)z1 * inz1 + (size_t)z2 * inz2;
    const int rr = threadIdx.x >> 2, cg = (threadIdx.x & 3) * 32;
#pragma unroll
    for (int c = 0; c < 4; c++) {
        s16x8 v = *(const s16x8*)(ip + (size_t)(n0 + rr) * ldin + cg + c * 8);
        *(s16x8*)&T[rr][cg + c * 8] = v;
    }
    __syncthreads();
    const int d = threadIdx.x >> 1, j0 = (threadIdx.x & 1) * 32;
    ushort_t* op = out + (size_t)z * outz + (size_t)d * 1024 + n0 + j0;
#pragma unroll
    for (int c = 0; c < 4; c++) {
        s16x8 v;
#pragma unroll
        for (int j = 0; j < 8; j++) v[j] = (short)T[j0 + c * 8 + j][d];
        *(s16x8*)(op + c * 8) = v;
    }
}

// ---------------------------------------------------------------------------
// Collapsed feature-attention precompute
// consts (floats): u@0(384) v@512(384) abcd@1024(16) wv@1088(512) c0@1600(128)
// Gb packed: bf16[2048][8]: cols 0..3 = g[m][h], col 4 = g0[m], 5..7 = 0
// ---------------------------------------------------------------------------
__global__ void precomp1(const float* __restrict__ fa_wi, const float* __restrict__ fa_bi,
                         const float* __restrict__ pl1_w, const float* __restrict__ pl1_b,
                         float* __restrict__ consts)
{
    int j = threadIdx.x;
    if (j < 384) {
        float u = 0.f, v = 0.f;
        for (int k = 0; k < 128; k++) {
            float w = fa_wi[j * 128 + k];
            u = fmaf(w, pl1_w[k], u);
            v = fmaf(w, pl1_b[k], v);
        }
        consts[j]       = u;
        consts[512 + j] = v + fa_bi[j];
    }
}

__global__ void precomp2(const float* __restrict__ fa_wo, const float* __restrict__ fa_bo,
                         float* __restrict__ consts)
{
    int tid = threadIdx.x;  // 128
    const float* u = consts;
    const float* v = consts + 512;
    if (tid < 16) {
        int h = tid >> 2, w = tid & 3;
        const float* ql = (w < 2) ? u : v;
        const float* kr = ((w & 1) == 0) ? u : v;
        float acc = 0.f;
        for (int d = 0; d < 32; d++) acc += ql[h * 32 + d] * kr[128 + h * 32 + d];
        consts[1024 + tid] = acc * 0.17677669529663687f;
    }
#pragma unroll
    for (int h = 0; h < 4; h++) {
        float acc = 0.f;
        for (int d = 0; d < 32; d++)
            acc = fmaf(fa_wo[tid * 128 + h * 32 + d], u[256 + h * 32 + d], acc);
        consts[1088 + h * 128 + tid] = acc;
    }
    float c0 = fa_bo[tid];
    for (int idx = 0; idx < 128; idx++)
        c0 = fmaf(fa_wo[tid * 128 + idx], v[256 + idx], c0);
    consts[1600 + tid] = c0;
}

__global__ void precomp3(const float* __restrict__ pl2_w, const float* __restrict__ pl2_b,
                         const float* __restrict__ consts, ushort_t* __restrict__ Gb)
{
    int m = blockIdx.x * 256 + threadIdx.x;   // 2048
    const float* wv = consts + 1088;
    const float* c0 = consts + 1600;
    float a0 = 0.f, ah[4] = {0.f, 0.f, 0.f, 0.f};
    for (int j = 0; j < 128; j++) {
        float w = pl2_w[m * 128 + j];
        ah[0] = fmaf(w, wv[0 * 128 + j], ah[0]);
        ah[1] = fmaf(w, wv[1 * 128 + j], ah[1]);
        ah[2] = fmaf(w, wv[2 * 128 + j], ah[2]);
        ah[3] = fmaf(w, wv[3 * 128 + j], ah[3]);
        a0    = fmaf(w, c0[j], a0);
    }
    ushort_t row[8];
#pragma unroll
    for (int h = 0; h < 4; h++) row[h] = f2bf(ah[h]);
    row[4] = f2bf(a0 + pl2_b[m]);
    row[5] = row[6] = row[7] = 0;
    *(uint4*)&Gb[m * 8] = *(uint4*)row;
}

// ---------------------------------------------------------------------------
// Fused: feature-attention (moment softmax) + pl2/pl3 MLP (MFMA) + LN.
// 512 threads (8 waves): wave = (mq, fhalf); each wave 64 f x 512 m,
// 32 barrier-free m-iterations. G (32 KB) + pl3_w (8 KB) + T (2 KB) in LDS.
// LDS ~46 KB -> 3 blocks/CU = 24 waves (75% occupancy).
// ---------------------------------------------------------------------------
__global__ __launch_bounds__(512, 6)
void feat_mlp_ln(const float* __restrict__ src, const float* __restrict__ consts,
                 const ushort_t* __restrict__ Gb, const float* __restrict__ pl3_w,
                 const float* __restrict__ pl3_b, const float* __restrict__ pn1_g,
                 const float* __restrict__ pn1_b, ushort_t* __restrict__ src1)
{
    __shared__ ushort_t Gs[2048 * 8];   // 32 KB packed G
    __shared__ float    wlds[2048];     // 8 KB pl3_w
    __shared__ ushort_t Ts[128 * 8];    // 2 KB packed T
    __shared__ float    sv[128];
    __shared__ float    ypart[4][128];
    __shared__ float    red[8];

    const int n   = blockIdx.x;
    const int tid = threadIdx.x;        // 0..511
    const int f   = tid & 127;
    const int h   = tid >> 7;           // head 0..3 (one per thread)
    const bool act = (tid < 128);

    // ---- stage G + pl3_w once ----
#pragma unroll
    for (int p = 0; p < 4; p++) {
        int ci = tid + p * 512;
        load_lds16(Gb + (size_t)ci * 8, &Gs[ci * 8]);
    }
    load_lds16(pl3_w + tid * 4, &wlds[tid * 4]);
    if (act) sv[f] = src[n * 128 + f];
    __syncthreads();

    const float si = sv[f];
    float S1 = block_reduce(act ? si : 0.f, 0, red);
    float S2 = block_reduce(act ? si * si : 0.f, 0, red);
    float S3 = block_reduce(act ? si * si * si : 0.f, 0, red);
    float S4 = block_reduce(act ? si * si * si * si : 0.f, 0, red);
    float amax = block_reduce(act ? fabsf(si) : 0.f, 1, red);

    const float p_ = consts[1024 + h * 4 + 0] * si + consts[1024 + h * 4 + 2];
    float pmax = block_reduce(fabsf(p_), 1, red);

    float tt;
    if (pmax * amax < 0.25f) {   // Taylor regime (block-uniform)
        float num = fmaf(p_, fmaf(p_, fmaf(p_, S4 * (1.f / 6.f), 0.5f * S3), S2), S1);
        float den = fmaf(p_, fmaf(p_, fmaf(p_, S3 * (1.f / 6.f), 0.5f * S2), S1), 128.f);
        tt = num / den;
    } else {                     // exact fallback
        float smax = block_reduce(act ? si : -3.4e38f, 1, red);
        float smin = -block_reduce(act ? -si : -3.4e38f, 1, red);
        float m = fmaxf(p_ * smax, p_ * smin);
        float l = 0.f, t = 0.f;
        for (int j = 0; j < 128; j++) {
            float e = __expf(fmaf(p_, sv[j], -m));
            l += e; t = fmaf(e, sv[j], t);
        }
        tt = t / l;
    }

    // pack T row f: [t0 t1 t2 t3 1 0 0 0]
    Ts[f * 8 + h] = f2bf(tt);
    if (act) {
        Ts[f * 8 + 4] = 0x3F80;
        Ts[f * 8 + 5] = 0; Ts[f * 8 + 6] = 0; Ts[f * 8 + 7] = 0;
    }
    __syncthreads();

    const int wave = tid >> 6, lane = tid & 63;
    const int wm = (wave & 1) * 64;     // f half
    const int mq = wave >> 1;           // m quarter (0..3)
    const int mi = lane & 15, quad = lane >> 4;

    // A fragments: quad 0 carries data, quads 1..3 exact zero (B is broadcast).
    s16x8 af[4];
#pragma unroll
    for (int t = 0; t < 4; t++) {
        s16x8 v = *(const s16x8*)&Ts[(wm + t * 16 + mi) * 8];
        af[t] = (quad == 0) ? v : (s16x8)0;
    }

    f32x2 partial2[4][2];
#pragma unroll
    for (int i = 0; i < 4; i++) { partial2[i][0] = (f32x2)0.f; partial2[i][1] = (f32x2)0.f; }
    const f32x2 zero2 = (f32x2)0.f;

#pragma unroll 4
    for (int mt = 0; mt < 32; mt++) {
        const int m0 = mq * 512 + mt * 16;
        s16x8 bfr = *(const s16x8*)&Gs[(m0 + mi) * 8];   // bcast across quads
        float w = wlds[m0 + mi];
        f32x2 w2 = { w, w };
        f32x4 acc[4];
#pragma unroll
        for (int tm = 0; tm < 4; tm++)
            acc[tm] = __builtin_amdgcn_mfma_f32_16x16x32_bf16(af[tm], bfr, (f32x4)0.f, 0, 0, 0);
#pragma unroll
        for (int tm = 0; tm < 4; tm++) {
            f32x2* pa = (f32x2*)&acc[tm];
#pragma unroll
            for (int i = 0; i < 2; i++) {
                f32x2 r = __builtin_elementwise_max(pa[i], zero2);   // v_pk_max_f32
                partial2[tm][i] = r * w2 + partial2[tm][i];          // v_pk_fma_f32
            }
        }
    }

    // reduce across the 16 mi lanes (same f rows)
#pragma unroll
    for (int tm = 0; tm < 4; tm++)
#pragma unroll
        for (int r = 0; r < 4; r++) {
            float v = partial2[tm][r >> 1][r & 1];
            v += __shfl_xor(v, 8);
            v += __shfl_xor(v, 4);
            v += __shfl_xor(v, 2);
            v += __shfl_xor(v, 1);
            if (mi == 0) ypart[mq][wm + tm * 16 + quad * 4 + r] = v;
        }
    __syncthreads();

    float yv = 0.f;
    if (act)
        yv = ypart[0][f] + ypart[1][f] + ypart[2][f] + ypart[3][f] + pl3_b[0] + sv[f];
    float s  = block_reduce(yv, 0, red);
    float ss = block_reduce(yv * yv, 0, red);
    float mean = s * (1.f / 128.f);
    float var  = ss * (1.f / 128.f) - mean * mean;
    float inv  = rsqrtf(var + 1e-5f);
    if (act)
        src1[n * 128 + f] = f2bf((yv - mean) * inv * pn1_g[f] + pn1_b[f]);
}

// LN over bf16: out = LN(a [+ b]) * g + beta;  out bf16 or fp32
template<bool OUTF32>
__global__ void ln_bf16(const ushort_t* __restrict__ a, const ushort_t* __restrict__ b,
                        const ushort_t* __restrict__ post, const float* __restrict__ g,
                        const float* __restrict__ beta, void* __restrict__ out, int D)
{
    __shared__ float red[4];
    const size_t row = blockIdx.x;
    const int tid = threadIdx.x;
    const int nit = D / blockDim.x;   // <= 4
    const ushort_t* ap = a + row * D;
    const ushort_t* bp = b ? b + row * D : nullptr;
    float xr[4];
    float s = 0.f, ss = 0.f;
    for (int i = 0; i < nit; i++) {
        int idx = i * blockDim.x + tid;
        float x = bf2f(ap[idx]) + (bp ? bf2f(bp[idx]) : 0.f);
        xr[i] = x; s += x; ss = fmaf(x, x, ss);
    }
    s  = block_reduce(s, 0, red);
    ss = block_reduce(ss, 0, red);
    float mean = s / D, var = ss / D - mean * mean;
    float inv = rsqrtf(var + 1e-5f);
    const ushort_t* pp = post ? post + row * D : nullptr;
    for (int i = 0; i < nit; i++) {
        int idx = i * blockDim.x + tid;
        float v = (xr[i] - mean) * inv * g[idx] + beta[idx];
        if (pp) v += bf2f(pp[idx]);
        if (OUTF32) ((float*)out)[row * D + idx] = v;
        else        ((ushort_t*)out)[row * D + idx] = f2bf(v);
    }
}

// LN over concat(a1[0:split], a2[split:]) + b  -> out (bf16), D=1024
__global__ void ln_cat(const ushort_t* __restrict__ a1, const ushort_t* __restrict__ a2,
                       int split, const ushort_t* __restrict__ b,
                       const float* __restrict__ g, const float* __restrict__ beta,
                       ushort_t* __restrict__ out, int D)
{
    __shared__ float red[4];
    const int row = blockIdx.x;
    const int tid = threadIdx.x;
    const int nit = D / blockDim.x;
    const ushort_t* ap = (row < split) ? a1 + (size_t)row * D : a2 + (size_t)(row - split) * D;
    const ushort_t* bp = b + (size_t)row * D;
    float xr[4];
    float s = 0.f, ss = 0.f;
    for (int i = 0; i < nit; i++) {
        int idx = i * blockDim.x + tid;
        float x = bf2f(ap[idx]) + bf2f(bp[idx]);
        xr[i] = x; s += x; ss = fmaf(x, x, ss);
    }
    s  = block_reduce(s, 0, red);
    ss = block_reduce(ss, 0, red);
    float mean = s / D, var = ss / D - mean * mean;
    float inv = rsqrtf(var + 1e-5f);
    for (int i = 0; i < nit; i++) {
        int idx = i * blockDim.x + tid;
        out[(size_t)row * D + idx] = f2bf((xr[i] - mean) * inv * g[idx] + beta[idx]);
    }
}

// row softmax in place, bf16, cols == 1024, 256 threads
__global__ __launch_bounds__(256)
void softmax_bf16(ushort_t* __restrict__ S)
{
    __shared__ float red[4];
    const size_t row = blockIdx.x;
    ushort_t* p = S + row * 1024;
    const int tid = threadIdx.x;
    uint2 u = *(const uint2*)&p[tid * 4];
    ushort_t* us = (ushort_t*)&u;
    float xr[4];
    float mx = -3.4e38f;
#pragma unroll
    for (int i = 0; i < 4; i++) { xr[i] = bf2f(us[i]); mx = fmaxf(mx, xr[i]); }
    mx = block_reduce(mx, 1, red);
    float sum = 0.f;
#pragma unroll
    for (int i = 0; i < 4; i++) { xr[i] = __expf(xr[i] - mx); sum += xr[i]; }
    sum = block_reduce(sum, 0, red);
    float inv = 1.f / sum;
#pragma unroll
    for (int i = 0; i < 4; i++) us[i] = f2bf(xr[i] * inv);
    *(uint2*)&p[tid * 4] = u;
}

// ---------------------------------------------------------------------------
// Host side
// ---------------------------------------------------------------------------
static inline void gemm_go(hipStream_t s, const ushort_t* A, const ushort_t* B,
                           const float* bias, ushort_t* C,
                           int M, int N, int K, int lda, int ldb, int ldc,
                           long sAz, long sBz, long sCz, int Z, float alpha,
                           bool relu,
                           long sA2 = 0, long sB2 = 0, long sC2 = 0, int zshift = 0,
                           int ksplit = 1, float* Cp = nullptr, long pstride = 0)
{
    dim3 g(M / 128, N / 128, Z * ksplit), b(256);
    int ksplen = K / ksplit;
    if (ksplit > 1)
        gemm_bf16<false, true ><<<g, b, 0, s>>>(A, B, nullptr, nullptr, Cp, pstride, ksplen, Z,
            M, N, K, lda, ldb, ldc, sAz, sBz, sCz, sA2, sB2, sC2, zshift, alpha);
    else if (relu)
        gemm_bf16<true,  false><<<g, b, 0, s>>>(A, B, bias, C, nullptr, 0, 0, Z,
            M, N, K, lda, ldb, ldc, sAz, sBz, sCz, sA2, sB2, sC2, zshift, alpha);
    else
        gemm_bf16<false, false><<<g, b, 0, s>>>(A, B, bias, C, nullptr, 0, 0, Z,
            M, N, K, lda, ldb, ldc, sAz, sBz, sCz, sA2, sB2, sC2, zshift, alpha);
}

extern "C" void kernel_launch(void* const* d_in, const int* in_sizes, int n_in,
                              void* d_out, int out_size, void* d_ws, size_t ws_size,
                              hipStream_t stream)
{
    const float* src   = (const float*)d_in[0];
    const float* sa_wi = (const float*)d_in[2];
    const float* sa_bi = (const float*)d_in[3];
    const float* sa_wo = (const float*)d_in[4];
    const float* sa_bo = (const float*)d_in[5];
    const float* fa_wi = (const float*)d_in[6];
    const float* fa_bi = (const float*)d_in[7];
    const float* fa_wo = (const float*)d_in[8];
    const float* fa_bo = (const float*)d_in[9];
    const float* pl1_w = (const float*)d_in[10];
    const float* pl1_b = (const float*)d_in[11];
    const float* pl2_w = (const float*)d_in[12];
    const float* pl2_b = (const float*)d_in[13];
    const float* pl3_w = (const float*)d_in[14];
    const float* pl3_b = (const float*)d_in[15];
    const float* pl4_w = (const float*)d_in[16];
    const float* pl4_b = (const float*)d_in[17];
    const float* pl5_w = (const float*)d_in[18];
    const float* pl5_b = (const float*)d_in[19];
    const float* pl6_w = (const float*)d_in[20];
    const float* pl6_b = (const float*)d_in[21];
    const float* pl7_w = (const float*)d_in[22];
    const float* pl7_b = (const float*)d_in[23];
    const float* l1_w  = (const float*)d_in[24];
    const float* l1_b  = (const float*)d_in[25];
    const float* l2_w  = (const float*)d_in[26];
    const float* l2_b  = (const float*)d_in[27];
    const float* pn1_g = (const float*)d_in[28];
    const float* pn1_b = (const float*)d_in[29];
    const float* pn2_g = (const float*)d_in[30];
    const float* pn2_b = (const float*)d_in[31];
    const float* n1_g  = (const float*)d_in[32];
    const float* n1_b  = (const float*)d_in[33];
    const float* n2_g  = (const float*)d_in[34];
    const float* n2_b  = (const float*)d_in[35];

    float* ws  = (float*)d_ws;
    float* out = (float*)d_out;

    float* CONSTS = ws;                   // 16384 floats
    ushort_t* wsb = (ushort_t*)(ws + 16384);
    ushort_t* SAWIb  = wsb + 0;           // 3145728
    ushort_t* SAWOb  = wsb + 3145728;     // 1048576
    ushort_t* PL4b   = wsb + 4194304;     // 262144
    ushort_t* PL5b   = wsb + 4456448;     // 2097152
    ushort_t* PL6b   = wsb + 6553600;     // 2097152
    ushort_t* PL7b   = wsb + 8650752;     // 2097152
    ushort_t* L1b    = wsb + 10747904;    // 2097152
    ushort_t* L2b    = wsb + 12845056;    // 262144
    ushort_t* Gbb    = wsb + 13107200;    // 65536 (packed 2048x8 used)
    ushort_t* SRC1b  = wsb + 13172736;    // 294912
    ushort_t* HBIGb  = wsb + 13467648;    // 4718592 (2304x2048; also VT scratch)
    ushort_t* SRC1_b = wsb + 18186240;    // 2359296 (2304x1024)
    ushort_t* QKVb   = wsb + 20545536;    // 7077888 (2304x3072)
    ushort_t* SBUFb  = wsb + 27623424;    // 16777216 (scores / cross / splitK partials)
    ushort_t* OBUFb  = wsb + 44400640;    // 2097152 (contiguous after SBUF)
    ushort_t* SLb    = wsb + 46497792;    // 2097152
    ushort_t* SLPb   = wsb + 48594944;    // 2097152
    ushort_t* SOb    = wsb + 50692096;    // 2359296
    // total ~107 MB
    float* PARTS = (float*)SBUFb;         // fp32 split-K partials (time-shared)

    // ---- one-time weight conversion (single dispatch) ----
    {
        CvtArgs a;
        const float* srcs[8] = { sa_wi, sa_wo, pl4_w, pl5_w, pl6_w, pl7_w, l1_w, l2_w };
        ushort_t*    dsts[8] = { SAWIb, SAWOb, PL4b, PL5b, PL6b, PL7b, L1b, L2b };
        int          ns[8]   = { 3145728, 1048576, 262144, 2097152, 2097152, 2097152, 2097152, 262144 };
        int cum = 0;
        for (int i = 0; i < 8; i++) { a.src[i] = srcs[i]; a.dst[i] = dsts[i]; cum += ns[i] / 4; a.end[i] = cum; }
        cvt_all<<<(cum + 255) / 256, 256, 0, stream>>>(a);
    }

    // ---- collapsed feature-attention block ----
    precomp1<<<1, 384, 0, stream>>>(fa_wi, fa_bi, pl1_w, pl1_b, CONSTS);
    precomp2<<<1, 128, 0, stream>>>(fa_wo, fa_bo, CONSTS);
    precomp3<<<8, 256, 0, stream>>>(pl2_w, pl2_b, CONSTS, Gbb);
    feat_mlp_ln<<<2304, 512, 0, stream>>>(src, CONSTS, Gbb, pl3_w, pl3_b, pn1_g, pn1_b, SRC1b);

    // ---- src1_ = relu(src1@pl4^T+b)@pl5^T+b  (pl5 split-K x2) ----
    gemm_go(stream, SRC1b, PL4b, pl4_b, HBIGb, 2304, 2048, 128, 128, 128, 2048, 0, 0, 0, 1, 1.f, true);
    gemm_go(stream, HBIGb, PL5b, nullptr, nullptr, 2304, 1024, 2048, 2048, 2048, 1024, 0, 0, 0, 1, 1.f, false,
            0, 0, 0, 0, 2, PARTS, 2359296);
    sum_cvt<false><<<2304, 256, 0, stream>>>(PARTS, 2359296, 2, pl5_b, 1024, SRC1_b, 589824);

    // ---- qkv over ALL 2304 rows (rows 2048+ give cross-attn Q for free) ----
    gemm_go(stream, SRC1_b, SAWIb, sa_bi, QKVb, 2304, 3072, 1024, 1024, 1024, 3072, 0, 0, 0, 1, 1.f, false);
    const float iscale = 0.08838834764831845f;   // 1/sqrt(128)
    ushort_t* VT1 = HBIGb;
    transp128<<<dim3(16, 1, 16), 256, 0, stream>>>(QKVb + 2048, VT1, 6144, 128, 3072, 131072);
    // self-attention on rows 0..2047, z = h + 8*b
    gemm_go(stream, QKVb, QKVb + 1024, nullptr, SBUFb,
            1024, 1024, 128, 6144, 6144, 1024, 128, 128, 1048576, 16, iscale, false,
            3072, 3072, 8388608, 3);
    softmax_bf16<<<16384, 256, 0, stream>>>(SBUFb);
    gemm_go(stream, SBUFb, VT1, nullptr, OBUFb,
            1024, 128, 1024, 1024, 1024, 2048, 1048576, 131072, 128, 16, 1.f, false,
            8388608, 1048576, 1024, 3);
    // wo split-K x2: 128 -> 256 blocks (scores dead, PARTS = SBUF)
    gemm_go(stream, OBUFb, SAWOb, nullptr, nullptr, 2048, 1024, 1024, 1024, 1024, 1024, 0, 0, 0, 1, 1.f, false,
            0, 0, 0, 0, 2, PARTS, 2097152);
    sum_cvt<false><<<2048, 256, 0, stream>>>(PARTS, 2097152, 2, sa_bo, 1024, HBIGb, 524288);
    ln_bf16<false><<<2048, 256, 0, stream>>>(HBIGb, SRC1_b, nullptr, pn2_g, pn2_b, SLb, 1024);

    // ---- sl_ = ln(relu(sl@pl6^T)@pl7^T, pn2) + sl ----
    // pl6 split-K x2: 256 -> 512 blocks (partials = 33.5 MB = whole SBUF)
    gemm_go(stream, SLb, PL6b, nullptr, nullptr, 2048, 2048, 1024, 1024, 1024, 2048, 0, 0, 0, 1, 1.f, false,
            0, 0, 0, 0, 2, PARTS, 4194304);
    sum_cvt<true><<<4096, 256, 0, stream>>>(PARTS, 4194304, 2, pl6_b, 2048, HBIGb, 1048576);
    // pl7 split-K x2 (K=2048): 128 -> 256 blocks
    gemm_go(stream, HBIGb, PL7b, nullptr, nullptr, 2048, 1024, 2048, 2048, 2048, 1024, 0, 0, 0, 1, 1.f, false,
            0, 0, 0, 0, 2, PARTS, 2097152);
    sum_cvt<false><<<2048, 256, 0, stream>>>(PARTS, 2097152, 2, pl7_b, 1024, OBUFb, 524288);
    ln_bf16<false><<<2048, 256, 0, stream>>>(OBUFb, nullptr, SLb, pn2_g, pn2_b, SLPb, 1024);

    // ---- cross-attention: q from qkv rows 2048+, k/v from sl_ ----
    ushort_t* KV2 = SBUFb;               // 2048x2048
    ushort_t* S2  = SBUFb + 4456448;     // 16x128x1024
    ushort_t* SR  = SBUFb + 6553600;     // 256x1024
    gemm_go(stream, SLPb, SAWIb + 1024 * 1024, sa_bi + 1024, KV2, 2048, 2048, 1024, 1024, 1024, 2048, 0, 0, 0, 1, 1.f, false);
    ushort_t* VT2 = HBIGb;
    transp128<<<dim3(16, 1, 16), 256, 0, stream>>>(KV2 + 1024, VT2, 4096, 128, 2048, 131072);
    gemm_go(stream, QKVb + 2048 * 3072, KV2, nullptr, S2,
            128, 1024, 128, 6144, 4096, 1024, 128, 128, 131072, 16, iscale, false,
            3072, 2048, 1048576, 3);
    softmax_bf16<<<2048, 256, 0, stream>>>(S2);
    // S2-PV split-K x8 (partials in dead KV2 region = SBUF base)
    gemm_go(stream, S2, VT2, nullptr, nullptr,
            128, 128, 1024, 1024, 1024, 2048, 131072, 131072, 128, 16, 1.f, false,
            1048576, 1048576, 1024, 3, 8, PARTS, 262144);
    sum_cvt<false><<<256, 256, 0, stream>>>(PARTS, 262144, 8, nullptr, 2048, OBUFb, 65536);
    // sr-out split-K x8
    gemm_go(stream, OBUFb, SAWOb, nullptr, nullptr, 256, 1024, 1024, 1024, 1024, 1024, 0, 0, 0, 1, 1.f, false,
            0, 0, 0, 0, 8, PARTS, 262144);
    sum_cvt<false><<<256, 256, 0, stream>>>(PARTS, 262144, 8, sa_bo, 1024, SR, 65536);

    // ---- so = ln(concat(sl, sr) + src1_, n1) ----
    ln_cat<<<2304, 256, 0, stream>>>(SLb, SR, 2048, SRC1_b, n1_g, n1_b, SOb, 1024);

    // ---- ff = relu(so@l1^T)@l2^T ; out = ln(src1 + ff, n2) ----
    // l1 split-K x2: 288 -> 576 blocks (partials 37.7 MB = SBUF+OBUF, both dead)
    gemm_go(stream, SOb, L1b, nullptr, nullptr, 2304, 2048, 1024, 1024, 1024, 2048, 0, 0, 0, 1, 1.f, false,
            0, 0, 0, 0, 2, PARTS, 4718592);
    sum_cvt<true><<<4608, 256, 0, stream>>>(PARTS, 4718592, 2, l1_b, 2048, HBIGb, 1179648);
    // l2 split-K x8: final LN reads the partials directly
    gemm_go(stream, HBIGb, L2b, nullptr, nullptr, 2304, 128, 2048, 2048, 2048, 128, 0, 0, 0, 1, 1.f, false,
            0, 0, 0, 0, 8, PARTS, 294912);
    ln_part<<<2304, 128, 0, stream>>>(PARTS, 294912, 8, l2_b, SRC1b, n2_g, n2_b, out);
}